// Round 1
// baseline (558.024 us; speedup 1.0000x reference)
//
#include <hip/hip_runtime.h>
#include <hip/hip_bf16.h>

#define EPS 1e-5f

// ---------------------------------------------------------------- degree ----
__global__ void deg_init_kernel(float* __restrict__ deg, int n) {
    int i = blockIdx.x * blockDim.x + threadIdx.x;
    if (i < n) deg[i] = 1.0f;   // self-loop
}

__global__ void deg_accum_kernel(const int* __restrict__ ei, float* __restrict__ deg, int E) {
    int e = blockIdx.x * blockDim.x + threadIdx.x;
    if (e < E) atomicAdd(&deg[ei[E + e]], 1.0f);   // col = ei[1][e]
}

// ------------------------------------------------------------------ GEMM ----
// C[M, NTOT] = op(A)[M, K] @ B[K, NTOT]; op = BN(scale/shift from raw stats)+ReLU if FUSE.
// BM=64, BN=128 per block (grid.y tiles NTOT), BK=32, 256 threads, 4x8 micro-tile.
template <int K, int NTOT, bool FUSE>
__launch_bounds__(256)
__global__ void gemm_kernel(const float* __restrict__ A, const float* __restrict__ B,
                            float* __restrict__ C, int M,
                            const float* __restrict__ st,     // [K] sum, [K..2K) sumsq
                            const float* __restrict__ gamma,
                            const float* __restrict__ beta,
                            float inv_n) {
    constexpr int BM = 64, BN = 128, BK = 32;
    __shared__ float As[BK][BM + 1];
    __shared__ float Bs[BK][BN];
    __shared__ float sc[FUSE ? K : 1];
    __shared__ float sh[FUSE ? K : 1];

    const int t = threadIdx.x;
    const int row0 = blockIdx.x * BM;
    const int col0 = blockIdx.y * BN;

    if (FUSE) {
        for (int f = t; f < K; f += 256) {
            float mean = st[f] * inv_n;
            float var  = st[K + f] * inv_n - mean * mean;
            float s    = gamma[f] * rsqrtf(var + EPS);
            sc[f] = s;
            sh[f] = beta[f] - mean * s;
        }
        __syncthreads();
    }

    float acc[4][8] = {};
    const int ty = t >> 4;    // 0..15 -> rows ty*4..ty*4+3
    const int tx = t & 15;    // 0..15 -> cols tx + j*16

    for (int kk = 0; kk < K; kk += BK) {
        // A tile: 64 rows x 32 k  (thread: 2 passes of float4)
#pragma unroll
        for (int p = 0; p < 2; p++) {
            int r    = (t >> 3) + p * 32;   // 0..63
            int c4   = (t & 7) * 4;         // 0..28
            int grow = row0 + r;
            float4 v = make_float4(0.f, 0.f, 0.f, 0.f);
            if (grow < M) v = *(const float4*)&A[(size_t)grow * K + kk + c4];
            if (FUSE) {
                v.x = fmaxf(v.x * sc[kk + c4 + 0] + sh[kk + c4 + 0], 0.f);
                v.y = fmaxf(v.y * sc[kk + c4 + 1] + sh[kk + c4 + 1], 0.f);
                v.z = fmaxf(v.z * sc[kk + c4 + 2] + sh[kk + c4 + 2], 0.f);
                v.w = fmaxf(v.w * sc[kk + c4 + 3] + sh[kk + c4 + 3], 0.f);
            }
            As[c4 + 0][r] = v.x;
            As[c4 + 1][r] = v.y;
            As[c4 + 2][r] = v.z;
            As[c4 + 3][r] = v.w;
        }
        // B tile: 32 k x 128 n  (thread: 4 passes of float4)
#pragma unroll
        for (int p = 0; p < 4; p++) {
            int kr = (t >> 5) + p * 8;      // 0..31
            int n4 = (t & 31) * 4;          // 0..124
            *(float4*)&Bs[kr][n4] = *(const float4*)&B[(size_t)(kk + kr) * NTOT + col0 + n4];
        }
        __syncthreads();

#pragma unroll
        for (int k = 0; k < BK; k++) {
            float a[4], b[8];
#pragma unroll
            for (int i = 0; i < 4; i++) a[i] = As[k][ty * 4 + i];
#pragma unroll
            for (int j = 0; j < 8; j++) b[j] = Bs[k][tx + j * 16];
#pragma unroll
            for (int i = 0; i < 4; i++)
#pragma unroll
                for (int j = 0; j < 8; j++) acc[i][j] = fmaf(a[i], b[j], acc[i][j]);
        }
        __syncthreads();
    }

#pragma unroll
    for (int i = 0; i < 4; i++) {
        int grow = row0 + ty * 4 + i;
        if (grow < M) {
#pragma unroll
            for (int j = 0; j < 8; j++)
                C[(size_t)grow * NTOT + col0 + tx + j * 16] = acc[i][j];
        }
    }
}

// --------------------------------------------------------------- scatter ----
// agg[i][:] = hw[i][:] / deg[i] + bias[:]   (self-loop term + conv bias)
template <int F>
__global__ void scatter_init_kernel(const float* __restrict__ hw, const float* __restrict__ deg,
                                    const float* __restrict__ bias, float* __restrict__ agg, int n) {
    int idx = blockIdx.x * blockDim.x + threadIdx.x;
    if (idx >= n * (F / 4)) return;
    int i  = idx / (F / 4);
    int f4 = (idx % (F / 4)) * 4;
    float inv = 1.0f / deg[i];
    float4 v = *(const float4*)&hw[(size_t)i * F + f4];
    float4 b = *(const float4*)&bias[f4];
    float4 o;
    o.x = v.x * inv + b.x;
    o.y = v.y * inv + b.y;
    o.z = v.z * inv + b.z;
    o.w = v.w * inv + b.w;
    *(float4*)&agg[(size_t)i * F + f4] = o;
}

// agg[col[e]][:] += hw[row[e]][:] * rsqrt(deg[row]*deg[col]) for each edge.
template <int F>
__launch_bounds__(256)
__global__ void scatter_edges_kernel(const float* __restrict__ hw, const int* __restrict__ ei,
                                     const float* __restrict__ deg, float* __restrict__ agg, int E) {
    constexpr int L   = F / 4;     // lanes per edge
    constexpr int EPB = 256 / L;   // edges per block
    int e    = blockIdx.x * EPB + threadIdx.x / L;
    int lane = threadIdx.x % L;
    if (e >= E) return;
    int r = ei[e];
    int c = ei[E + e];
    float norm = rsqrtf(deg[r] * deg[c]);
    const float* src = hw + (size_t)r * F;
    float* dst       = agg + (size_t)c * F;
#pragma unroll
    for (int j = 0; j < 4; j++) {
        int f = j * L + lane;
        atomicAdd(&dst[f], src[f] * norm);
    }
}

// ----------------------------------------------------------------- stats ----
// out[0..F) += per-feature sum; out[F..2F) += per-feature sum of squares.
template <int F>
__launch_bounds__(256)
__global__ void stats_kernel(const float* __restrict__ h, int n, float* __restrict__ out) {
    constexpr int R = 256 / F;
    __shared__ float red[512];
    int t  = threadIdx.x;
    int f  = t % F;
    int rs = t / F;
    float s = 0.f, s2 = 0.f;
    int rows = (n + gridDim.x - 1) / gridDim.x;
    int i0 = blockIdx.x * rows;
    int i1 = min(i0 + rows, n);
    for (int i = i0 + rs; i < i1; i += R) {
        float v = h[(size_t)i * F + f];
        s  += v;
        s2 += v * v;
    }
    if (R == 2) {
        red[t]       = s;
        red[256 + t] = s2;
        __syncthreads();
        if (t < F) {
            s  += red[t + F];
            s2 += red[256 + t + F];
        }
    }
    if (t < F) {
        atomicAdd(&out[f], s);
        atomicAdd(&out[F + f], s2);
    }
}

// ------------------------------------------------------------------ pool ----
// pooled[g][:] += relu(BN2(agg2[i][:])) for nodes i with batch[i]==g; counts[g] += 1.
// Exploits sorted batch: per-chunk local accumulation, flush on segment change.
__launch_bounds__(256)
__global__ void pool_kernel(const float* __restrict__ agg2, const int* __restrict__ batch,
                            const float* __restrict__ st2, const float* __restrict__ g2,
                            const float* __restrict__ be2, float inv_n,
                            float* __restrict__ pooled, float* __restrict__ counts, int n) {
    constexpr int CHUNK = 32;
    int f = threadIdx.x;   // 256 = feature
    float mean = st2[f] * inv_n;
    float var  = st2[256 + f] * inv_n - mean * mean;
    float sc   = g2[f] * rsqrtf(var + EPS);
    float sh   = be2[f] - mean * sc;
    int i0 = blockIdx.x * CHUNK;
    int i1 = min(i0 + CHUNK, n);
    int cur = -1;
    float acc = 0.f, cnt = 0.f;
    for (int i = i0; i < i1; i++) {
        int g = batch[i];
        if (g != cur) {
            if (cur >= 0) {
                atomicAdd(&pooled[(size_t)cur * 256 + f], acc);
                if (f == 0) atomicAdd(&counts[cur], cnt);
            }
            cur = g;
            acc = 0.f;
            cnt = 0.f;
        }
        float v = fmaxf(agg2[(size_t)i * 256 + f] * sc + sh, 0.f);
        acc += v;
        cnt += 1.f;
    }
    if (cur >= 0) {
        atomicAdd(&pooled[(size_t)cur * 256 + f], acc);
        if (f == 0) atomicAdd(&counts[cur], cnt);
    }
}

// -------------------------------------------------------------- small FC ----
__launch_bounds__(128)
__global__ void solv_kernel(const float* __restrict__ sf, const float* __restrict__ Ws,
                            const float* __restrict__ bs, float* __restrict__ solv) {
    __shared__ float s[128];
    int g = blockIdx.x, f = threadIdx.x;
    s[f] = sf[g * 128 + f];
    __syncthreads();
    float acc = 0.f;
#pragma unroll 8
    for (int k = 0; k < 128; k++) acc = fmaf(s[k], Ws[k * 128 + f], acc);
    solv[g * 128 + f] = fmaxf(acc + bs[f], 0.f);
}

__launch_bounds__(128)
__global__ void fc1_kernel(const float* __restrict__ pooled, const float* __restrict__ counts,
                           const float* __restrict__ solv, const float* __restrict__ Wf1,
                           const float* __restrict__ bf1, float* __restrict__ y) {
    __shared__ float z[384];
    int g = blockIdx.x, f = threadIdx.x;   // 128 threads
    float inv = 1.0f / fmaxf(counts[g], 1.0f);
    z[f]       = pooled[g * 256 + f] * inv;
    z[128 + f] = pooled[g * 256 + 128 + f] * inv;
    z[256 + f] = solv[g * 128 + f];
    __syncthreads();
    float acc = 0.f;
#pragma unroll 8
    for (int k = 0; k < 384; k++) acc = fmaf(z[k], Wf1[k * 128 + f], acc);
    y[g * 128 + f] = acc + bf1[f];
}

__launch_bounds__(128)
__global__ void final_kernel(const float* __restrict__ y, const float* __restrict__ stf,
                             const float* __restrict__ gf, const float* __restrict__ bef,
                             const float* __restrict__ Wf2, const float* __restrict__ bf2,
                             float* __restrict__ out, float inv_n) {
    __shared__ float red[2];
    int g = blockIdx.x, f = threadIdx.x;   // 128 threads = 2 waves
    float mean = stf[f] * inv_n;
    float var  = stf[128 + f] * inv_n - mean * mean;
    float sc   = gf[f] * rsqrtf(var + EPS);
    float sh   = bef[f] - mean * sc;
    float v = fmaxf(y[g * 128 + f] * sc + sh, 0.f) * Wf2[f];
#pragma unroll
    for (int off = 32; off > 0; off >>= 1) v += __shfl_down(v, off);
    if ((f & 63) == 0) red[f >> 6] = v;
    __syncthreads();
    if (f == 0) out[g] = red[0] + red[1] + bf2[0];
}

// ---------------------------------------------------------------- launch ----
extern "C" void kernel_launch(void* const* d_in, const int* in_sizes, int n_in,
                              void* d_out, int out_size, void* d_ws, size_t ws_size,
                              hipStream_t stream) {
    const float* x    = (const float*)d_in[0];
    const int*   ei   = (const int*)d_in[1];
    const int*   batch= (const int*)d_in[2];
    const float* sf   = (const float*)d_in[3];
    const float* W1   = (const float*)d_in[4];
    const float* b1   = (const float*)d_in[5];
    const float* g1   = (const float*)d_in[6];
    const float* be1  = (const float*)d_in[7];
    const float* W2   = (const float*)d_in[8];
    const float* b2   = (const float*)d_in[9];
    const float* g2   = (const float*)d_in[10];
    const float* be2  = (const float*)d_in[11];
    const float* Ws   = (const float*)d_in[12];
    const float* bs   = (const float*)d_in[13];
    const float* Wf1  = (const float*)d_in[14];
    const float* bf1  = (const float*)d_in[15];
    const float* gf1  = (const float*)d_in[16];
    const float* bef1 = (const float*)d_in[17];
    const float* Wf2  = (const float*)d_in[18];
    const float* bf2  = (const float*)d_in[19];
    float* out = (float*)d_out;

    const int n = in_sizes[0] / 64;    // 20000 nodes
    const int E = in_sizes[1] / 2;     // 320000 edges
    const int G = in_sizes[3] / 128;   // 512 graphs

    // workspace layout (floats); agg2 aliases hw1+agg1 (both dead before scatter2)
    float* ws     = (float*)d_ws;
    float* deg    = ws;                            // n
    float* hw1    = deg + n;                       // n*128
    float* agg1   = hw1 + (size_t)n * 128;         // n*128
    float* agg2   = hw1;                           // n*256 (alias)
    float* hw2    = agg1 + (size_t)n * 128;        // n*256
    float* pooled = hw2 + (size_t)n * 256;         // G*256
    float* counts = pooled + (size_t)G * 256;      // G
    float* solv   = counts + G;                    // G*128
    float* yf     = solv + (size_t)G * 128;        // G*128
    float* st1    = yf + (size_t)G * 128;          // 256
    float* st2    = st1 + 256;                     // 512
    float* stf    = st2 + 512;                     // 256

    // zero the accumulator tail (pooled .. stf end) every launch
    size_t tail_floats = (size_t)G * 256 + G + (size_t)G * 128 * 2 + 256 + 512 + 256;
    hipMemsetAsync(pooled, 0, tail_floats * sizeof(float), stream);

    const float inv_nn = 1.0f / (float)n;
    const float inv_gg = 1.0f / (float)G;

    deg_init_kernel<<<(n + 255) / 256, 256, 0, stream>>>(deg, n);
    deg_accum_kernel<<<(E + 255) / 256, 256, 0, stream>>>(ei, deg, E);

    // layer 1: hw1 = x @ W1
    gemm_kernel<64, 128, false><<<dim3((n + 63) / 64, 1), 256, 0, stream>>>(
        x, W1, hw1, n, nullptr, nullptr, nullptr, 0.f);
    scatter_init_kernel<128><<<((size_t)n * 32 + 255) / 256, 256, 0, stream>>>(hw1, deg, b1, agg1, n);
    scatter_edges_kernel<128><<<(E + 7) / 8, 256, 0, stream>>>(hw1, ei, deg, agg1, E);
    stats_kernel<128><<<256, 256, 0, stream>>>(agg1, n, st1);

    // layer 2: hw2 = relu(BN1(agg1)) @ W2   (BN fused into A load)
    gemm_kernel<128, 256, true><<<dim3((n + 63) / 64, 2), 256, 0, stream>>>(
        agg1, W2, hw2, n, st1, g1, be1, inv_nn);
    scatter_init_kernel<256><<<((size_t)n * 64 + 255) / 256, 256, 0, stream>>>(hw2, deg, b2, agg2, n);
    scatter_edges_kernel<256><<<(E + 3) / 4, 256, 0, stream>>>(hw2, ei, deg, agg2, E);
    stats_kernel<256><<<256, 256, 0, stream>>>(agg2, n, st2);

    // pool with fused BN2+ReLU
    pool_kernel<<<(n + 31) / 32, 256, 0, stream>>>(agg2, batch, st2, g2, be2, inv_nn,
                                                   pooled, counts, n);

    // head
    solv_kernel<<<G, 128, 0, stream>>>(sf, Ws, bs, solv);
    fc1_kernel<<<G, 128, 0, stream>>>(pooled, counts, solv, Wf1, bf1, yf);
    stats_kernel<128><<<8, 256, 0, stream>>>(yf, G, stf);
    final_kernel<<<G, 128, 0, stream>>>(yf, stf, gf1, bef1, Wf2, bf2, out, inv_gg);
}

// Round 2
// 297.993 us; speedup vs baseline: 1.8726x; 1.8726x over previous
//
#include <hip/hip_runtime.h>
#include <hip/hip_bf16.h>

#define EPS 1e-5f

// ------------------------------------------------------------- CSR build ----
__global__ void count_kernel(const int* __restrict__ ei, int* __restrict__ counts, int E) {
    int e = blockIdx.x * blockDim.x + threadIdx.x;
    if (e < E) atomicAdd(&counts[ei[E + e]], 1);   // col = ei[1][e]
}

// single block, 256 threads: exclusive prefix sum of counts -> start, cursor
__global__ void scan_kernel(const int* __restrict__ counts, int* __restrict__ start,
                            int* __restrict__ cursor, int n) {
    __shared__ int ls[256];
    int t = threadIdx.x;
    int chunk = (n + 255) / 256;
    int i0 = t * chunk, i1 = min(i0 + chunk, n);
    int s = 0;
    for (int i = i0; i < i1; i++) s += counts[i];
    ls[t] = s;
    __syncthreads();
    if (t == 0) {
        int run = 0;
        for (int k = 0; k < 256; k++) { int v = ls[k]; ls[k] = run; run += v; }
        start[n] = run;
    }
    __syncthreads();
    int run = ls[t];
    for (int i = i0; i < i1; i++) {
        start[i]  = run;
        cursor[i] = run;
        run += counts[i];
    }
}

__global__ void fill_kernel(const int* __restrict__ ei, const int* __restrict__ counts,
                            int* __restrict__ cursor, int* __restrict__ csr_row,
                            float* __restrict__ csr_norm, int E) {
    int e = blockIdx.x * blockDim.x + threadIdx.x;
    if (e >= E) return;
    int r = ei[e];
    int c = ei[E + e];
    int pos = atomicAdd(&cursor[c], 1);
    csr_row[pos]  = r;
    csr_norm[pos] = rsqrtf((float)(counts[r] + 1) * (float)(counts[c] + 1));
}

// ---------------------------------------------------------------- gather ----
// agg[i][:] = hw[i][:]/deg[i] + bias[:] + sum_{e in in(i)} hw[row[e]][:]*norm[e]
template <int F>
__launch_bounds__(F)
__global__ void gather_kernel(const float* __restrict__ hw, const int* __restrict__ start,
                              const int* __restrict__ csr_row, const float* __restrict__ csr_norm,
                              const int* __restrict__ counts, const float* __restrict__ bias,
                              float* __restrict__ agg, int n) {
    int i = blockIdx.x;
    int f = threadIdx.x;
    float inv = 1.0f / (float)(counts[i] + 1);
    float acc = hw[(size_t)i * F + f] * inv + bias[f];
    int e  = start[i];
    int e1 = start[i + 1];
    float acc2 = 0.f;
    for (; e + 1 < e1; e += 2) {
        int   r0 = csr_row[e],  r1 = csr_row[e + 1];
        float n0 = csr_norm[e], n1 = csr_norm[e + 1];
        float v0 = hw[(size_t)r0 * F + f];
        float v1 = hw[(size_t)r1 * F + f];
        acc  = fmaf(v0, n0, acc);
        acc2 = fmaf(v1, n1, acc2);
    }
    if (e < e1) {
        acc = fmaf(hw[(size_t)csr_row[e] * F + f], csr_norm[e], acc);
    }
    agg[(size_t)i * F + f] = acc + acc2;
}

// ------------------------------------------------------------------ GEMM ----
template <int K, int NTOT, bool FUSE>
__launch_bounds__(256)
__global__ void gemm_kernel(const float* __restrict__ A, const float* __restrict__ B,
                            float* __restrict__ C, int M,
                            const float* __restrict__ st,
                            const float* __restrict__ gamma,
                            const float* __restrict__ beta,
                            float inv_n) {
    constexpr int BM = 64, BN = 128, BK = 32;
    __shared__ float As[BK][BM + 1];
    __shared__ float Bs[BK][BN];
    __shared__ float sc[FUSE ? K : 1];
    __shared__ float sh[FUSE ? K : 1];

    const int t = threadIdx.x;
    const int row0 = blockIdx.x * BM;
    const int col0 = blockIdx.y * BN;

    if (FUSE) {
        for (int f = t; f < K; f += 256) {
            float mean = st[f] * inv_n;
            float var  = st[K + f] * inv_n - mean * mean;
            float s    = gamma[f] * rsqrtf(var + EPS);
            sc[f] = s;
            sh[f] = beta[f] - mean * s;
        }
        __syncthreads();
    }

    float acc[4][8] = {};
    const int ty = t >> 4;
    const int tx = t & 15;

    for (int kk = 0; kk < K; kk += BK) {
#pragma unroll
        for (int p = 0; p < 2; p++) {
            int r    = (t >> 3) + p * 32;
            int c4   = (t & 7) * 4;
            int grow = row0 + r;
            float4 v = make_float4(0.f, 0.f, 0.f, 0.f);
            if (grow < M) v = *(const float4*)&A[(size_t)grow * K + kk + c4];
            if (FUSE) {
                v.x = fmaxf(v.x * sc[kk + c4 + 0] + sh[kk + c4 + 0], 0.f);
                v.y = fmaxf(v.y * sc[kk + c4 + 1] + sh[kk + c4 + 1], 0.f);
                v.z = fmaxf(v.z * sc[kk + c4 + 2] + sh[kk + c4 + 2], 0.f);
                v.w = fmaxf(v.w * sc[kk + c4 + 3] + sh[kk + c4 + 3], 0.f);
            }
            As[c4 + 0][r] = v.x;
            As[c4 + 1][r] = v.y;
            As[c4 + 2][r] = v.z;
            As[c4 + 3][r] = v.w;
        }
#pragma unroll
        for (int p = 0; p < 4; p++) {
            int kr = (t >> 5) + p * 8;
            int n4 = (t & 31) * 4;
            *(float4*)&Bs[kr][n4] = *(const float4*)&B[(size_t)(kk + kr) * NTOT + col0 + n4];
        }
        __syncthreads();

#pragma unroll
        for (int k = 0; k < BK; k++) {
            float a[4], b[8];
#pragma unroll
            for (int i = 0; i < 4; i++) a[i] = As[k][ty * 4 + i];
#pragma unroll
            for (int j = 0; j < 8; j++) b[j] = Bs[k][tx + j * 16];
#pragma unroll
            for (int i = 0; i < 4; i++)
#pragma unroll
                for (int j = 0; j < 8; j++) acc[i][j] = fmaf(a[i], b[j], acc[i][j]);
        }
        __syncthreads();
    }

#pragma unroll
    for (int i = 0; i < 4; i++) {
        int grow = row0 + ty * 4 + i;
        if (grow < M) {
#pragma unroll
            for (int j = 0; j < 8; j++)
                C[(size_t)grow * NTOT + col0 + tx + j * 16] = acc[i][j];
        }
    }
}

// ----------------------------------------------------------------- stats ----
template <int F>
__launch_bounds__(256)
__global__ void stats_kernel(const float* __restrict__ h, int n, float* __restrict__ out) {
    constexpr int R = 256 / F;
    __shared__ float red[512];
    int t  = threadIdx.x;
    int f  = t % F;
    int rs = t / F;
    float s = 0.f, s2 = 0.f;
    int rows = (n + gridDim.x - 1) / gridDim.x;
    int i0 = blockIdx.x * rows;
    int i1 = min(i0 + rows, n);
    for (int i = i0 + rs; i < i1; i += R) {
        float v = h[(size_t)i * F + f];
        s  += v;
        s2 += v * v;
    }
    if (R == 2) {
        red[t]       = s;
        red[256 + t] = s2;
        __syncthreads();
        if (t < F) {
            s  += red[t + F];
            s2 += red[256 + t + F];
        }
    }
    if (t < F) {
        atomicAdd(&out[f], s);
        atomicAdd(&out[F + f], s2);
    }
}

// ------------------------------------------------------------------ pool ----
__launch_bounds__(256)
__global__ void pool_kernel(const float* __restrict__ agg2, const int* __restrict__ batch,
                            const float* __restrict__ st2, const float* __restrict__ g2,
                            const float* __restrict__ be2, float inv_n,
                            float* __restrict__ pooled, float* __restrict__ counts, int n) {
    constexpr int CHUNK = 32;
    int f = threadIdx.x;
    float mean = st2[f] * inv_n;
    float var  = st2[256 + f] * inv_n - mean * mean;
    float sc   = g2[f] * rsqrtf(var + EPS);
    float sh   = be2[f] - mean * sc;
    int i0 = blockIdx.x * CHUNK;
    int i1 = min(i0 + CHUNK, n);
    int cur = -1;
    float acc = 0.f, cnt = 0.f;
    for (int i = i0; i < i1; i++) {
        int g = batch[i];
        if (g != cur) {
            if (cur >= 0) {
                atomicAdd(&pooled[(size_t)cur * 256 + f], acc);
                if (f == 0) atomicAdd(&counts[cur], cnt);
            }
            cur = g;
            acc = 0.f;
            cnt = 0.f;
        }
        float v = fmaxf(agg2[(size_t)i * 256 + f] * sc + sh, 0.f);
        acc += v;
        cnt += 1.f;
    }
    if (cur >= 0) {
        atomicAdd(&pooled[(size_t)cur * 256 + f], acc);
        if (f == 0) atomicAdd(&counts[cur], cnt);
    }
}

// -------------------------------------------------------------- small FC ----
__launch_bounds__(128)
__global__ void solv_kernel(const float* __restrict__ sf, const float* __restrict__ Ws,
                            const float* __restrict__ bs, float* __restrict__ solv) {
    __shared__ float s[128];
    int g = blockIdx.x, f = threadIdx.x;
    s[f] = sf[g * 128 + f];
    __syncthreads();
    float acc = 0.f;
#pragma unroll 8
    for (int k = 0; k < 128; k++) acc = fmaf(s[k], Ws[k * 128 + f], acc);
    solv[g * 128 + f] = fmaxf(acc + bs[f], 0.f);
}

__launch_bounds__(128)
__global__ void fc1_kernel(const float* __restrict__ pooled, const float* __restrict__ counts,
                           const float* __restrict__ solv, const float* __restrict__ Wf1,
                           const float* __restrict__ bf1, float* __restrict__ y) {
    __shared__ float z[384];
    int g = blockIdx.x, f = threadIdx.x;
    float inv = 1.0f / fmaxf(counts[g], 1.0f);
    z[f]       = pooled[g * 256 + f] * inv;
    z[128 + f] = pooled[g * 256 + 128 + f] * inv;
    z[256 + f] = solv[g * 128 + f];
    __syncthreads();
    float acc = 0.f;
#pragma unroll 8
    for (int k = 0; k < 384; k++) acc = fmaf(z[k], Wf1[k * 128 + f], acc);
    y[g * 128 + f] = acc + bf1[f];
}

__launch_bounds__(128)
__global__ void final_kernel(const float* __restrict__ y, const float* __restrict__ stf,
                             const float* __restrict__ gf, const float* __restrict__ bef,
                             const float* __restrict__ Wf2, const float* __restrict__ bf2,
                             float* __restrict__ out, float inv_n) {
    __shared__ float red[2];
    int g = blockIdx.x, f = threadIdx.x;
    float mean = stf[f] * inv_n;
    float var  = stf[128 + f] * inv_n - mean * mean;
    float sc   = gf[f] * rsqrtf(var + EPS);
    float sh   = bef[f] - mean * sc;
    float v = fmaxf(y[g * 128 + f] * sc + sh, 0.f) * Wf2[f];
#pragma unroll
    for (int off = 32; off > 0; off >>= 1) v += __shfl_down(v, off);
    if ((f & 63) == 0) red[f >> 6] = v;
    __syncthreads();
    if (f == 0) out[g] = red[0] + red[1] + bf2[0];
}

// ---------------------------------------------------------------- launch ----
extern "C" void kernel_launch(void* const* d_in, const int* in_sizes, int n_in,
                              void* d_out, int out_size, void* d_ws, size_t ws_size,
                              hipStream_t stream) {
    const float* x    = (const float*)d_in[0];
    const int*   ei   = (const int*)d_in[1];
    const int*   batch= (const int*)d_in[2];
    const float* sf   = (const float*)d_in[3];
    const float* W1   = (const float*)d_in[4];
    const float* b1   = (const float*)d_in[5];
    const float* g1   = (const float*)d_in[6];
    const float* be1  = (const float*)d_in[7];
    const float* W2   = (const float*)d_in[8];
    const float* b2   = (const float*)d_in[9];
    const float* g2   = (const float*)d_in[10];
    const float* be2  = (const float*)d_in[11];
    const float* Ws   = (const float*)d_in[12];
    const float* bs   = (const float*)d_in[13];
    const float* Wf1  = (const float*)d_in[14];
    const float* bf1  = (const float*)d_in[15];
    const float* gf1  = (const float*)d_in[16];
    const float* bef1 = (const float*)d_in[17];
    const float* Wf2  = (const float*)d_in[18];
    const float* bf2  = (const float*)d_in[19];
    float* out = (float*)d_out;

    const int n = in_sizes[0] / 64;    // 20000 nodes
    const int E = in_sizes[1] / 2;     // 320000 edges
    const int G = in_sizes[3] / 128;   // 512 graphs

    // workspace layout:
    // hw1[n*128] | agg1[n*128] | hw2[n*256] | pooled[G*256] | cnt_g[G] | st1[256] |
    // st2[512] | stf[256] | counts[n] | start[n+1] | cursor[n] | csr_row[E] | csr_nm[E] |
    // solv[G*128] | yf[G*128].   agg2 aliases hw1+agg1 (both dead before gather2 writes).
    float* ws     = (float*)d_ws;
    float* hw1    = ws;
    float* agg1   = hw1 + (size_t)n * 128;
    float* agg2   = hw1;                           // alias
    float* hw2    = agg1 + (size_t)n * 128;
    float* pooled = hw2 + (size_t)n * 256;
    float* cnt_g  = pooled + (size_t)G * 256;
    float* st1    = cnt_g + G;
    float* st2    = st1 + 256;
    float* stf    = st2 + 512;
    int*   counts = (int*)(stf + 256);
    int*   start  = counts + n;
    int*   cursor = start + n + 1;
    int*   csr_row= cursor + n;
    float* csr_nm = (float*)(csr_row + E);
    float* solv   = csr_nm + E;
    float* yf     = solv + (size_t)G * 128;

    // zero: pooled..stf (G*256+G+1024 floats) + counts (n ints) — contiguous region
    size_t zero_floats = (size_t)G * 256 + G + 1024 + n;
    hipMemsetAsync(pooled, 0, zero_floats * sizeof(float), stream);

    const float inv_nn = 1.0f / (float)n;
    const float inv_gg = 1.0f / (float)G;

    // CSR build (edges sorted by destination)
    count_kernel<<<(E + 255) / 256, 256, 0, stream>>>(ei, counts, E);
    scan_kernel<<<1, 256, 0, stream>>>(counts, start, cursor, n);
    fill_kernel<<<(E + 255) / 256, 256, 0, stream>>>(ei, counts, cursor, csr_row, csr_nm, E);

    // layer 1
    gemm_kernel<64, 128, false><<<dim3((n + 63) / 64, 1), 256, 0, stream>>>(
        x, W1, hw1, n, nullptr, nullptr, nullptr, 0.f);
    gather_kernel<128><<<n, 128, 0, stream>>>(hw1, start, csr_row, csr_nm, counts, b1, agg1, n);
    stats_kernel<128><<<256, 256, 0, stream>>>(agg1, n, st1);

    // layer 2 (BN1+ReLU fused into GEMM A-load)
    gemm_kernel<128, 256, true><<<dim3((n + 63) / 64, 2), 256, 0, stream>>>(
        agg1, W2, hw2, n, st1, g1, be1, inv_nn);
    gather_kernel<256><<<n, 256, 0, stream>>>(hw2, start, csr_row, csr_nm, counts, b2, agg2, n);
    stats_kernel<256><<<256, 256, 0, stream>>>(agg2, n, st2);

    // pool with fused BN2+ReLU
    pool_kernel<<<(n + 31) / 32, 256, 0, stream>>>(agg2, batch, st2, g2, be2, inv_nn,
                                                   pooled, cnt_g, n);

    // head
    solv_kernel<<<G, 128, 0, stream>>>(sf, Ws, bs, solv);
    fc1_kernel<<<G, 128, 0, stream>>>(pooled, cnt_g, solv, Wf1, bf1, yf);
    stats_kernel<128><<<8, 256, 0, stream>>>(yf, G, stf);
    final_kernel<<<G, 128, 0, stream>>>(yf, stf, gf1, bef1, Wf2, bf2, out, inv_gg);
}

// Round 3
// 277.818 us; speedup vs baseline: 2.0086x; 1.0726x over previous
//
#include <hip/hip_runtime.h>
#include <hip/hip_bf16.h>

#define EPS 1e-5f

// ------------------------------------------------------------- CSR build ----
__global__ void count_kernel(const int* __restrict__ ei, int* __restrict__ counts, int E) {
    int e = blockIdx.x * blockDim.x + threadIdx.x;
    if (e < E) atomicAdd(&counts[ei[E + e]], 1);   // col = ei[1][e]
}

// single block, 256 threads: exclusive prefix sum of counts -> start, cursor
__global__ void scan_kernel(const int* __restrict__ counts, int* __restrict__ start,
                            int* __restrict__ cursor, int n) {
    __shared__ int ls[256];
    int t = threadIdx.x;
    int chunk = (n + 255) / 256;
    int i0 = t * chunk, i1 = min(i0 + chunk, n);
    int s = 0;
    for (int i = i0; i < i1; i++) s += counts[i];
    ls[t] = s;
    __syncthreads();
    if (t == 0) {
        int run = 0;
        for (int k = 0; k < 256; k++) { int v = ls[k]; ls[k] = run; run += v; }
        start[n] = run;
    }
    __syncthreads();
    int run = ls[t];
    for (int i = i0; i < i1; i++) {
        start[i]  = run;
        cursor[i] = run;
        run += counts[i];
    }
}

__global__ void fill_kernel(const int* __restrict__ ei, const int* __restrict__ counts,
                            int* __restrict__ cursor, int* __restrict__ csr_row,
                            float* __restrict__ csr_norm, int E) {
    int e = blockIdx.x * blockDim.x + threadIdx.x;
    if (e >= E) return;
    int r = ei[e];
    int c = ei[E + e];
    int pos = atomicAdd(&cursor[c], 1);
    csr_row[pos]  = r;
    csr_norm[pos] = rsqrtf((float)(counts[r] + 1) * (float)(counts[c] + 1));
}

// ---------------------------------------------------------------- gather ----
// dst[i][f] = T(src[i][f])/deg_i + sum_{e in in(i)} T(src[row_e][f]) * norm_e
// T = identity, or relu(BN(.)) when BN=true (per-feature affine from raw stats).
// Feature dim split into SLICES halves, pinned to XCD subsets via blockIdx%8:
// XCDs 0..3 work slice 0, XCDs 4..7 slice 1 -> per-XCD table slice may be L2-resident.
template <int F, int SLICES, bool BN>
__launch_bounds__(256)
__global__ void gather_kernel(const float* __restrict__ src, const int* __restrict__ start,
                              const int* __restrict__ csr_row, const float* __restrict__ csr_norm,
                              const int* __restrict__ counts,
                              const float* __restrict__ st, const float* __restrict__ gamma,
                              const float* __restrict__ beta, float inv_n,
                              float* __restrict__ dst, int n, int groups_per_slice) {
    constexpr int W   = F / SLICES;   // lanes per node
    constexpr int NPB = 256 / W;      // nodes per block

    int bid = blockIdx.x;
    int slice, group;
    if (SLICES == 2) {
        int xl = bid & 7;
        slice  = xl >> 2;                       // XCD 0-3 -> 0, 4-7 -> 1
        group  = (bid >> 3) * 4 + (xl & 3);
    } else {
        slice = 0;
        group = bid;
    }
    if (group >= groups_per_slice) return;

    int local = threadIdx.x / W;
    int lane  = threadIdx.x % W;
    int node  = group * NPB + local;
    if (node >= n) return;
    int feat  = slice * W + lane;

    float sc = 1.f, sh = 0.f;
    if (BN) {
        float mean = st[feat] * inv_n;
        float var  = st[F + feat] * inv_n - mean * mean;
        sc = gamma[feat] * rsqrtf(var + EPS);
        sh = beta[feat] - mean * sc;
    }
#define T(v) (BN ? fmaxf(fmaf((v), sc, sh), 0.f) : (v))

    float inv = 1.0f / (float)(counts[node] + 1);
    float acc = T(src[(size_t)node * F + feat]) * inv;
    float acc2 = 0.f;
    int e  = start[node];
    int e1 = start[node + 1];
    for (; e + 1 < e1; e += 2) {
        int   r0 = csr_row[e],  r1 = csr_row[e + 1];
        float n0 = csr_norm[e], n1 = csr_norm[e + 1];
        float v0 = T(src[(size_t)r0 * F + feat]);
        float v1 = T(src[(size_t)r1 * F + feat]);
        acc  = fmaf(v0, n0, acc);
        acc2 = fmaf(v1, n1, acc2);
    }
    if (e < e1) {
        acc = fmaf(T(src[(size_t)csr_row[e] * F + feat]), csr_norm[e], acc);
    }
    dst[(size_t)node * F + feat] = acc + acc2;
#undef T
}

// ------------------------------------------------------------------ GEMM ----
// C[M, NTOT] = A[M, K] @ B[K, NTOT] + bias[NTOT]
template <int K, int NTOT>
__launch_bounds__(256)
__global__ void gemm_kernel(const float* __restrict__ A, const float* __restrict__ B,
                            const float* __restrict__ bias, float* __restrict__ C, int M) {
    constexpr int BM = 64, BN = 128, BK = 32;
    __shared__ float As[BK][BM + 1];
    __shared__ float Bs[BK][BN];

    const int t = threadIdx.x;
    const int row0 = blockIdx.x * BM;
    const int col0 = blockIdx.y * BN;

    float acc[4][8] = {};
    const int ty = t >> 4;
    const int tx = t & 15;

    for (int kk = 0; kk < K; kk += BK) {
#pragma unroll
        for (int p = 0; p < 2; p++) {
            int r    = (t >> 3) + p * 32;
            int c4   = (t & 7) * 4;
            int grow = row0 + r;
            float4 v = make_float4(0.f, 0.f, 0.f, 0.f);
            if (grow < M) v = *(const float4*)&A[(size_t)grow * K + kk + c4];
            As[c4 + 0][r] = v.x;
            As[c4 + 1][r] = v.y;
            As[c4 + 2][r] = v.z;
            As[c4 + 3][r] = v.w;
        }
#pragma unroll
        for (int p = 0; p < 4; p++) {
            int kr = (t >> 5) + p * 8;
            int n4 = (t & 31) * 4;
            *(float4*)&Bs[kr][n4] = *(const float4*)&B[(size_t)(kk + kr) * NTOT + col0 + n4];
        }
        __syncthreads();

#pragma unroll
        for (int k = 0; k < BK; k++) {
            float a[4], b[8];
#pragma unroll
            for (int i = 0; i < 4; i++) a[i] = As[k][ty * 4 + i];
#pragma unroll
            for (int j = 0; j < 8; j++) b[j] = Bs[k][tx + j * 16];
#pragma unroll
            for (int i = 0; i < 4; i++)
#pragma unroll
                for (int j = 0; j < 8; j++) acc[i][j] = fmaf(a[i], b[j], acc[i][j]);
        }
        __syncthreads();
    }

#pragma unroll
    for (int i = 0; i < 4; i++) {
        int grow = row0 + ty * 4 + i;
        if (grow < M) {
#pragma unroll
            for (int j = 0; j < 8; j++) {
                int col = col0 + tx + j * 16;
                C[(size_t)grow * NTOT + col] = acc[i][j] + bias[col];
            }
        }
    }
}

// ----------------------------------------------------------------- stats ----
template <int F>
__launch_bounds__(256)
__global__ void stats_kernel(const float* __restrict__ h, int n, float* __restrict__ out) {
    constexpr int R = 256 / F;
    __shared__ float red[512];
    int t  = threadIdx.x;
    int f  = t % F;
    int rs = t / F;
    float s = 0.f, s2 = 0.f;
    int rows = (n + gridDim.x - 1) / gridDim.x;
    int i0 = blockIdx.x * rows;
    int i1 = min(i0 + rows, n);
    for (int i = i0 + rs; i < i1; i += R) {
        float v = h[(size_t)i * F + f];
        s  += v;
        s2 += v * v;
    }
    if (R == 2) {
        red[t]       = s;
        red[256 + t] = s2;
        __syncthreads();
        if (t < F) {
            s  += red[t + F];
            s2 += red[256 + t + F];
        }
    }
    if (t < F) {
        atomicAdd(&out[f], s);
        atomicAdd(&out[F + f], s2);
    }
}

// ------------------------------------------------------------------ pool ----
__launch_bounds__(256)
__global__ void pool_kernel(const float* __restrict__ a2, const int* __restrict__ batch,
                            const float* __restrict__ st2, const float* __restrict__ g2,
                            const float* __restrict__ be2, float inv_n,
                            float* __restrict__ pooled, float* __restrict__ counts, int n) {
    constexpr int CHUNK = 32;
    int f = threadIdx.x;
    float mean = st2[f] * inv_n;
    float var  = st2[256 + f] * inv_n - mean * mean;
    float sc   = g2[f] * rsqrtf(var + EPS);
    float sh   = be2[f] - mean * sc;
    int i0 = blockIdx.x * CHUNK;
    int i1 = min(i0 + CHUNK, n);
    int cur = -1;
    float acc = 0.f, cnt = 0.f;
    for (int i = i0; i < i1; i++) {
        int g = batch[i];
        if (g != cur) {
            if (cur >= 0) {
                atomicAdd(&pooled[(size_t)cur * 256 + f], acc);
                if (f == 0) atomicAdd(&counts[cur], cnt);
            }
            cur = g;
            acc = 0.f;
            cnt = 0.f;
        }
        float v = fmaxf(a2[(size_t)i * 256 + f] * sc + sh, 0.f);
        acc += v;
        cnt += 1.f;
    }
    if (cur >= 0) {
        atomicAdd(&pooled[(size_t)cur * 256 + f], acc);
        if (f == 0) atomicAdd(&counts[cur], cnt);
    }
}

// -------------------------------------------------------------- small FC ----
__launch_bounds__(128)
__global__ void solv_kernel(const float* __restrict__ sf, const float* __restrict__ Ws,
                            const float* __restrict__ bs, float* __restrict__ solv) {
    __shared__ float s[128];
    int g = blockIdx.x, f = threadIdx.x;
    s[f] = sf[g * 128 + f];
    __syncthreads();
    float acc = 0.f;
#pragma unroll 8
    for (int k = 0; k < 128; k++) acc = fmaf(s[k], Ws[k * 128 + f], acc);
    solv[g * 128 + f] = fmaxf(acc + bs[f], 0.f);
}

__launch_bounds__(128)
__global__ void fc1_kernel(const float* __restrict__ pooled, const float* __restrict__ counts,
                           const float* __restrict__ solv, const float* __restrict__ Wf1,
                           const float* __restrict__ bf1, float* __restrict__ y) {
    __shared__ float z[384];
    int g = blockIdx.x, f = threadIdx.x;
    float inv = 1.0f / fmaxf(counts[g], 1.0f);
    z[f]       = pooled[g * 256 + f] * inv;
    z[128 + f] = pooled[g * 256 + 128 + f] * inv;
    z[256 + f] = solv[g * 128 + f];
    __syncthreads();
    float acc = 0.f;
#pragma unroll 8
    for (int k = 0; k < 384; k++) acc = fmaf(z[k], Wf1[k * 128 + f], acc);
    y[g * 128 + f] = acc + bf1[f];
}

__launch_bounds__(128)
__global__ void final_kernel(const float* __restrict__ y, const float* __restrict__ stf,
                             const float* __restrict__ gf, const float* __restrict__ bef,
                             const float* __restrict__ Wf2, const float* __restrict__ bf2,
                             float* __restrict__ out, float inv_n) {
    __shared__ float red[2];
    int g = blockIdx.x, f = threadIdx.x;
    float mean = stf[f] * inv_n;
    float var  = stf[128 + f] * inv_n - mean * mean;
    float sc   = gf[f] * rsqrtf(var + EPS);
    float sh   = bef[f] - mean * sc;
    float v = fmaxf(y[g * 128 + f] * sc + sh, 0.f) * Wf2[f];
#pragma unroll
    for (int off = 32; off > 0; off >>= 1) v += __shfl_down(v, off);
    if ((f & 63) == 0) red[f >> 6] = v;
    __syncthreads();
    if (f == 0) out[g] = red[0] + red[1] + bf2[0];
}

// ---------------------------------------------------------------- launch ----
extern "C" void kernel_launch(void* const* d_in, const int* in_sizes, int n_in,
                              void* d_out, int out_size, void* d_ws, size_t ws_size,
                              hipStream_t stream) {
    const float* x    = (const float*)d_in[0];
    const int*   ei   = (const int*)d_in[1];
    const int*   batch= (const int*)d_in[2];
    const float* sf   = (const float*)d_in[3];
    const float* W1   = (const float*)d_in[4];
    const float* b1   = (const float*)d_in[5];
    const float* g1   = (const float*)d_in[6];
    const float* be1  = (const float*)d_in[7];
    const float* W2   = (const float*)d_in[8];
    const float* b2   = (const float*)d_in[9];
    const float* g2   = (const float*)d_in[10];
    const float* be2  = (const float*)d_in[11];
    const float* Ws   = (const float*)d_in[12];
    const float* bs   = (const float*)d_in[13];
    const float* Wf1  = (const float*)d_in[14];
    const float* bf1  = (const float*)d_in[15];
    const float* gf1  = (const float*)d_in[16];
    const float* bef1 = (const float*)d_in[17];
    const float* Wf2  = (const float*)d_in[18];
    const float* bf2  = (const float*)d_in[19];
    float* out = (float*)d_out;

    const int n = in_sizes[0] / 64;    // 20000 nodes
    const int E = in_sizes[1] / 2;     // 320000 edges
    const int G = in_sizes[3] / 128;   // 512 graphs

    // workspace layout (floats):
    // a2 [0,256n)  (xa [0,64n) aliases its head; xa dead before GEMM2 writes a2)
    // h1a [256n,384n) | a1 [384n,512n) | pooled[G*256] | cnt_g[G] | st1[256] |
    // st2[512] | stf[256] | counts[n] | start[n+1] | cursor[n] | csr_row[E] |
    // csr_nm[E] | solv[G*128] | yf[G*128]
    float* ws     = (float*)d_ws;
    float* a2     = ws;
    float* xa     = ws;                            // alias (dead before GEMM2)
    float* h1a    = ws + (size_t)n * 256;
    float* a1     = ws + (size_t)n * 384;
    float* pooled = ws + (size_t)n * 512;
    float* cnt_g  = pooled + (size_t)G * 256;
    float* st1    = cnt_g + G;
    float* st2    = st1 + 256;
    float* stf    = st2 + 512;
    int*   counts = (int*)(stf + 256);
    int*   start  = counts + n;
    int*   cursor = start + n + 1;
    int*   csr_row= cursor + n;
    float* csr_nm = (float*)(csr_row + E);
    float* solv   = csr_nm + E;
    float* yf     = solv + (size_t)G * 128;

    // zero: pooled..stf (G*256+G+1024 floats) + counts (n ints) — contiguous
    size_t zero_floats = (size_t)G * 256 + G + 1024 + n;
    hipMemsetAsync(pooled, 0, zero_floats * sizeof(float), stream);

    const float inv_nn = 1.0f / (float)n;
    const float inv_gg = 1.0f / (float)G;

    // CSR build (edges sorted by destination)
    count_kernel<<<(E + 255) / 256, 256, 0, stream>>>(ei, counts, E);
    scan_kernel<<<1, 256, 0, stream>>>(counts, start, cursor, n);
    fill_kernel<<<(E + 255) / 256, 256, 0, stream>>>(ei, counts, cursor, csr_row, csr_nm, E);

    // layer 1: xa = A_hat @ X  (gather on X, 64-wide, sliced 2x32)
    {
        constexpr int NPB = 256 / (64 / 2);
        int gps  = (n + NPB - 1) / NPB;
        int grid = ((gps + 3) / 4) * 8;
        gather_kernel<64, 2, false><<<grid, 256, 0, stream>>>(
            x, start, csr_row, csr_nm, counts, nullptr, nullptr, nullptr, 0.f, xa, n, gps);
    }
    // a1 = xa @ W1 + b1
    gemm_kernel<64, 128><<<dim3((n + 63) / 64, 1), 256, 0, stream>>>(xa, W1, b1, a1, n);
    stats_kernel<128><<<256, 256, 0, stream>>>(a1, n, st1);

    // layer 2: h1a = A_hat @ relu(BN1(a1))  (gather on a1, 128-wide, sliced 2x64, BN fused)
    {
        constexpr int NPB = 256 / (128 / 2);
        int gps  = (n + NPB - 1) / NPB;
        int grid = ((gps + 3) / 4) * 8;
        gather_kernel<128, 2, true><<<grid, 256, 0, stream>>>(
            a1, start, csr_row, csr_nm, counts, st1, g1, be1, inv_nn, h1a, n, gps);
    }
    // a2 = h1a @ W2 + b2
    gemm_kernel<128, 256><<<dim3((n + 63) / 64, 2), 256, 0, stream>>>(h1a, W2, b2, a2, n);
    stats_kernel<256><<<256, 256, 0, stream>>>(a2, n, st2);

    // pool with fused BN2+ReLU
    pool_kernel<<<(n + 31) / 32, 256, 0, stream>>>(a2, batch, st2, g2, be2, inv_nn,
                                                   pooled, cnt_g, n);

    // head
    solv_kernel<<<G, 128, 0, stream>>>(sf, Ws, bs, solv);
    fc1_kernel<<<G, 128, 0, stream>>>(pooled, cnt_g, solv, Wf1, bf1, yf);
    stats_kernel<128><<<8, 256, 0, stream>>>(yf, G, stf);
    final_kernel<<<G, 128, 0, stream>>>(yf, stf, gf1, bef1, Wf2, bf2, out, inv_gg);
}

// Round 4
// 238.392 us; speedup vs baseline: 2.3408x; 1.1654x over previous
//
#include <hip/hip_runtime.h>
#include <hip/hip_bf16.h>

#define EPS 1e-5f

// ------------------------------------------------------------- CSR build ----
__global__ void count_kernel(const int* __restrict__ ei, int* __restrict__ counts, int E) {
    int e = blockIdx.x * blockDim.x + threadIdx.x;
    if (e < E) atomicAdd(&counts[ei[E + e]], 1);   // col = ei[1][e]
}

// phase 1: per-block (256-wide) sums of counts -> bsum[b]
__global__ void scan_partial_kernel(const int* __restrict__ counts, int* __restrict__ bsum, int n) {
    __shared__ int s[256];
    int t = threadIdx.x;
    int i = blockIdx.x * 256 + t;
    s[t] = (i < n) ? counts[i] : 0;
    __syncthreads();
#pragma unroll
    for (int off = 128; off > 0; off >>= 1) {
        if (t < off) s[t] += s[t + off];
        __syncthreads();
    }
    if (t == 0) bsum[blockIdx.x] = s[0];
}

// phase 2: single block; exclusive-scan bsum in place (nb <= 256); start[n] = total
__global__ void scan_offsets_kernel(int* __restrict__ bsum, int* __restrict__ start, int nb, int n) {
    __shared__ int s[256];
    int t = threadIdx.x;
    int v = (t < nb) ? bsum[t] : 0;
    s[t] = v;
    __syncthreads();
#pragma unroll
    for (int off = 1; off < 256; off <<= 1) {
        int x = (t >= off) ? s[t - off] : 0;
        __syncthreads();
        s[t] += x;
        __syncthreads();
    }
    if (t < nb) bsum[t] = s[t] - v;     // exclusive
    if (t == 255) start[n] = s[255];    // grand total (zeros beyond nb)
}

// phase 3: local exclusive scan + block offset -> start, cursor
__global__ void scan_write_kernel(const int* __restrict__ counts, const int* __restrict__ bsum,
                                  int* __restrict__ start, int* __restrict__ cursor, int n) {
    __shared__ int s[256];
    int t = threadIdx.x;
    int i = blockIdx.x * 256 + t;
    int v = (i < n) ? counts[i] : 0;
    s[t] = v;
    __syncthreads();
#pragma unroll
    for (int off = 1; off < 256; off <<= 1) {
        int x = (t >= off) ? s[t - off] : 0;
        __syncthreads();
        s[t] += x;
        __syncthreads();
    }
    if (i < n) {
        int g = bsum[blockIdx.x] + s[t] - v;   // exclusive global prefix
        start[i]  = g;
        cursor[i] = g;
    }
}

__global__ void fill_kernel(const int* __restrict__ ei, const int* __restrict__ counts,
                            int* __restrict__ cursor, int* __restrict__ csr_row,
                            float* __restrict__ csr_norm, int E) {
    int e = blockIdx.x * blockDim.x + threadIdx.x;
    if (e >= E) return;
    int r = ei[e];
    int c = ei[E + e];
    int pos = atomicAdd(&cursor[c], 1);
    csr_row[pos]  = r;
    csr_norm[pos] = rsqrtf((float)(counts[r] + 1) * (float)(counts[c] + 1));
}

// ---------------------------------------------------------------- gather ----
// dst[i][f] = T(src[i][f])/deg_i + sum_{e in in(i)} T(src[row_e][f]) * norm_e
// T = identity, or relu(BN(.)) when BN=true (per-feature affine from raw stats).
// Feature dim split into SLICES halves, pinned to XCD subsets via blockIdx%8.
template <int F, int SLICES, bool BN>
__launch_bounds__(256)
__global__ void gather_kernel(const float* __restrict__ src, const int* __restrict__ start,
                              const int* __restrict__ csr_row, const float* __restrict__ csr_norm,
                              const int* __restrict__ counts,
                              const float* __restrict__ st, const float* __restrict__ gamma,
                              const float* __restrict__ beta, float inv_n,
                              float* __restrict__ dst, int n, int groups_per_slice) {
    constexpr int W   = F / SLICES;   // lanes per node
    constexpr int NPB = 256 / W;      // nodes per block

    int bid = blockIdx.x;
    int slice, group;
    if (SLICES == 2) {
        int xl = bid & 7;
        slice  = xl >> 2;                       // XCD 0-3 -> 0, 4-7 -> 1
        group  = (bid >> 3) * 4 + (xl & 3);
    } else {
        slice = 0;
        group = bid;
    }
    if (group >= groups_per_slice) return;

    int local = threadIdx.x / W;
    int lane  = threadIdx.x % W;
    int node  = group * NPB + local;
    if (node >= n) return;
    int feat  = slice * W + lane;

    float sc = 1.f, sh = 0.f;
    if (BN) {
        float mean = st[feat] * inv_n;
        float var  = st[F + feat] * inv_n - mean * mean;
        sc = gamma[feat] * rsqrtf(var + EPS);
        sh = beta[feat] - mean * sc;
    }
#define T(v) (BN ? fmaxf(fmaf((v), sc, sh), 0.f) : (v))

    float inv = 1.0f / (float)(counts[node] + 1);
    float acc = T(src[(size_t)node * F + feat]) * inv;
    float acc2 = 0.f;
    int e  = start[node];
    int e1 = start[node + 1];
    for (; e + 1 < e1; e += 2) {
        int   r0 = csr_row[e],  r1 = csr_row[e + 1];
        float n0 = csr_norm[e], n1 = csr_norm[e + 1];
        float v0 = T(src[(size_t)r0 * F + feat]);
        float v1 = T(src[(size_t)r1 * F + feat]);
        acc  = fmaf(v0, n0, acc);
        acc2 = fmaf(v1, n1, acc2);
    }
    if (e < e1) {
        acc = fmaf(T(src[(size_t)csr_row[e] * F + feat]), csr_norm[e], acc);
    }
    dst[(size_t)node * F + feat] = acc + acc2;
#undef T
}

// ------------------------------------------------------------------ GEMM ----
// C[M, NTOT] = A[M, K] @ B[K, NTOT] + bias[NTOT]
template <int K, int NTOT>
__launch_bounds__(256)
__global__ void gemm_kernel(const float* __restrict__ A, const float* __restrict__ B,
                            const float* __restrict__ bias, float* __restrict__ C, int M) {
    constexpr int BM = 64, BN = 128, BK = 32;
    __shared__ float As[BK][BM + 1];
    __shared__ float Bs[BK][BN];

    const int t = threadIdx.x;
    const int row0 = blockIdx.x * BM;
    const int col0 = blockIdx.y * BN;

    float acc[4][8] = {};
    const int ty = t >> 4;
    const int tx = t & 15;

    for (int kk = 0; kk < K; kk += BK) {
#pragma unroll
        for (int p = 0; p < 2; p++) {
            int r    = (t >> 3) + p * 32;
            int c4   = (t & 7) * 4;
            int grow = row0 + r;
            float4 v = make_float4(0.f, 0.f, 0.f, 0.f);
            if (grow < M) v = *(const float4*)&A[(size_t)grow * K + kk + c4];
            As[c4 + 0][r] = v.x;
            As[c4 + 1][r] = v.y;
            As[c4 + 2][r] = v.z;
            As[c4 + 3][r] = v.w;
        }
#pragma unroll
        for (int p = 0; p < 4; p++) {
            int kr = (t >> 5) + p * 8;
            int n4 = (t & 31) * 4;
            *(float4*)&Bs[kr][n4] = *(const float4*)&B[(size_t)(kk + kr) * NTOT + col0 + n4];
        }
        __syncthreads();

#pragma unroll
        for (int k = 0; k < BK; k++) {
            float a[4], b[8];
#pragma unroll
            for (int i = 0; i < 4; i++) a[i] = As[k][ty * 4 + i];
#pragma unroll
            for (int j = 0; j < 8; j++) b[j] = Bs[k][tx + j * 16];
#pragma unroll
            for (int i = 0; i < 4; i++)
#pragma unroll
                for (int j = 0; j < 8; j++) acc[i][j] = fmaf(a[i], b[j], acc[i][j]);
        }
        __syncthreads();
    }

#pragma unroll
    for (int i = 0; i < 4; i++) {
        int grow = row0 + ty * 4 + i;
        if (grow < M) {
#pragma unroll
            for (int j = 0; j < 8; j++) {
                int col = col0 + tx + j * 16;
                C[(size_t)grow * NTOT + col] = acc[i][j] + bias[col];
            }
        }
    }
}

// ----------------------------------------------------------------- stats ----
template <int F>
__launch_bounds__(256)
__global__ void stats_kernel(const float* __restrict__ h, int n, float* __restrict__ out) {
    constexpr int R = 256 / F;
    __shared__ float red[512];
    int t  = threadIdx.x;
    int f  = t % F;
    int rs = t / F;
    float s = 0.f, s2 = 0.f;
    int rows = (n + gridDim.x - 1) / gridDim.x;
    int i0 = blockIdx.x * rows;
    int i1 = min(i0 + rows, n);
    for (int i = i0 + rs; i < i1; i += R) {
        float v = h[(size_t)i * F + f];
        s  += v;
        s2 += v * v;
    }
    if (R == 2) {
        red[t]       = s;
        red[256 + t] = s2;
        __syncthreads();
        if (t < F) {
            s  += red[t + F];
            s2 += red[256 + t + F];
        }
    }
    if (t < F) {
        atomicAdd(&out[f], s);
        atomicAdd(&out[F + f], s2);
    }
}

// ------------------------------------------------------------------ pool ----
__launch_bounds__(256)
__global__ void pool_kernel(const float* __restrict__ a2, const int* __restrict__ batch,
                            const float* __restrict__ st2, const float* __restrict__ g2,
                            const float* __restrict__ be2, float inv_n,
                            float* __restrict__ pooled, float* __restrict__ counts, int n) {
    constexpr int CHUNK = 32;
    int f = threadIdx.x;
    float mean = st2[f] * inv_n;
    float var  = st2[256 + f] * inv_n - mean * mean;
    float sc   = g2[f] * rsqrtf(var + EPS);
    float sh   = be2[f] - mean * sc;
    int i0 = blockIdx.x * CHUNK;
    int i1 = min(i0 + CHUNK, n);
    int cur = -1;
    float acc = 0.f, cnt = 0.f;
    for (int i = i0; i < i1; i++) {
        int g = batch[i];
        if (g != cur) {
            if (cur >= 0) {
                atomicAdd(&pooled[(size_t)cur * 256 + f], acc);
                if (f == 0) atomicAdd(&counts[cur], cnt);
            }
            cur = g;
            acc = 0.f;
            cnt = 0.f;
        }
        float v = fmaxf(a2[(size_t)i * 256 + f] * sc + sh, 0.f);
        acc += v;
        cnt += 1.f;
    }
    if (cur >= 0) {
        atomicAdd(&pooled[(size_t)cur * 256 + f], acc);
        if (f == 0) atomicAdd(&counts[cur], cnt);
    }
}

// -------------------------------------------------------------- small FC ----
__launch_bounds__(128)
__global__ void solv_kernel(const float* __restrict__ sf, const float* __restrict__ Ws,
                            const float* __restrict__ bs, float* __restrict__ solv) {
    __shared__ float s[128];
    int g = blockIdx.x, f = threadIdx.x;
    s[f] = sf[g * 128 + f];
    __syncthreads();
    float acc = 0.f;
#pragma unroll 8
    for (int k = 0; k < 128; k++) acc = fmaf(s[k], Ws[k * 128 + f], acc);
    solv[g * 128 + f] = fmaxf(acc + bs[f], 0.f);
}

__launch_bounds__(128)
__global__ void fc1_kernel(const float* __restrict__ pooled, const float* __restrict__ counts,
                           const float* __restrict__ solv, const float* __restrict__ Wf1,
                           const float* __restrict__ bf1, float* __restrict__ y) {
    __shared__ float z[384];
    int g = blockIdx.x, f = threadIdx.x;
    float inv = 1.0f / fmaxf(counts[g], 1.0f);
    z[f]       = pooled[g * 256 + f] * inv;
    z[128 + f] = pooled[g * 256 + 128 + f] * inv;
    z[256 + f] = solv[g * 128 + f];
    __syncthreads();
    float acc = 0.f;
#pragma unroll 8
    for (int k = 0; k < 384; k++) acc = fmaf(z[k], Wf1[k * 128 + f], acc);
    y[g * 128 + f] = acc + bf1[f];
}

__launch_bounds__(128)
__global__ void final_kernel(const float* __restrict__ y, const float* __restrict__ stf,
                             const float* __restrict__ gf, const float* __restrict__ bef,
                             const float* __restrict__ Wf2, const float* __restrict__ bf2,
                             float* __restrict__ out, float inv_n) {
    __shared__ float red[2];
    int g = blockIdx.x, f = threadIdx.x;
    float mean = stf[f] * inv_n;
    float var  = stf[128 + f] * inv_n - mean * mean;
    float sc   = gf[f] * rsqrtf(var + EPS);
    float sh   = bef[f] - mean * sc;
    float v = fmaxf(y[g * 128 + f] * sc + sh, 0.f) * Wf2[f];
#pragma unroll
    for (int off = 32; off > 0; off >>= 1) v += __shfl_down(v, off);
    if ((f & 63) == 0) red[f >> 6] = v;
    __syncthreads();
    if (f == 0) out[g] = red[0] + red[1] + bf2[0];
}

// ---------------------------------------------------------------- launch ----
extern "C" void kernel_launch(void* const* d_in, const int* in_sizes, int n_in,
                              void* d_out, int out_size, void* d_ws, size_t ws_size,
                              hipStream_t stream) {
    const float* x    = (const float*)d_in[0];
    const int*   ei   = (const int*)d_in[1];
    const int*   batch= (const int*)d_in[2];
    const float* sf   = (const float*)d_in[3];
    const float* W1   = (const float*)d_in[4];
    const float* b1   = (const float*)d_in[5];
    const float* g1   = (const float*)d_in[6];
    const float* be1  = (const float*)d_in[7];
    const float* W2   = (const float*)d_in[8];
    const float* b2   = (const float*)d_in[9];
    const float* g2   = (const float*)d_in[10];
    const float* be2  = (const float*)d_in[11];
    const float* Ws   = (const float*)d_in[12];
    const float* bs   = (const float*)d_in[13];
    const float* Wf1  = (const float*)d_in[14];
    const float* bf1  = (const float*)d_in[15];
    const float* gf1  = (const float*)d_in[16];
    const float* bef1 = (const float*)d_in[17];
    const float* Wf2  = (const float*)d_in[18];
    const float* bf2  = (const float*)d_in[19];
    float* out = (float*)d_out;

    const int n = in_sizes[0] / 64;    // 20000 nodes
    const int E = in_sizes[1] / 2;     // 320000 edges
    const int G = in_sizes[3] / 128;   // 512 graphs
    const int nb = (n + 255) / 256;    // scan blocks (79 <= 256)

    // workspace layout (floats):
    // a2 [0,256n)  (xa [0,64n) aliases its head; xa dead before GEMM2 writes a2)
    // h1a [256n,384n) | a1 [384n,512n) | pooled[G*256] | cnt_g[G] | st1[256] |
    // st2[512] | stf[256] | counts[n] | start[n+1] | cursor[n] | bsum[256] |
    // csr_row[E] | csr_nm[E] | solv[G*128] | yf[G*128]
    float* ws     = (float*)d_ws;
    float* a2     = ws;
    float* xa     = ws;                            // alias (dead before GEMM2)
    float* h1a    = ws + (size_t)n * 256;
    float* a1     = ws + (size_t)n * 384;
    float* pooled = ws + (size_t)n * 512;
    float* cnt_g  = pooled + (size_t)G * 256;
    float* st1    = cnt_g + G;
    float* st2    = st1 + 256;
    float* stf    = st2 + 512;
    int*   counts = (int*)(stf + 256);
    int*   start  = counts + n;
    int*   cursor = start + n + 1;
    int*   bsum   = cursor + n;
    int*   csr_row= bsum + 256;
    float* csr_nm = (float*)(csr_row + E);
    float* solv   = csr_nm + E;
    float* yf     = solv + (size_t)G * 128;

    // zero: pooled..stf (G*256+G+1024 floats) + counts (n ints) — contiguous
    size_t zero_floats = (size_t)G * 256 + G + 1024 + n;
    hipMemsetAsync(pooled, 0, zero_floats * sizeof(float), stream);

    const float inv_nn = 1.0f / (float)n;
    const float inv_gg = 1.0f / (float)G;

    // CSR build (edges sorted by destination); parallel 3-phase scan
    count_kernel<<<(E + 255) / 256, 256, 0, stream>>>(ei, counts, E);
    scan_partial_kernel<<<nb, 256, 0, stream>>>(counts, bsum, n);
    scan_offsets_kernel<<<1, 256, 0, stream>>>(bsum, start, nb, n);
    scan_write_kernel<<<nb, 256, 0, stream>>>(counts, bsum, start, cursor, n);
    fill_kernel<<<(E + 255) / 256, 256, 0, stream>>>(ei, counts, cursor, csr_row, csr_nm, E);

    // layer 1: xa = A_hat @ X  (gather on X, 64-wide, sliced 2x32)
    {
        constexpr int NPB = 256 / (64 / 2);
        int gps  = (n + NPB - 1) / NPB;
        int grid = ((gps + 3) / 4) * 8;
        gather_kernel<64, 2, false><<<grid, 256, 0, stream>>>(
            x, start, csr_row, csr_nm, counts, nullptr, nullptr, nullptr, 0.f, xa, n, gps);
    }
    // a1 = xa @ W1 + b1
    gemm_kernel<64, 128><<<dim3((n + 63) / 64, 1), 256, 0, stream>>>(xa, W1, b1, a1, n);
    stats_kernel<128><<<256, 256, 0, stream>>>(a1, n, st1);

    // layer 2: h1a = A_hat @ relu(BN1(a1))  (gather on a1, 128-wide, sliced 2x64, BN fused)
    {
        constexpr int NPB = 256 / (128 / 2);
        int gps  = (n + NPB - 1) / NPB;
        int grid = ((gps + 3) / 4) * 8;
        gather_kernel<128, 2, true><<<grid, 256, 0, stream>>>(
            a1, start, csr_row, csr_nm, counts, st1, g1, be1, inv_nn, h1a, n, gps);
    }
    // a2 = h1a @ W2 + b2
    gemm_kernel<128, 256><<<dim3((n + 63) / 64, 2), 256, 0, stream>>>(h1a, W2, b2, a2, n);
    stats_kernel<256><<<256, 256, 0, stream>>>(a2, n, st2);

    // pool with fused BN2+ReLU
    pool_kernel<<<(n + 31) / 32, 256, 0, stream>>>(a2, batch, st2, g2, be2, inv_nn,
                                                   pooled, cnt_g, n);

    // head
    solv_kernel<<<G, 128, 0, stream>>>(sf, Ws, bs, solv);
    fc1_kernel<<<G, 128, 0, stream>>>(pooled, cnt_g, solv, Wf1, bf1, yf);
    stats_kernel<128><<<8, 256, 0, stream>>>(yf, G, stf);
    final_kernel<<<G, 128, 0, stream>>>(yf, stf, gf1, bef1, Wf2, bf2, out, inv_gg);
}

// Round 5
// 208.556 us; speedup vs baseline: 2.6757x; 1.1431x over previous
//
#include <hip/hip_runtime.h>
#include <hip/hip_bf16.h>

#define EPS 1e-5f

// ------------------------------------------------------------------ zero ----
__global__ void zero_kernel(int* __restrict__ counts, float* __restrict__ st, int n) {
    int i = blockIdx.x * blockDim.x + threadIdx.x;
    if (i < n) counts[i] = 0;
    if (i < 1024) st[i] = 0.f;   // st1[256] | st2[512] | stf[256] contiguous
}

// ------------------------------------------------------------- CSR build ----
__global__ void count_kernel(const int* __restrict__ ei, int* __restrict__ counts, int E) {
    int e = blockIdx.x * blockDim.x + threadIdx.x;
    if (e < E) atomicAdd(&counts[ei[E + e]], 1);   // col = ei[1][e]
}

// phase 1: per-block (256-wide) sums of counts -> bsum[b]
__global__ void scan_partial_kernel(const int* __restrict__ counts, int* __restrict__ bsum, int n) {
    __shared__ int s[256];
    int t = threadIdx.x;
    int i = blockIdx.x * 256 + t;
    s[t] = (i < n) ? counts[i] : 0;
    __syncthreads();
#pragma unroll
    for (int off = 128; off > 0; off >>= 1) {
        if (t < off) s[t] += s[t + off];
        __syncthreads();
    }
    if (t == 0) bsum[blockIdx.x] = s[0];
}

// phase 2: single block; exclusive-scan bsum in place (nb <= 256); start[n] = total
__global__ void scan_offsets_kernel(int* __restrict__ bsum, int* __restrict__ start, int nb, int n) {
    __shared__ int s[256];
    int t = threadIdx.x;
    int v = (t < nb) ? bsum[t] : 0;
    s[t] = v;
    __syncthreads();
#pragma unroll
    for (int off = 1; off < 256; off <<= 1) {
        int x = (t >= off) ? s[t - off] : 0;
        __syncthreads();
        s[t] += x;
        __syncthreads();
    }
    if (t < nb) bsum[t] = s[t] - v;     // exclusive
    if (t == 255) start[n] = s[255];    // grand total
}

// phase 3: local exclusive scan + block offset -> start, cursor; also dis = rsqrt(deg)
__global__ void scan_write_kernel(const int* __restrict__ counts, const int* __restrict__ bsum,
                                  int* __restrict__ start, int* __restrict__ cursor,
                                  float* __restrict__ dis, int n) {
    __shared__ int s[256];
    int t = threadIdx.x;
    int i = blockIdx.x * 256 + t;
    int v = (i < n) ? counts[i] : 0;
    s[t] = v;
    __syncthreads();
#pragma unroll
    for (int off = 1; off < 256; off <<= 1) {
        int x = (t >= off) ? s[t - off] : 0;
        __syncthreads();
        s[t] += x;
        __syncthreads();
    }
    if (i < n) {
        int g = bsum[blockIdx.x] + s[t] - v;   // exclusive global prefix
        start[i]  = g;
        cursor[i] = g;
        dis[i]    = rsqrtf((float)v + 1.0f);   // deg = counts + self-loop
    }
}

__global__ void fill_kernel(const int* __restrict__ ei, int* __restrict__ cursor,
                            unsigned short* __restrict__ rows, int E) {
    int e = blockIdx.x * blockDim.x + threadIdx.x;
    if (e >= E) return;
    int r = ei[e];
    int c = ei[E + e];
    int pos = atomicAdd(&cursor[c], 1);
    rows[pos] = (unsigned short)r;
}

// ---------------------------------------------------------------- gather ----
// dst[i][f] = dis_i * ( T(src[i][f])*dis_i + sum_e T(src[row_e][f])*dis[row_e] )
// T = identity, or relu(BN(.)) when BN=true. Feature dim split into SLICES,
// pinned to XCD subsets via blockIdx%8 so each XCD's table slice is L2-resident.
template <int F, int SLICES, bool BN>
__launch_bounds__(256)
__global__ void gather_kernel(const float* __restrict__ src, const int* __restrict__ start,
                              const unsigned short* __restrict__ rows,
                              const float* __restrict__ dis,
                              const float* __restrict__ st, const float* __restrict__ gamma,
                              const float* __restrict__ beta, float inv_n,
                              float* __restrict__ dst, int n, int gps) {
    constexpr int W   = F / SLICES;   // lanes per node
    constexpr int NPB = 256 / W;      // nodes per block

    int bid = blockIdx.x;
    int xl  = bid & 7;
    int slice, group;
    if (SLICES == 4)      { slice = xl >> 1; group = (bid >> 3) * 2 + (xl & 1); }
    else if (SLICES == 2) { slice = xl >> 2; group = (bid >> 3) * 4 + (xl & 3); }
    else                  { slice = 0;       group = bid; }
    if (group >= gps) return;

    int local = threadIdx.x / W;
    int lane  = threadIdx.x % W;
    int node  = group * NPB + local;
    if (node >= n) return;
    int feat  = slice * W + lane;

    float sc = 1.f, sh = 0.f;
    if (BN) {
        float mean = st[feat] * inv_n;
        float var  = st[F + feat] * inv_n - mean * mean;
        sc = gamma[feat] * rsqrtf(var + EPS);
        sh = beta[feat] - mean * sc;
    }
#define T(v) (BN ? fmaxf(fmaf((v), sc, sh), 0.f) : (v))

    float di   = dis[node];
    float acc  = T(src[(size_t)node * F + feat]) * di;
    float acc2 = 0.f;
    int e  = start[node];
    int e1 = start[node + 1];
    for (; e + 1 < e1; e += 2) {
        int   r0 = rows[e], r1 = rows[e + 1];
        float w0 = dis[r0], w1 = dis[r1];
        float v0 = T(src[(size_t)r0 * F + feat]);
        float v1 = T(src[(size_t)r1 * F + feat]);
        acc  = fmaf(v0, w0, acc);
        acc2 = fmaf(v1, w1, acc2);
    }
    if (e < e1) {
        int r0 = rows[e];
        acc = fmaf(T(src[(size_t)r0 * F + feat]), dis[r0], acc);
    }
    dst[(size_t)node * F + feat] = (acc + acc2) * di;
#undef T
}

// ------------------------------------------------------------------ GEMM ----
// C[M, NTOT] = A[M, K] @ B[K, NTOT] + bias[NTOT]; optionally accumulate
// per-column sum/sumsq of C into st[0..NTOT) / st[NTOT..2*NTOT) (atomic).
template <int K, int NTOT, bool STATS>
__launch_bounds__(256)
__global__ void gemm_kernel(const float* __restrict__ A, const float* __restrict__ B,
                            const float* __restrict__ bias, float* __restrict__ C,
                            float* __restrict__ st, int M) {
    constexpr int BM = 64, BN = 128, BK = 32;
    __shared__ float As[BK][BM + 1];   // 2080 floats
    __shared__ float Bs[BK][BN];       // 4096 floats

    const int t = threadIdx.x;
    const int row0 = blockIdx.x * BM;
    const int col0 = blockIdx.y * BN;

    float acc[4][8] = {};
    const int ty = t >> 4;
    const int tx = t & 15;

    for (int kk = 0; kk < K; kk += BK) {
#pragma unroll
        for (int p = 0; p < 2; p++) {
            int r    = (t >> 3) + p * 32;
            int c4   = (t & 7) * 4;
            int grow = row0 + r;
            float4 v = make_float4(0.f, 0.f, 0.f, 0.f);
            if (grow < M) v = *(const float4*)&A[(size_t)grow * K + kk + c4];
            As[c4 + 0][r] = v.x;
            As[c4 + 1][r] = v.y;
            As[c4 + 2][r] = v.z;
            As[c4 + 3][r] = v.w;
        }
#pragma unroll
        for (int p = 0; p < 4; p++) {
            int kr = (t >> 5) + p * 8;
            int n4 = (t & 31) * 4;
            *(float4*)&Bs[kr][n4] = *(const float4*)&B[(size_t)(kk + kr) * NTOT + col0 + n4];
        }
        __syncthreads();

#pragma unroll
        for (int k = 0; k < BK; k++) {
            float a[4], b[8];
#pragma unroll
            for (int i = 0; i < 4; i++) a[i] = As[k][ty * 4 + i];
#pragma unroll
            for (int j = 0; j < 8; j++) b[j] = Bs[k][tx + j * 16];
#pragma unroll
            for (int i = 0; i < 4; i++)
#pragma unroll
                for (int j = 0; j < 8; j++) acc[i][j] = fmaf(a[i], b[j], acc[i][j]);
        }
        __syncthreads();
    }

    float s1[8], s2[8];
#pragma unroll
    for (int j = 0; j < 8; j++) { s1[j] = 0.f; s2[j] = 0.f; }
#pragma unroll
    for (int i = 0; i < 4; i++) {
        int grow = row0 + ty * 4 + i;
        if (grow < M) {
#pragma unroll
            for (int j = 0; j < 8; j++) {
                int col = col0 + tx + j * 16;
                float v = acc[i][j] + bias[col];
                C[(size_t)grow * NTOT + col] = v;
                if (STATS) { s1[j] += v; s2[j] += v * v; }
            }
        }
    }
    if (STATS) {
        // k-loop ended with a barrier; As/Bs are free for reuse
        float* red1 = &As[0][0];   // need 16*128 = 2048 <= 2080
        float* red2 = &Bs[0][0];   // 2048 <= 4096
#pragma unroll
        for (int j = 0; j < 8; j++) {
            red1[ty * 128 + tx + j * 16] = s1[j];
            red2[ty * 128 + tx + j * 16] = s2[j];
        }
        __syncthreads();
        if (t < 128) {
            float a = 0.f, b = 0.f;
#pragma unroll
            for (int r = 0; r < 16; r++) {
                a += red1[r * 128 + t];
                b += red2[r * 128 + t];
            }
            atomicAdd(&st[col0 + t], a);
            atomicAdd(&st[NTOT + col0 + t], b);
        }
    }
}

// ----------------------------------------------------------------- stats ----
template <int F>
__launch_bounds__(256)
__global__ void stats_kernel(const float* __restrict__ h, int n, float* __restrict__ out) {
    constexpr int R = 256 / F;
    __shared__ float red[512];
    int t  = threadIdx.x;
    int f  = t % F;
    int rs = t / F;
    float s = 0.f, s2 = 0.f;
    int rows = (n + gridDim.x - 1) / gridDim.x;
    int i0 = blockIdx.x * rows;
    int i1 = min(i0 + rows, n);
    for (int i = i0 + rs; i < i1; i += R) {
        float v = h[(size_t)i * F + f];
        s  += v;
        s2 += v * v;
    }
    if (R == 2) {
        red[t]       = s;
        red[256 + t] = s2;
        __syncthreads();
        if (t < F) {
            s  += red[t + F];
            s2 += red[256 + t + F];
        }
    }
    if (t < F) {
        atomicAdd(&out[f], s);
        atomicAdd(&out[F + f], s2);
    }
}

// -------------------------------------------------------------- segments ----
// seg[g] = first index i with batch[i] >= g (batch sorted); seg[G] = n
__global__ void seg_kernel(const int* __restrict__ batch, int* __restrict__ seg, int n, int G) {
    int g = blockIdx.x * blockDim.x + threadIdx.x;
    if (g > G) return;
    if (g == G) { seg[G] = n; return; }
    int lo = 0, hi = n;
    while (lo < hi) {
        int mid = (lo + hi) >> 1;
        if (batch[mid] < g) lo = mid + 1; else hi = mid;
    }
    seg[g] = lo;
}

// ------------------------------------------------------------------ pool ----
// pooled[g][f] = mean over nodes in segment g of relu(BN2(a2)); no atomics.
__launch_bounds__(256)
__global__ void pool_kernel(const float* __restrict__ a2, const int* __restrict__ seg,
                            const float* __restrict__ st2, const float* __restrict__ g2,
                            const float* __restrict__ be2, float inv_n,
                            float* __restrict__ pooled) {
    int g = blockIdx.x, f = threadIdx.x;
    float mean = st2[f] * inv_n;
    float var  = st2[256 + f] * inv_n - mean * mean;
    float sc   = g2[f] * rsqrtf(var + EPS);
    float sh   = be2[f] - mean * sc;
    int i0 = seg[g], i1 = seg[g + 1];
    float acc = 0.f, accB = 0.f;
    int i = i0;
    for (; i + 1 < i1; i += 2) {
        acc  += fmaxf(fmaf(a2[(size_t)i * 256 + f], sc, sh), 0.f);
        accB += fmaxf(fmaf(a2[(size_t)(i + 1) * 256 + f], sc, sh), 0.f);
    }
    if (i < i1) acc += fmaxf(fmaf(a2[(size_t)i * 256 + f], sc, sh), 0.f);
    pooled[(size_t)g * 256 + f] = (acc + accB) / fmaxf((float)(i1 - i0), 1.f);
}

// -------------------------------------------------------------- small FC ----
// fc1 with fused solvent FC: z = [pooled_mean(256) | relu(sf@Ws+bs)(128)] @ Wf1 + bf1
__launch_bounds__(128)
__global__ void fc1_kernel(const float* __restrict__ pooled, const float* __restrict__ sf,
                           const float* __restrict__ Ws, const float* __restrict__ bs,
                           const float* __restrict__ Wf1, const float* __restrict__ bf1,
                           float* __restrict__ y) {
    __shared__ float z[384];
    __shared__ float s[128];
    int g = blockIdx.x, f = threadIdx.x;
    s[f]       = sf[g * 128 + f];
    z[f]       = pooled[g * 256 + f];
    z[128 + f] = pooled[g * 256 + 128 + f];
    __syncthreads();
    float a = 0.f;
#pragma unroll 8
    for (int k = 0; k < 128; k++) a = fmaf(s[k], Ws[k * 128 + f], a);
    z[256 + f] = fmaxf(a + bs[f], 0.f);
    __syncthreads();
    float acc = 0.f;
#pragma unroll 8
    for (int k = 0; k < 384; k++) acc = fmaf(z[k], Wf1[k * 128 + f], acc);
    y[g * 128 + f] = acc + bf1[f];
}

__launch_bounds__(128)
__global__ void final_kernel(const float* __restrict__ y, const float* __restrict__ stf,
                             const float* __restrict__ gf, const float* __restrict__ bef,
                             const float* __restrict__ Wf2, const float* __restrict__ bf2,
                             float* __restrict__ out, float inv_n) {
    __shared__ float red[2];
    int g = blockIdx.x, f = threadIdx.x;
    float mean = stf[f] * inv_n;
    float var  = stf[128 + f] * inv_n - mean * mean;
    float sc   = gf[f] * rsqrtf(var + EPS);
    float sh   = bef[f] - mean * sc;
    float v = fmaxf(y[g * 128 + f] * sc + sh, 0.f) * Wf2[f];
#pragma unroll
    for (int off = 32; off > 0; off >>= 1) v += __shfl_down(v, off);
    if ((f & 63) == 0) red[f >> 6] = v;
    __syncthreads();
    if (f == 0) out[g] = red[0] + red[1] + bf2[0];
}

// ---------------------------------------------------------------- launch ----
extern "C" void kernel_launch(void* const* d_in, const int* in_sizes, int n_in,
                              void* d_out, int out_size, void* d_ws, size_t ws_size,
                              hipStream_t stream) {
    const float* x    = (const float*)d_in[0];
    const int*   ei   = (const int*)d_in[1];
    const int*   batch= (const int*)d_in[2];
    const float* sf   = (const float*)d_in[3];
    const float* W1   = (const float*)d_in[4];
    const float* b1   = (const float*)d_in[5];
    const float* g1   = (const float*)d_in[6];
    const float* be1  = (const float*)d_in[7];
    const float* W2   = (const float*)d_in[8];
    const float* b2   = (const float*)d_in[9];
    const float* g2   = (const float*)d_in[10];
    const float* be2  = (const float*)d_in[11];
    const float* Ws   = (const float*)d_in[12];
    const float* bs   = (const float*)d_in[13];
    const float* Wf1  = (const float*)d_in[14];
    const float* bf1  = (const float*)d_in[15];
    const float* gf1  = (const float*)d_in[16];
    const float* bef1 = (const float*)d_in[17];
    const float* Wf2  = (const float*)d_in[18];
    const float* bf2  = (const float*)d_in[19];
    float* out = (float*)d_out;

    const int n = in_sizes[0] / 64;    // 20000 nodes
    const int E = in_sizes[1] / 2;     // 320000 edges
    const int G = in_sizes[3] / 128;   // 512 graphs
    const int nb = (n + 255) / 256;    // scan blocks (<= 256)

    // workspace layout (floats):
    // a2 [0,256n)  (xa [0,64n) aliases; dead before GEMM2 writes a2)
    // h1a [256n,384n) | a1 [384n,512n) | pooled[G*256] | st1[256] st2[512] stf[256]
    // | counts[n] | start[n+1] | cursor[n] | bsum[256] | seg[G+1] | dis[n]
    // | rows[E u16] | yf[G*128]
    float* ws     = (float*)d_ws;
    float* a2     = ws;
    float* xa     = ws;                            // alias (dead before GEMM2)
    float* h1a    = ws + (size_t)n * 256;
    float* a1     = ws + (size_t)n * 384;
    float* pooled = ws + (size_t)n * 512;
    float* st1    = pooled + (size_t)G * 256;
    float* st2    = st1 + 256;
    float* stf    = st2 + 512;
    int*   counts = (int*)(stf + 256);
    int*   start  = counts + n;
    int*   cursor = start + n + 1;
    int*   bsum   = cursor + n;
    int*   seg    = bsum + 256;
    float* dis    = (float*)(seg + G + 1);
    unsigned short* rows = (unsigned short*)(dis + n);
    float* yf     = (float*)(rows + ((E + 1) & ~1));   // 4B-aligned

    const float inv_nn = 1.0f / (float)n;
    const float inv_gg = 1.0f / (float)G;

    // zero counts + stats accumulators (st1|st2|stf = 1024 floats at st1)
    zero_kernel<<<nb, 256, 0, stream>>>(counts, st1, n);
    seg_kernel<<<(G + 256) / 256, 256, 0, stream>>>(batch, seg, n, G);

    // CSR build (edges sorted by destination)
    count_kernel<<<(E + 255) / 256, 256, 0, stream>>>(ei, counts, E);
    scan_partial_kernel<<<nb, 256, 0, stream>>>(counts, bsum, n);
    scan_offsets_kernel<<<1, 256, 0, stream>>>(bsum, start, nb, n);
    scan_write_kernel<<<nb, 256, 0, stream>>>(counts, bsum, start, cursor, dis, n);
    fill_kernel<<<(E + 255) / 256, 256, 0, stream>>>(ei, cursor, rows, E);

    // layer 1: xa = A_hat @ X  (gather on X, 2 slices x 32 feats)
    {
        constexpr int NPB = 8;                     // 256 / 32
        int gps  = (n + NPB - 1) / NPB;
        int grid = ((gps + 3) / 4) * 8;
        gather_kernel<64, 2, false><<<grid, 256, 0, stream>>>(
            x, start, rows, dis, nullptr, nullptr, nullptr, 0.f, xa, n, gps);
    }
    // a1 = xa @ W1 + b1, fused BN1 stats -> st1
    gemm_kernel<64, 128, true><<<dim3((n + 63) / 64, 1), 256, 0, stream>>>(
        xa, W1, b1, a1, st1, n);

    // layer 2: h1a = A_hat @ relu(BN1(a1))  (gather on a1, 4 slices x 32 feats)
    {
        constexpr int NPB = 8;                     // 256 / 32
        int gps  = (n + NPB - 1) / NPB;
        int grid = ((gps + 1) / 2) * 8;
        gather_kernel<128, 4, true><<<grid, 256, 0, stream>>>(
            a1, start, rows, dis, st1, g1, be1, inv_nn, h1a, n, gps);
    }
    // a2 = h1a @ W2 + b2, fused BN2 stats -> st2
    gemm_kernel<128, 256, true><<<dim3((n + 63) / 64, 2), 256, 0, stream>>>(
        h1a, W2, b2, a2, st2, n);

    // pool with fused BN2+ReLU (segment ranges, writes means, no atomics)
    pool_kernel<<<G, 256, 0, stream>>>(a2, seg, st2, g2, be2, inv_nn, pooled);

    // head: fc1 (fused solvent FC) -> BN stats -> final
    fc1_kernel<<<G, 128, 0, stream>>>(pooled, sf, Ws, bs, Wf1, bf1, yf);
    stats_kernel<128><<<8, 256, 0, stream>>>(yf, G, stf);
    final_kernel<<<G, 128, 0, stream>>>(yf, stf, gf1, bef1, Wf2, bf2, out, inv_gg);
}

// Round 7
// 172.882 us; speedup vs baseline: 3.2278x; 1.2063x over previous
//
#include <hip/hip_runtime.h>
#include <hip/hip_bf16.h>
#include <hip/hip_fp16.h>

#define EPS 1e-5f

// ------------------------------------------------------- zero + segments ----
// zeroes counts[n] and st[1024]; computes seg[g] via binary search (batch sorted)
__global__ void zero_seg_kernel(int* __restrict__ counts, float* __restrict__ st,
                                const int* __restrict__ batch, int* __restrict__ seg,
                                int n, int G) {
    int i = blockIdx.x * blockDim.x + threadIdx.x;
    if (i < n) counts[i] = 0;
    if (i < 1024) st[i] = 0.f;   // st1[256] | st2[512] | stf[256] contiguous
    if (i <= G) {
        if (i == G) { seg[G] = n; }
        else {
            int lo = 0, hi = n;
            while (lo < hi) {
                int mid = (lo + hi) >> 1;
                if (batch[mid] < i) lo = mid + 1; else hi = mid;
            }
            seg[i] = lo;
        }
    }
}

// ------------------------------------------------------------- CSR build ----
__global__ void count_kernel(const int* __restrict__ ei, int* __restrict__ counts, int E) {
    int e = blockIdx.x * blockDim.x + threadIdx.x;
    if (e < E) atomicAdd(&counts[ei[E + e]], 1);   // col = ei[1][e]
}

// phase 1: per-block (256-wide) sums of counts -> bsum[b]
__global__ void scan_partial_kernel(const int* __restrict__ counts, int* __restrict__ bsum, int n) {
    __shared__ int s[256];
    int t = threadIdx.x;
    int i = blockIdx.x * 256 + t;
    s[t] = (i < n) ? counts[i] : 0;
    __syncthreads();
#pragma unroll
    for (int off = 128; off > 0; off >>= 1) {
        if (t < off) s[t] += s[t + off];
        __syncthreads();
    }
    if (t == 0) bsum[blockIdx.x] = s[0];
}

// phase 2: single block; exclusive-scan bsum in place (nb <= 256); start[n] = total
__global__ void scan_offsets_kernel(int* __restrict__ bsum, int* __restrict__ start, int nb, int n) {
    __shared__ int s[256];
    int t = threadIdx.x;
    int v = (t < nb) ? bsum[t] : 0;
    s[t] = v;
    __syncthreads();
#pragma unroll
    for (int off = 1; off < 256; off <<= 1) {
        int x = (t >= off) ? s[t - off] : 0;
        __syncthreads();
        s[t] += x;
        __syncthreads();
    }
    if (t < nb) bsum[t] = s[t] - v;     // exclusive
    if (t == 255) start[n] = s[255];    // grand total
}

// phase 3: local exclusive scan + block offset -> start, cursor; dis = rsqrt(deg)
__global__ void scan_write_kernel(const int* __restrict__ counts, const int* __restrict__ bsum,
                                  int* __restrict__ start, int* __restrict__ cursor,
                                  float* __restrict__ dis, int n) {
    __shared__ int s[256];
    int t = threadIdx.x;
    int i = blockIdx.x * 256 + t;
    int v = (i < n) ? counts[i] : 0;
    s[t] = v;
    __syncthreads();
#pragma unroll
    for (int off = 1; off < 256; off <<= 1) {
        int x = (t >= off) ? s[t - off] : 0;
        __syncthreads();
        s[t] += x;
        __syncthreads();
    }
    if (i < n) {
        int g = bsum[blockIdx.x] + s[t] - v;   // exclusive global prefix
        start[i]  = g;
        cursor[i] = g;
        dis[i]    = rsqrtf((float)v + 1.0f);   // deg = counts + self-loop
    }
}

// packed edge record: low 16 = source row (n < 65536), high 16 = f16(dis[row])
__global__ void fill_kernel(const int* __restrict__ ei, int* __restrict__ cursor,
                            const float* __restrict__ dis, unsigned int* __restrict__ recs,
                            int E) {
    int e = blockIdx.x * blockDim.x + threadIdx.x;
    if (e >= E) return;
    int r = ei[e];
    int c = ei[E + e];
    int pos = atomicAdd(&cursor[c], 1);
    unsigned int hw = __half_as_ushort(__float2half_rn(dis[r]));
    recs[pos] = (hw << 16) | (unsigned int)r;
}

// ---------------------------------------------------------------- gather ----
__device__ inline void fma4(float4& d, const float4& v, float wgt) {
    d.x = fmaf(v.x, wgt, d.x);
    d.y = fmaf(v.y, wgt, d.y);
    d.z = fmaf(v.z, wgt, d.z);
    d.w = fmaf(v.w, wgt, d.w);
}

__device__ inline void bnrelu4(float4& v, const float4& sc, const float4& sh) {
    v.x = fmaxf(fmaf(v.x, sc.x, sh.x), 0.f);
    v.y = fmaxf(fmaf(v.y, sc.y, sh.y), 0.f);
    v.z = fmaxf(fmaf(v.z, sc.z, sh.z), 0.f);
    v.w = fmaxf(fmaf(v.w, sc.w, sh.w), 0.f);
}

// dst[i][:] = dis_i * ( T(src[i][:])*dis_i + sum_e T(src[row_e][:])*dis[row_e] )
// T = identity, or relu(BN(.)) when BN=true. Each lane owns 4 consecutive feats
// (float4). Feature dim split into SLICES, pinned to XCD subsets via blockIdx%8.
template <int F, int SLICES, bool BN>
__launch_bounds__(256)
__global__ void gather_kernel(const float* __restrict__ src, const int* __restrict__ start,
                              const unsigned int* __restrict__ recs,
                              const float* __restrict__ dis,
                              const float* __restrict__ st, const float* __restrict__ gamma,
                              const float* __restrict__ beta, float inv_n,
                              float* __restrict__ dst, int n, int gps) {
    constexpr int F4  = F / 4;        // float4s per node row
    constexpr int W4  = F4 / SLICES;  // lanes per node (each lane: 4 feats)
    constexpr int NPB = 256 / W4;     // nodes per block

    int bid = blockIdx.x;
    int xl  = bid & 7;
    int slice, group;
    if (SLICES == 4)      { slice = xl >> 1; group = (bid >> 3) * 2 + (xl & 1); }
    else if (SLICES == 2) { slice = xl >> 2; group = (bid >> 3) * 4 + (xl & 3); }
    else                  { slice = 0;       group = bid; }
    if (group >= gps) return;

    int local = threadIdx.x / W4;
    int lane  = threadIdx.x % W4;
    int node  = group * NPB + local;
    if (node >= n) return;
    int f4    = slice * W4 + lane;    // float4 index within row
    int feat0 = f4 * 4;

    float4 sc = make_float4(1.f, 1.f, 1.f, 1.f);
    float4 sh = make_float4(0.f, 0.f, 0.f, 0.f);
    if (BN) {
        float m0 = st[feat0 + 0] * inv_n, m1 = st[feat0 + 1] * inv_n;
        float m2 = st[feat0 + 2] * inv_n, m3 = st[feat0 + 3] * inv_n;
        sc.x = gamma[feat0 + 0] * rsqrtf(st[F + feat0 + 0] * inv_n - m0 * m0 + EPS);
        sc.y = gamma[feat0 + 1] * rsqrtf(st[F + feat0 + 1] * inv_n - m1 * m1 + EPS);
        sc.z = gamma[feat0 + 2] * rsqrtf(st[F + feat0 + 2] * inv_n - m2 * m2 + EPS);
        sc.w = gamma[feat0 + 3] * rsqrtf(st[F + feat0 + 3] * inv_n - m3 * m3 + EPS);
        sh.x = beta[feat0 + 0] - m0 * sc.x;
        sh.y = beta[feat0 + 1] - m1 * sc.y;
        sh.z = beta[feat0 + 2] - m2 * sc.z;
        sh.w = beta[feat0 + 3] - m3 * sc.w;
    }

    const float4* src4 = (const float4*)src;

    float di = dis[node];
    float4 self = src4[(size_t)node * F4 + f4];
    if (BN) bnrelu4(self, sc, sh);
    float4 acc  = make_float4(self.x * di, self.y * di, self.z * di, self.w * di);
    float4 acc2 = make_float4(0.f, 0.f, 0.f, 0.f);

    int e  = start[node];
    int e1 = start[node + 1];
    for (; e + 3 < e1; e += 4) {
        unsigned int q0 = recs[e],     q1 = recs[e + 1];
        unsigned int q2 = recs[e + 2], q3 = recs[e + 3];
        int r0 = q0 & 0xFFFF, r1 = q1 & 0xFFFF, r2 = q2 & 0xFFFF, r3 = q3 & 0xFFFF;
        float w0 = __half2float(__ushort_as_half((unsigned short)(q0 >> 16)));
        float w1 = __half2float(__ushort_as_half((unsigned short)(q1 >> 16)));
        float w2 = __half2float(__ushort_as_half((unsigned short)(q2 >> 16)));
        float w3 = __half2float(__ushort_as_half((unsigned short)(q3 >> 16)));
        float4 v0 = src4[(size_t)r0 * F4 + f4];
        float4 v1 = src4[(size_t)r1 * F4 + f4];
        float4 v2 = src4[(size_t)r2 * F4 + f4];
        float4 v3 = src4[(size_t)r3 * F4 + f4];
        if (BN) { bnrelu4(v0, sc, sh); bnrelu4(v1, sc, sh); bnrelu4(v2, sc, sh); bnrelu4(v3, sc, sh); }
        fma4(acc, v0, w0);
        fma4(acc2, v1, w1);
        fma4(acc, v2, w2);
        fma4(acc2, v3, w3);
    }
    for (; e < e1; e++) {
        unsigned int q0 = recs[e];
        int r0 = q0 & 0xFFFF;
        float w0 = __half2float(__ushort_as_half((unsigned short)(q0 >> 16)));
        float4 v0 = src4[(size_t)r0 * F4 + f4];
        if (BN) bnrelu4(v0, sc, sh);
        fma4(acc, v0, w0);
    }
    float4 o;
    o.x = (acc.x + acc2.x) * di;
    o.y = (acc.y + acc2.y) * di;
    o.z = (acc.z + acc2.z) * di;
    o.w = (acc.w + acc2.w) * di;
    ((float4*)dst)[(size_t)node * F4 + f4] = o;
}

// ------------------------------------------------------------------ GEMM ----
// C[M, NTOT] = A[M, K] @ B[K, NTOT] + bias[NTOT]; optionally accumulate
// per-column sum/sumsq of C into st[0..NTOT) / st[NTOT..2*NTOT) (atomic).
template <int K, int NTOT, bool STATS>
__launch_bounds__(256)
__global__ void gemm_kernel(const float* __restrict__ A, const float* __restrict__ B,
                            const float* __restrict__ bias, float* __restrict__ C,
                            float* __restrict__ st, int M) {
    constexpr int BM = 64, BN = 128, BK = 32;
    __shared__ float As[BK][BM + 1];   // 2080 floats
    __shared__ float Bs[BK][BN];       // 4096 floats

    const int t = threadIdx.x;
    const int row0 = blockIdx.x * BM;
    const int col0 = blockIdx.y * BN;

    float acc[4][8] = {};
    const int ty = t >> 4;
    const int tx = t & 15;

    for (int kk = 0; kk < K; kk += BK) {
#pragma unroll
        for (int p = 0; p < 2; p++) {
            int r    = (t >> 3) + p * 32;
            int c4   = (t & 7) * 4;
            int grow = row0 + r;
            float4 v = make_float4(0.f, 0.f, 0.f, 0.f);
            if (grow < M) v = *(const float4*)&A[(size_t)grow * K + kk + c4];
            As[c4 + 0][r] = v.x;
            As[c4 + 1][r] = v.y;
            As[c4 + 2][r] = v.z;
            As[c4 + 3][r] = v.w;
        }
#pragma unroll
        for (int p = 0; p < 4; p++) {
            int kr = (t >> 5) + p * 8;
            int n4 = (t & 31) * 4;
            *(float4*)&Bs[kr][n4] = *(const float4*)&B[(size_t)(kk + kr) * NTOT + col0 + n4];
        }
        __syncthreads();

#pragma unroll
        for (int k = 0; k < BK; k++) {
            float a[4], b[8];
#pragma unroll
            for (int i = 0; i < 4; i++) a[i] = As[k][ty * 4 + i];
#pragma unroll
            for (int j = 0; j < 8; j++) b[j] = Bs[k][tx + j * 16];
#pragma unroll
            for (int i = 0; i < 4; i++)
#pragma unroll
                for (int j = 0; j < 8; j++) acc[i][j] = fmaf(a[i], b[j], acc[i][j]);
        }
        __syncthreads();
    }

    float s1[8], s2[8];
#pragma unroll
    for (int j = 0; j < 8; j++) { s1[j] = 0.f; s2[j] = 0.f; }
#pragma unroll
    for (int i = 0; i < 4; i++) {
        int grow = row0 + ty * 4 + i;
        if (grow < M) {
#pragma unroll
            for (int j = 0; j < 8; j++) {
                int col = col0 + tx + j * 16;
                float v = acc[i][j] + bias[col];
                C[(size_t)grow * NTOT + col] = v;
                if (STATS) { s1[j] += v; s2[j] += v * v; }
            }
        }
    }
    if (STATS) {
        float* red1 = &As[0][0];   // 2048 <= 2080
        float* red2 = &Bs[0][0];   // 2048 <= 4096
#pragma unroll
        for (int j = 0; j < 8; j++) {
            red1[ty * 128 + tx + j * 16] = s1[j];
            red2[ty * 128 + tx + j * 16] = s2[j];
        }
        __syncthreads();
        if (t < 128) {
            float a = 0.f, b = 0.f;
#pragma unroll
            for (int r = 0; r < 16; r++) {
                a += red1[r * 128 + t];
                b += red2[r * 128 + t];
            }
            atomicAdd(&st[col0 + t], a);
            atomicAdd(&st[NTOT + col0 + t], b);
        }
    }
}

// ----------------------------------------------------------------- stats ----
template <int F>
__launch_bounds__(256)
__global__ void stats_kernel(const float* __restrict__ h, int n, float* __restrict__ out) {
    constexpr int R = 256 / F;
    __shared__ float red[512];
    int t  = threadIdx.x;
    int f  = t % F;
    int rs = t / F;
    float s = 0.f, s2 = 0.f;
    int rows = (n + gridDim.x - 1) / gridDim.x;
    int i0 = blockIdx.x * rows;
    int i1 = min(i0 + rows, n);
    for (int i = i0 + rs; i < i1; i += R) {
        float v = h[(size_t)i * F + f];
        s  += v;
        s2 += v * v;
    }
    if (R == 2) {
        red[t]       = s;
        red[256 + t] = s2;
        __syncthreads();
        if (t < F) {
            s  += red[t + F];
            s2 += red[256 + t + F];
        }
    }
    if (t < F) {
        atomicAdd(&out[f], s);
        atomicAdd(&out[F + f], s2);
    }
}

// ------------------------------------------------------------------ pool ----
// pooled[g][f] = mean over nodes in segment g of relu(BN2(a2)); no atomics.
__launch_bounds__(256)
__global__ void pool_kernel(const float* __restrict__ a2, const int* __restrict__ seg,
                            const float* __restrict__ st2, const float* __restrict__ g2,
                            const float* __restrict__ be2, float inv_n,
                            float* __restrict__ pooled) {
    int g = blockIdx.x, f = threadIdx.x;
    float mean = st2[f] * inv_n;
    float var  = st2[256 + f] * inv_n - mean * mean;
    float sc   = g2[f] * rsqrtf(var + EPS);
    float sh   = be2[f] - mean * sc;
    int i0 = seg[g], i1 = seg[g + 1];
    float acc = 0.f, accB = 0.f;
    int i = i0;
    for (; i + 1 < i1; i += 2) {
        acc  += fmaxf(fmaf(a2[(size_t)i * 256 + f], sc, sh), 0.f);
        accB += fmaxf(fmaf(a2[(size_t)(i + 1) * 256 + f], sc, sh), 0.f);
    }
    if (i < i1) acc += fmaxf(fmaf(a2[(size_t)i * 256 + f], sc, sh), 0.f);
    pooled[(size_t)g * 256 + f] = (acc + accB) / fmaxf((float)(i1 - i0), 1.f);
}

// -------------------------------------------------------------- small FC ----
// fc1 with fused solvent FC: z = [pooled_mean(256) | relu(sf@Ws+bs)(128)] @ Wf1 + bf1
__launch_bounds__(128)
__global__ void fc1_kernel(const float* __restrict__ pooled, const float* __restrict__ sf,
                           const float* __restrict__ Ws, const float* __restrict__ bs,
                           const float* __restrict__ Wf1, const float* __restrict__ bf1,
                           float* __restrict__ y) {
    __shared__ float z[384];
    __shared__ float s[128];
    int g = blockIdx.x, f = threadIdx.x;
    s[f]       = sf[g * 128 + f];
    z[f]       = pooled[g * 256 + f];
    z[128 + f] = pooled[g * 256 + 128 + f];
    __syncthreads();
    float a = 0.f;
#pragma unroll 8
    for (int k = 0; k < 128; k++) a = fmaf(s[k], Ws[k * 128 + f], a);
    z[256 + f] = fmaxf(a + bs[f], 0.f);
    __syncthreads();
    float acc = 0.f;
#pragma unroll 8
    for (int k = 0; k < 384; k++) acc = fmaf(z[k], Wf1[k * 128 + f], acc);
    y[g * 128 + f] = acc + bf1[f];
}

__launch_bounds__(128)
__global__ void final_kernel(const float* __restrict__ y, const float* __restrict__ stf,
                             const float* __restrict__ gf, const float* __restrict__ bef,
                             const float* __restrict__ Wf2, const float* __restrict__ bf2,
                             float* __restrict__ out, float inv_n) {
    __shared__ float red[2];
    int g = blockIdx.x, f = threadIdx.x;
    float mean = stf[f] * inv_n;
    float var  = stf[128 + f] * inv_n - mean * mean;
    float sc   = gf[f] * rsqrtf(var + EPS);
    float sh   = bef[f] - mean * sc;
    float v = fmaxf(y[g * 128 + f] * sc + sh, 0.f) * Wf2[f];
#pragma unroll
    for (int off = 32; off > 0; off >>= 1) v += __shfl_down(v, off);
    if ((f & 63) == 0) red[f >> 6] = v;
    __syncthreads();
    if (f == 0) out[g] = red[0] + red[1] + bf2[0];
}

// ---------------------------------------------------------------- launch ----
extern "C" void kernel_launch(void* const* d_in, const int* in_sizes, int n_in,
                              void* d_out, int out_size, void* d_ws, size_t ws_size,
                              hipStream_t stream) {
    const float* x    = (const float*)d_in[0];
    const int*   ei   = (const int*)d_in[1];
    const int*   batch= (const int*)d_in[2];
    const float* sf   = (const float*)d_in[3];
    const float* W1   = (const float*)d_in[4];
    const float* b1   = (const float*)d_in[5];
    const float* g1   = (const float*)d_in[6];
    const float* be1  = (const float*)d_in[7];
    const float* W2   = (const float*)d_in[8];
    const float* b2   = (const float*)d_in[9];
    const float* g2   = (const float*)d_in[10];
    const float* be2  = (const float*)d_in[11];
    const float* Ws   = (const float*)d_in[12];
    const float* bs   = (const float*)d_in[13];
    const float* Wf1  = (const float*)d_in[14];
    const float* bf1  = (const float*)d_in[15];
    const float* gf1  = (const float*)d_in[16];
    const float* bef1 = (const float*)d_in[17];
    const float* Wf2  = (const float*)d_in[18];
    const float* bf2  = (const float*)d_in[19];
    float* out = (float*)d_out;

    const int n = in_sizes[0] / 64;    // 20000 nodes
    const int E = in_sizes[1] / 2;     // 320000 edges
    const int G = in_sizes[3] / 128;   // 512 graphs
    const int nb = (n + 255) / 256;    // scan blocks (<= 256)

    // workspace layout (floats):
    // a2 [0,256n)  (xa [0,64n) aliases; dead before GEMM2 writes a2)
    // h1a [256n,384n) | a1 [384n,512n) | pooled[G*256] | st1[256] st2[512] stf[256]
    // | counts[n] | start[n+1] | cursor[n] | bsum[256] | seg[G+1] | dis[n]
    // | recs[E u32] | yf[G*128]
    float* ws     = (float*)d_ws;
    float* a2     = ws;
    float* xa     = ws;                            // alias (dead before GEMM2)
    float* h1a    = ws + (size_t)n * 256;
    float* a1     = ws + (size_t)n * 384;
    float* pooled = ws + (size_t)n * 512;
    float* st1    = pooled + (size_t)G * 256;
    float* st2    = st1 + 256;
    float* stf    = st2 + 512;
    int*   counts = (int*)(stf + 256);
    int*   start  = counts + n;
    int*   cursor = start + n + 1;
    int*   bsum   = cursor + n;
    int*   seg    = bsum + 256;
    float* dis    = (float*)(seg + G + 1);
    unsigned int* recs = (unsigned int*)(dis + n);
    float* yf     = (float*)(recs + E);

    const float inv_nn = 1.0f / (float)n;
    const float inv_gg = 1.0f / (float)G;

    // zero counts + stats, compute segment pointers
    zero_seg_kernel<<<nb, 256, 0, stream>>>(counts, st1, batch, seg, n, G);

    // CSR build (edges sorted by destination), packed (row | f16 weight) records
    count_kernel<<<(E + 255) / 256, 256, 0, stream>>>(ei, counts, E);
    scan_partial_kernel<<<nb, 256, 0, stream>>>(counts, bsum, n);
    scan_offsets_kernel<<<1, 256, 0, stream>>>(bsum, start, nb, n);
    scan_write_kernel<<<nb, 256, 0, stream>>>(counts, bsum, start, cursor, dis, n);
    fill_kernel<<<(E + 255) / 256, 256, 0, stream>>>(ei, cursor, dis, recs, E);

    // layer 1: xa = A_hat @ X  (gather on X, 2 slices x 8 float4-lanes)
    {
        constexpr int NPB = 32;
        int gps  = (n + NPB - 1) / NPB;
        int grid = ((gps + 3) / 4) * 8;
        gather_kernel<64, 2, false><<<grid, 256, 0, stream>>>(
            x, start, recs, dis, nullptr, nullptr, nullptr, 0.f, xa, n, gps);
    }
    // a1 = xa @ W1 + b1, fused BN1 stats -> st1
    gemm_kernel<64, 128, true><<<dim3((n + 63) / 64, 1), 256, 0, stream>>>(
        xa, W1, b1, a1, st1, n);

    // layer 2: h1a = A_hat @ relu(BN1(a1))  (gather on a1, 4 slices x 8 float4-lanes)
    {
        constexpr int NPB = 32;
        int gps  = (n + NPB - 1) / NPB;
        int grid = ((gps + 1) / 2) * 8;
        gather_kernel<128, 4, true><<<grid, 256, 0, stream>>>(
            a1, start, recs, dis, st1, g1, be1, inv_nn, h1a, n, gps);
    }
    // a2 = h1a @ W2 + b2, fused BN2 stats -> st2
    gemm_kernel<128, 256, true><<<dim3((n + 63) / 64, 2), 256, 0, stream>>>(
        h1a, W2, b2, a2, st2, n);

    // pool with fused BN2+ReLU (segment ranges, writes means, no atomics)
    pool_kernel<<<G, 256, 0, stream>>>(a2, seg, st2, g2, be2, inv_nn, pooled);

    // head: fc1 (fused solvent FC) -> BN stats -> final
    fc1_kernel<<<G, 128, 0, stream>>>(pooled, sf, Ws, bs, Wf1, bf1, yf);
    stats_kernel<128><<<8, 256, 0, stream>>>(yf, G, stf);
    final_kernel<<<G, 128, 0, stream>>>(yf, stf, gf1, bef1, Wf2, bf2, out, inv_gg);
}

// Round 8
// 163.573 us; speedup vs baseline: 3.4115x; 1.0569x over previous
//
#include <hip/hip_runtime.h>
#include <hip/hip_bf16.h>
#include <hip/hip_fp16.h>

#define EPS 1e-5f

typedef __attribute__((ext_vector_type(8))) short short8_t;   // 8 bf16 (4 VGPRs)
typedef __attribute__((ext_vector_type(4))) float f32x4_t;    // MFMA accumulator

__device__ inline unsigned short f2bf(float f) {              // f32 -> bf16 RNE
    unsigned int u = __float_as_uint(f);
    unsigned int r = (u + 0x7FFFu + ((u >> 16) & 1u)) >> 16;
    return (unsigned short)r;
}

// ------------------------------------------------------- zero + segments ----
__global__ void zero_seg_kernel(int* __restrict__ counts, float* __restrict__ st,
                                const int* __restrict__ batch, int* __restrict__ seg,
                                int n, int G) {
    int i = blockIdx.x * blockDim.x + threadIdx.x;
    if (i < n) counts[i] = 0;
    if (i < 1024) st[i] = 0.f;   // st1[256] | st2[512] | stf[256] contiguous
    if (i <= G) {
        if (i == G) { seg[G] = n; }
        else {
            int lo = 0, hi = n;
            while (lo < hi) {
                int mid = (lo + hi) >> 1;
                if (batch[mid] < i) lo = mid + 1; else hi = mid;
            }
            seg[i] = lo;
        }
    }
}

// ------------------------------------------------------------- CSR build ----
__global__ void count_kernel(const int* __restrict__ ei, int* __restrict__ counts, int E) {
    int e = blockIdx.x * blockDim.x + threadIdx.x;
    if (e < E) atomicAdd(&counts[ei[E + e]], 1);   // col = ei[1][e]
}

__global__ void scan_partial_kernel(const int* __restrict__ counts, int* __restrict__ bsum, int n) {
    __shared__ int s[256];
    int t = threadIdx.x;
    int i = blockIdx.x * 256 + t;
    s[t] = (i < n) ? counts[i] : 0;
    __syncthreads();
#pragma unroll
    for (int off = 128; off > 0; off >>= 1) {
        if (t < off) s[t] += s[t + off];
        __syncthreads();
    }
    if (t == 0) bsum[blockIdx.x] = s[0];
}

__global__ void scan_offsets_kernel(int* __restrict__ bsum, int* __restrict__ start, int nb, int n) {
    __shared__ int s[256];
    int t = threadIdx.x;
    int v = (t < nb) ? bsum[t] : 0;
    s[t] = v;
    __syncthreads();
#pragma unroll
    for (int off = 1; off < 256; off <<= 1) {
        int x = (t >= off) ? s[t - off] : 0;
        __syncthreads();
        s[t] += x;
        __syncthreads();
    }
    if (t < nb) bsum[t] = s[t] - v;     // exclusive
    if (t == 255) start[n] = s[255];    // grand total
}

__global__ void scan_write_kernel(const int* __restrict__ counts, const int* __restrict__ bsum,
                                  int* __restrict__ start, int* __restrict__ cursor,
                                  float* __restrict__ dis, int n) {
    __shared__ int s[256];
    int t = threadIdx.x;
    int i = blockIdx.x * 256 + t;
    int v = (i < n) ? counts[i] : 0;
    s[t] = v;
    __syncthreads();
#pragma unroll
    for (int off = 1; off < 256; off <<= 1) {
        int x = (t >= off) ? s[t - off] : 0;
        __syncthreads();
        s[t] += x;
        __syncthreads();
    }
    if (i < n) {
        int g = bsum[blockIdx.x] + s[t] - v;
        start[i]  = g;
        cursor[i] = g;
        dis[i]    = rsqrtf((float)v + 1.0f);   // deg = counts + self-loop
    }
}

// packed edge record: low 16 = source row (n < 65536), high 16 = f16(dis[row])
__global__ void fill_kernel(const int* __restrict__ ei, int* __restrict__ cursor,
                            const float* __restrict__ dis, unsigned int* __restrict__ recs,
                            int E) {
    int e = blockIdx.x * blockDim.x + threadIdx.x;
    if (e >= E) return;
    int r = ei[e];
    int c = ei[E + e];
    int pos = atomicAdd(&cursor[c], 1);
    unsigned int hw = __half_as_ushort(__float2half_rn(dis[r]));
    recs[pos] = (hw << 16) | (unsigned int)r;
}

// ---------------------------------------------------------------- gather ----
__device__ inline void fma4(float4& d, const float4& v, float wgt) {
    d.x = fmaf(v.x, wgt, d.x);
    d.y = fmaf(v.y, wgt, d.y);
    d.z = fmaf(v.z, wgt, d.z);
    d.w = fmaf(v.w, wgt, d.w);
}

__device__ inline void bnrelu4(float4& v, const float4& sc, const float4& sh) {
    v.x = fmaxf(fmaf(v.x, sc.x, sh.x), 0.f);
    v.y = fmaxf(fmaf(v.y, sc.y, sh.y), 0.f);
    v.z = fmaxf(fmaf(v.z, sc.z, sh.z), 0.f);
    v.w = fmaxf(fmaf(v.w, sc.w, sh.w), 0.f);
}

template <int F, int SLICES, bool BN>
__launch_bounds__(256)
__global__ void gather_kernel(const float* __restrict__ src, const int* __restrict__ start,
                              const unsigned int* __restrict__ recs,
                              const float* __restrict__ dis,
                              const float* __restrict__ st, const float* __restrict__ gamma,
                              const float* __restrict__ beta, float inv_n,
                              float* __restrict__ dst, int n, int gps) {
    constexpr int F4  = F / 4;
    constexpr int W4  = F4 / SLICES;
    constexpr int NPB = 256 / W4;

    int bid = blockIdx.x;
    int xl  = bid & 7;
    int slice, group;
    if (SLICES == 4)      { slice = xl >> 1; group = (bid >> 3) * 2 + (xl & 1); }
    else if (SLICES == 2) { slice = xl >> 2; group = (bid >> 3) * 4 + (xl & 3); }
    else                  { slice = 0;       group = bid; }
    if (group >= gps) return;

    int local = threadIdx.x / W4;
    int lane  = threadIdx.x % W4;
    int node  = group * NPB + local;
    if (node >= n) return;
    int f4    = slice * W4 + lane;
    int feat0 = f4 * 4;

    float4 sc = make_float4(1.f, 1.f, 1.f, 1.f);
    float4 sh = make_float4(0.f, 0.f, 0.f, 0.f);
    if (BN) {
        float m0 = st[feat0 + 0] * inv_n, m1 = st[feat0 + 1] * inv_n;
        float m2 = st[feat0 + 2] * inv_n, m3 = st[feat0 + 3] * inv_n;
        sc.x = gamma[feat0 + 0] * rsqrtf(st[F + feat0 + 0] * inv_n - m0 * m0 + EPS);
        sc.y = gamma[feat0 + 1] * rsqrtf(st[F + feat0 + 1] * inv_n - m1 * m1 + EPS);
        sc.z = gamma[feat0 + 2] * rsqrtf(st[F + feat0 + 2] * inv_n - m2 * m2 + EPS);
        sc.w = gamma[feat0 + 3] * rsqrtf(st[F + feat0 + 3] * inv_n - m3 * m3 + EPS);
        sh.x = beta[feat0 + 0] - m0 * sc.x;
        sh.y = beta[feat0 + 1] - m1 * sc.y;
        sh.z = beta[feat0 + 2] - m2 * sc.z;
        sh.w = beta[feat0 + 3] - m3 * sc.w;
    }

    const float4* src4 = (const float4*)src;

    float di = dis[node];
    float4 self = src4[(size_t)node * F4 + f4];
    if (BN) bnrelu4(self, sc, sh);
    float4 acc  = make_float4(self.x * di, self.y * di, self.z * di, self.w * di);
    float4 acc2 = make_float4(0.f, 0.f, 0.f, 0.f);

    int e  = start[node];
    int e1 = start[node + 1];
    for (; e + 3 < e1; e += 4) {
        unsigned int q0 = recs[e],     q1 = recs[e + 1];
        unsigned int q2 = recs[e + 2], q3 = recs[e + 3];
        int r0 = q0 & 0xFFFF, r1 = q1 & 0xFFFF, r2 = q2 & 0xFFFF, r3 = q3 & 0xFFFF;
        float w0 = __half2float(__ushort_as_half((unsigned short)(q0 >> 16)));
        float w1 = __half2float(__ushort_as_half((unsigned short)(q1 >> 16)));
        float w2 = __half2float(__ushort_as_half((unsigned short)(q2 >> 16)));
        float w3 = __half2float(__ushort_as_half((unsigned short)(q3 >> 16)));
        float4 v0 = src4[(size_t)r0 * F4 + f4];
        float4 v1 = src4[(size_t)r1 * F4 + f4];
        float4 v2 = src4[(size_t)r2 * F4 + f4];
        float4 v3 = src4[(size_t)r3 * F4 + f4];
        if (BN) { bnrelu4(v0, sc, sh); bnrelu4(v1, sc, sh); bnrelu4(v2, sc, sh); bnrelu4(v3, sc, sh); }
        fma4(acc, v0, w0);
        fma4(acc2, v1, w1);
        fma4(acc, v2, w2);
        fma4(acc2, v3, w3);
    }
    for (; e < e1; e++) {
        unsigned int q0 = recs[e];
        int r0 = q0 & 0xFFFF;
        float w0 = __half2float(__ushort_as_half((unsigned short)(q0 >> 16)));
        float4 v0 = src4[(size_t)r0 * F4 + f4];
        if (BN) bnrelu4(v0, sc, sh);
        fma4(acc, v0, w0);
    }
    float4 o;
    o.x = (acc.x + acc2.x) * di;
    o.y = (acc.y + acc2.y) * di;
    o.z = (acc.z + acc2.z) * di;
    o.w = (acc.w + acc2.w) * di;
    ((float4*)dst)[(size_t)node * F4 + f4] = o;
}

// ------------------------------------------------------------- MFMA GEMM ----
// C[M, NTOT] = A[M, K] @ B[K, NTOT] + bias; f32 in/out, bf16 MFMA inside.
// Block: 256 thr = 4 waves (2x2), tile 64x64; wave: 32x32 via 2x2 16x16x32 frags.
// Also accumulates per-column sum/sumsq of C into st (atomic, one add/col/block).
template <int K, int NTOT>
__launch_bounds__(256)
__global__ void gemm_mfma_kernel(const float* __restrict__ A, const float* __restrict__ B,
                                 const float* __restrict__ bias, float* __restrict__ C,
                                 float* __restrict__ st, int M) {
    constexpr int KP = K + 8;            // +8 shorts pad: row stride 272B (K=128) -> 4-bank skew
    __shared__ unsigned short As[64][KP];   // [row][k]
    __shared__ unsigned short Bs[64][KP];   // [col][k]  (B transposed)
    __shared__ float sred[2][64][2];

    const int t    = threadIdx.x;
    const int lane = t & 63;
    const int wave = t >> 6;
    const int wr   = wave >> 1;          // 0..1 (row half)
    const int wc   = wave & 1;           // 0..1 (col half)
    const int row0 = blockIdx.x * 64;
    const int col0 = blockIdx.y * 64;

    // stage A (64 x K f32 -> bf16), coalesced float4 reads
    constexpr int PA = (64 * K / 4) / 256;
#pragma unroll
    for (int p = 0; p < PA; p++) {
        int fi = t + 256 * p;
        int r  = fi / (K / 4);
        int c4 = fi % (K / 4);
        float4 v = make_float4(0.f, 0.f, 0.f, 0.f);
        if (row0 + r < M) v = *(const float4*)&A[(size_t)(row0 + r) * K + c4 * 4];
        ushort4 h;
        h.x = f2bf(v.x); h.y = f2bf(v.y); h.z = f2bf(v.z); h.w = f2bf(v.w);
        *(ushort4*)&As[r][c4 * 4] = h;
    }
    // stage B (K x 64 f32 -> bf16, transposed into Bs[col][k])
    constexpr int PB = (K * 16) / 256;
#pragma unroll
    for (int p = 0; p < PB; p++) {
        int fi = t + 256 * p;
        int k  = fi >> 4;
        int c4 = fi & 15;
        float4 v = *(const float4*)&B[(size_t)k * NTOT + col0 + c4 * 4];
        Bs[c4 * 4 + 0][k] = f2bf(v.x);
        Bs[c4 * 4 + 1][k] = f2bf(v.y);
        Bs[c4 * 4 + 2][k] = f2bf(v.z);
        Bs[c4 * 4 + 3][k] = f2bf(v.w);
    }
    __syncthreads();

    const int l15 = lane & 15;
    const int l16 = lane >> 4;
    f32x4_t acc[2][2] = {};
#pragma unroll
    for (int ks = 0; ks < K / 32; ks++) {
        int koff = ks * 32 + l16 * 8;
        short8_t a0 = *(const short8_t*)&As[wr * 32 + l15][koff];
        short8_t a1 = *(const short8_t*)&As[wr * 32 + 16 + l15][koff];
        short8_t b0 = *(const short8_t*)&Bs[wc * 32 + l15][koff];
        short8_t b1 = *(const short8_t*)&Bs[wc * 32 + 16 + l15][koff];
        acc[0][0] = __builtin_amdgcn_mfma_f32_16x16x32_bf16(a0, b0, acc[0][0], 0, 0, 0);
        acc[0][1] = __builtin_amdgcn_mfma_f32_16x16x32_bf16(a0, b1, acc[0][1], 0, 0, 0);
        acc[1][0] = __builtin_amdgcn_mfma_f32_16x16x32_bf16(a1, b0, acc[1][0], 0, 0, 0);
        acc[1][1] = __builtin_amdgcn_mfma_f32_16x16x32_bf16(a1, b1, acc[1][1], 0, 0, 0);
    }

    // epilogue: bias + store + per-column stats (C/D: col=l&15, row=(l>>4)*4+j)
    float s1[2] = {0.f, 0.f}, s2[2] = {0.f, 0.f};
#pragma unroll
    for (int m = 0; m < 2; m++) {
#pragma unroll
        for (int j = 0; j < 4; j++) {
            int row = row0 + wr * 32 + m * 16 + l16 * 4 + j;
            if (row < M) {
#pragma unroll
                for (int nn = 0; nn < 2; nn++) {
                    int col = col0 + wc * 32 + nn * 16 + l15;
                    float v = acc[m][nn][j] + bias[col];
                    C[(size_t)row * NTOT + col] = v;
                    s1[nn] += v;
                    s2[nn] += v * v;
                }
            }
        }
    }
#pragma unroll
    for (int nn = 0; nn < 2; nn++) {
        s1[nn] += __shfl_xor(s1[nn], 16);
        s1[nn] += __shfl_xor(s1[nn], 32);
        s2[nn] += __shfl_xor(s2[nn], 16);
        s2[nn] += __shfl_xor(s2[nn], 32);
    }
    if (lane < 16) {
#pragma unroll
        for (int nn = 0; nn < 2; nn++) {
            sred[wr][wc * 32 + nn * 16 + lane][0] = s1[nn];
            sred[wr][wc * 32 + nn * 16 + lane][1] = s2[nn];
        }
    }
    __syncthreads();
    if (t < 64) {
        float a = sred[0][t][0] + sred[1][t][0];
        float b = sred[0][t][1] + sred[1][t][1];
        atomicAdd(&st[col0 + t], a);
        atomicAdd(&st[NTOT + col0 + t], b);
    }
}

// ----------------------------------------------------------------- stats ----
template <int F>
__launch_bounds__(256)
__global__ void stats_kernel(const float* __restrict__ h, int n, float* __restrict__ out) {
    constexpr int R = 256 / F;
    __shared__ float red[512];
    int t  = threadIdx.x;
    int f  = t % F;
    int rs = t / F;
    float s = 0.f, s2 = 0.f;
    int rows = (n + gridDim.x - 1) / gridDim.x;
    int i0 = blockIdx.x * rows;
    int i1 = min(i0 + rows, n);
    for (int i = i0 + rs; i < i1; i += R) {
        float v = h[(size_t)i * F + f];
        s  += v;
        s2 += v * v;
    }
    if (R == 2) {
        red[t]       = s;
        red[256 + t] = s2;
        __syncthreads();
        if (t < F) {
            s  += red[t + F];
            s2 += red[256 + t + F];
        }
    }
    if (t < F) {
        atomicAdd(&out[f], s);
        atomicAdd(&out[F + f], s2);
    }
}

// ------------------------------------------------------------------ pool ----
__launch_bounds__(256)
__global__ void pool_kernel(const float* __restrict__ a2, const int* __restrict__ seg,
                            const float* __restrict__ st2, const float* __restrict__ g2,
                            const float* __restrict__ be2, float inv_n,
                            float* __restrict__ pooled) {
    int g = blockIdx.x, f = threadIdx.x;
    float mean = st2[f] * inv_n;
    float var  = st2[256 + f] * inv_n - mean * mean;
    float sc   = g2[f] * rsqrtf(var + EPS);
    float sh   = be2[f] - mean * sc;
    int i0 = seg[g], i1 = seg[g + 1];
    float acc = 0.f, accB = 0.f;
    int i = i0;
    for (; i + 1 < i1; i += 2) {
        acc  += fmaxf(fmaf(a2[(size_t)i * 256 + f], sc, sh), 0.f);
        accB += fmaxf(fmaf(a2[(size_t)(i + 1) * 256 + f], sc, sh), 0.f);
    }
    if (i < i1) acc += fmaxf(fmaf(a2[(size_t)i * 256 + f], sc, sh), 0.f);
    pooled[(size_t)g * 256 + f] = (acc + accB) / fmaxf((float)(i1 - i0), 1.f);
}

// -------------------------------------------------------------- small FC ----
__launch_bounds__(128)
__global__ void fc1_kernel(const float* __restrict__ pooled, const float* __restrict__ sf,
                           const float* __restrict__ Ws, const float* __restrict__ bs,
                           const float* __restrict__ Wf1, const float* __restrict__ bf1,
                           float* __restrict__ y) {
    __shared__ float z[384];
    __shared__ float s[128];
    int g = blockIdx.x, f = threadIdx.x;
    s[f]       = sf[g * 128 + f];
    z[f]       = pooled[g * 256 + f];
    z[128 + f] = pooled[g * 256 + 128 + f];
    __syncthreads();
    float a = 0.f;
#pragma unroll 8
    for (int k = 0; k < 128; k++) a = fmaf(s[k], Ws[k * 128 + f], a);
    z[256 + f] = fmaxf(a + bs[f], 0.f);
    __syncthreads();
    float acc = 0.f;
#pragma unroll 8
    for (int k = 0; k < 384; k++) acc = fmaf(z[k], Wf1[k * 128 + f], acc);
    y[g * 128 + f] = acc + bf1[f];
}

__launch_bounds__(128)
__global__ void final_kernel(const float* __restrict__ y, const float* __restrict__ stf,
                             const float* __restrict__ gf, const float* __restrict__ bef,
                             const float* __restrict__ Wf2, const float* __restrict__ bf2,
                             float* __restrict__ out, float inv_n) {
    __shared__ float red[2];
    int g = blockIdx.x, f = threadIdx.x;
    float mean = stf[f] * inv_n;
    float var  = stf[128 + f] * inv_n - mean * mean;
    float sc   = gf[f] * rsqrtf(var + EPS);
    float sh   = bef[f] - mean * sc;
    float v = fmaxf(y[g * 128 + f] * sc + sh, 0.f) * Wf2[f];
#pragma unroll
    for (int off = 32; off > 0; off >>= 1) v += __shfl_down(v, off);
    if ((f & 63) == 0) red[f >> 6] = v;
    __syncthreads();
    if (f == 0) out[g] = red[0] + red[1] + bf2[0];
}

// ---------------------------------------------------------------- launch ----
extern "C" void kernel_launch(void* const* d_in, const int* in_sizes, int n_in,
                              void* d_out, int out_size, void* d_ws, size_t ws_size,
                              hipStream_t stream) {
    const float* x    = (const float*)d_in[0];
    const int*   ei   = (const int*)d_in[1];
    const int*   batch= (const int*)d_in[2];
    const float* sf   = (const float*)d_in[3];
    const float* W1   = (const float*)d_in[4];
    const float* b1   = (const float*)d_in[5];
    const float* g1   = (const float*)d_in[6];
    const float* be1  = (const float*)d_in[7];
    const float* W2   = (const float*)d_in[8];
    const float* b2   = (const float*)d_in[9];
    const float* g2   = (const float*)d_in[10];
    const float* be2  = (const float*)d_in[11];
    const float* Ws   = (const float*)d_in[12];
    const float* bs   = (const float*)d_in[13];
    const float* Wf1  = (const float*)d_in[14];
    const float* bf1  = (const float*)d_in[15];
    const float* gf1  = (const float*)d_in[16];
    const float* bef1 = (const float*)d_in[17];
    const float* Wf2  = (const float*)d_in[18];
    const float* bf2  = (const float*)d_in[19];
    float* out = (float*)d_out;

    const int n = in_sizes[0] / 64;    // 20000 nodes
    const int E = in_sizes[1] / 2;     // 320000 edges
    const int G = in_sizes[3] / 128;   // 512 graphs
    const int nb = (n + 255) / 256;

    float* ws     = (float*)d_ws;
    float* a2     = ws;
    float* xa     = ws;                            // alias (dead before GEMM2)
    float* h1a    = ws + (size_t)n * 256;
    float* a1     = ws + (size_t)n * 384;
    float* pooled = ws + (size_t)n * 512;
    float* st1    = pooled + (size_t)G * 256;
    float* st2    = st1 + 256;
    float* stf    = st2 + 512;
    int*   counts = (int*)(stf + 256);
    int*   start  = counts + n;
    int*   cursor = start + n + 1;
    int*   bsum   = cursor + n;
    int*   seg    = bsum + 256;
    float* dis    = (float*)(seg + G + 1);
    unsigned int* recs = (unsigned int*)(dis + n);
    float* yf     = (float*)(recs + E);

    const float inv_nn = 1.0f / (float)n;
    const float inv_gg = 1.0f / (float)G;

    zero_seg_kernel<<<nb, 256, 0, stream>>>(counts, st1, batch, seg, n, G);

    count_kernel<<<(E + 255) / 256, 256, 0, stream>>>(ei, counts, E);
    scan_partial_kernel<<<nb, 256, 0, stream>>>(counts, bsum, n);
    scan_offsets_kernel<<<1, 256, 0, stream>>>(bsum, start, nb, n);
    scan_write_kernel<<<nb, 256, 0, stream>>>(counts, bsum, start, cursor, dis, n);
    fill_kernel<<<(E + 255) / 256, 256, 0, stream>>>(ei, cursor, dis, recs, E);

    // layer 1: xa = A_hat @ X
    {
        constexpr int NPB = 32;
        int gps  = (n + NPB - 1) / NPB;
        int grid = ((gps + 3) / 4) * 8;
        gather_kernel<64, 2, false><<<grid, 256, 0, stream>>>(
            x, start, recs, dis, nullptr, nullptr, nullptr, 0.f, xa, n, gps);
    }
    // a1 = xa @ W1 + b1 (MFMA), fused BN1 stats -> st1
    gemm_mfma_kernel<64, 128><<<dim3((n + 63) / 64, 2), 256, 0, stream>>>(
        xa, W1, b1, a1, st1, n);

    // layer 2: h1a = A_hat @ relu(BN1(a1))
    {
        constexpr int NPB = 32;
        int gps  = (n + NPB - 1) / NPB;
        int grid = ((gps + 1) / 2) * 8;
        gather_kernel<128, 4, true><<<grid, 256, 0, stream>>>(
            a1, start, recs, dis, st1, g1, be1, inv_nn, h1a, n, gps);
    }
    // a2 = h1a @ W2 + b2 (MFMA), fused BN2 stats -> st2
    gemm_mfma_kernel<128, 256><<<dim3((n + 63) / 64, 4), 256, 0, stream>>>(
        h1a, W2, b2, a2, st2, n);

    pool_kernel<<<G, 256, 0, stream>>>(a2, seg, st2, g2, be2, inv_nn, pooled);

    fc1_kernel<<<G, 128, 0, stream>>>(pooled, sf, Ws, bs, Wf1, bf1, yf);
    stats_kernel<128><<<8, 256, 0, stream>>>(yf, G, stf);
    final_kernel<<<G, 128, 0, stream>>>(yf, stf, gf1, bef1, Wf2, bf2, out, inv_gg);
}

// Round 9
// 153.211 us; speedup vs baseline: 3.6422x; 1.0676x over previous
//
#include <hip/hip_runtime.h>
#include <hip/hip_bf16.h>
#include <hip/hip_fp16.h>

#define EPS 1e-5f

typedef __attribute__((ext_vector_type(8))) short short8_t;            // 8 bf16 (MFMA operand)
typedef __attribute__((ext_vector_type(8))) unsigned short ushort8_t;  // 8 bf16 storage
typedef __attribute__((ext_vector_type(4))) float f32x4_t;             // MFMA accumulator

__device__ inline unsigned short f2bf(float f) {              // f32 -> bf16 RNE
    unsigned int u = __float_as_uint(f);
    unsigned int r = (u + 0x7FFFu + ((u >> 16) & 1u)) >> 16;
    return (unsigned short)r;
}
__device__ inline float bf2f(unsigned short h) {
    return __uint_as_float((unsigned int)h << 16);
}

// ------------------------------------------------- prep: zero+seg+convert ----
// zero counts[n], st[1024]; seg[g] binary search; convert x (f32) -> xb (bf16)
__global__ void prep_kernel(const float* __restrict__ x, unsigned short* __restrict__ xb,
                            int* __restrict__ counts, float* __restrict__ st,
                            const int* __restrict__ batch, int* __restrict__ seg,
                            int n, int G) {
    int i = blockIdx.x * blockDim.x + threadIdx.x;
    if (i < n * 8) {               // one ushort8 (8 feats) per thread; x row = 64 feats
        const float4* xf4 = (const float4*)x;
        float4 u = xf4[i * 2];
        float4 v = xf4[i * 2 + 1];
        ushort8_t h;
        h[0] = f2bf(u.x); h[1] = f2bf(u.y); h[2] = f2bf(u.z); h[3] = f2bf(u.w);
        h[4] = f2bf(v.x); h[5] = f2bf(v.y); h[6] = f2bf(v.z); h[7] = f2bf(v.w);
        ((ushort8_t*)xb)[i] = h;
    }
    if (i < n) counts[i] = 0;
    if (i < 1024) st[i] = 0.f;     // st1[256] | st2[512] | stf[256]
    if (i <= G) {
        if (i == G) { seg[G] = n; }
        else {
            int lo = 0, hi = n;
            while (lo < hi) {
                int mid = (lo + hi) >> 1;
                if (batch[mid] < i) lo = mid + 1; else hi = mid;
            }
            seg[i] = lo;
        }
    }
}

// ------------------------------------------------------------- CSR build ----
__global__ void count_kernel(const int* __restrict__ ei, int* __restrict__ counts, int E) {
    int e = blockIdx.x * blockDim.x + threadIdx.x;
    if (e < E) atomicAdd(&counts[ei[E + e]], 1);   // col = ei[1][e]
}

__global__ void scan_partial_kernel(const int* __restrict__ counts, int* __restrict__ bsum, int n) {
    __shared__ int s[256];
    int t = threadIdx.x;
    int i = blockIdx.x * 256 + t;
    s[t] = (i < n) ? counts[i] : 0;
    __syncthreads();
#pragma unroll
    for (int off = 128; off > 0; off >>= 1) {
        if (t < off) s[t] += s[t + off];
        __syncthreads();
    }
    if (t == 0) bsum[blockIdx.x] = s[0];
}

__global__ void scan_offsets_kernel(int* __restrict__ bsum, int* __restrict__ start, int nb, int n) {
    __shared__ int s[256];
    int t = threadIdx.x;
    int v = (t < nb) ? bsum[t] : 0;
    s[t] = v;
    __syncthreads();
#pragma unroll
    for (int off = 1; off < 256; off <<= 1) {
        int x = (t >= off) ? s[t - off] : 0;
        __syncthreads();
        s[t] += x;
        __syncthreads();
    }
    if (t < nb) bsum[t] = s[t] - v;     // exclusive
    if (t == 255) start[n] = s[255];    // grand total
}

__global__ void scan_write_kernel(const int* __restrict__ counts, const int* __restrict__ bsum,
                                  int* __restrict__ start, int* __restrict__ cursor,
                                  float* __restrict__ dis, int n) {
    __shared__ int s[256];
    int t = threadIdx.x;
    int i = blockIdx.x * 256 + t;
    int v = (i < n) ? counts[i] : 0;
    s[t] = v;
    __syncthreads();
#pragma unroll
    for (int off = 1; off < 256; off <<= 1) {
        int x = (t >= off) ? s[t - off] : 0;
        __syncthreads();
        s[t] += x;
        __syncthreads();
    }
    if (i < n) {
        int g = bsum[blockIdx.x] + s[t] - v;
        start[i]  = g;
        cursor[i] = g;
        dis[i]    = rsqrtf((float)v + 1.0f);   // deg = counts + self-loop
    }
}

// packed edge record: low 16 = source row (n < 65536), high 16 = f16(dis[row])
__global__ void fill_kernel(const int* __restrict__ ei, int* __restrict__ cursor,
                            const float* __restrict__ dis, unsigned int* __restrict__ recs,
                            int E) {
    int e = blockIdx.x * blockDim.x + threadIdx.x;
    if (e >= E) return;
    int r = ei[e];
    int c = ei[E + e];
    int pos = atomicAdd(&cursor[c], 1);
    unsigned int hw = __half_as_ushort(__float2half_rn(dis[r]));
    recs[pos] = (hw << 16) | (unsigned int)r;
}

// ---------------------------------------------------------------- gather ----
// bf16 in / bf16 out. dst[i] = bf16( dis_i*( T(src[i])*dis_i + sum_e T(src[r_e])*w_e ) )
// T = identity or relu(BN(.)). Lane owns 8 consecutive feats (16B ushort8).
template <int F, int SLICES, bool BN>
__launch_bounds__(256)
__global__ void gather_kernel(const unsigned short* __restrict__ src, const int* __restrict__ start,
                              const unsigned int* __restrict__ recs,
                              const float* __restrict__ dis,
                              const float* __restrict__ st, const float* __restrict__ gamma,
                              const float* __restrict__ beta, float inv_n,
                              unsigned short* __restrict__ dst, int n, int gps) {
    constexpr int F8  = F / 8;        // ushort8s per node row
    constexpr int W8  = F8 / SLICES;  // lanes per node
    constexpr int NPB = 256 / W8;     // nodes per block

    int bid = blockIdx.x;
    int xl  = bid & 7;
    int slice, group;
    if (SLICES == 2) { slice = xl >> 2; group = (bid >> 3) * 4 + (xl & 3); }
    else             { slice = 0;       group = bid; }
    if (group >= gps) return;

    int local = threadIdx.x / W8;
    int lane  = threadIdx.x % W8;
    int node  = group * NPB + local;
    if (node >= n) return;
    int f8    = slice * W8 + lane;
    int feat0 = f8 * 8;

    float sc[8], sh[8];
    if (BN) {
#pragma unroll
        for (int j = 0; j < 8; j++) {
            float m = st[feat0 + j] * inv_n;
            float v = st[F + feat0 + j] * inv_n - m * m;
            sc[j] = gamma[feat0 + j] * rsqrtf(v + EPS);
            sh[j] = beta[feat0 + j] - m * sc[j];
        }
    }

    const ushort8_t* src8 = (const ushort8_t*)src;

    float di = dis[node];
    ushort8_t sv = src8[(size_t)node * F8 + f8];
    float acc[8], acc2[8];
#pragma unroll
    for (int j = 0; j < 8; j++) {
        float f = bf2f(sv[j]);
        if (BN) f = fmaxf(fmaf(f, sc[j], sh[j]), 0.f);
        acc[j]  = f * di;
        acc2[j] = 0.f;
    }

    int e  = start[node];
    int e1 = start[node + 1];
    for (; e + 1 < e1; e += 2) {
        unsigned int q0 = recs[e], q1 = recs[e + 1];
        int r0 = q0 & 0xFFFF, r1 = q1 & 0xFFFF;
        float w0 = __half2float(__ushort_as_half((unsigned short)(q0 >> 16)));
        float w1 = __half2float(__ushort_as_half((unsigned short)(q1 >> 16)));
        ushort8_t v0 = src8[(size_t)r0 * F8 + f8];
        ushort8_t v1 = src8[(size_t)r1 * F8 + f8];
#pragma unroll
        for (int j = 0; j < 8; j++) {
            float f0 = bf2f(v0[j]);
            float f1 = bf2f(v1[j]);
            if (BN) {
                f0 = fmaxf(fmaf(f0, sc[j], sh[j]), 0.f);
                f1 = fmaxf(fmaf(f1, sc[j], sh[j]), 0.f);
            }
            acc[j]  = fmaf(f0, w0, acc[j]);
            acc2[j] = fmaf(f1, w1, acc2[j]);
        }
    }
    if (e < e1) {
        unsigned int q0 = recs[e];
        int r0 = q0 & 0xFFFF;
        float w0 = __half2float(__ushort_as_half((unsigned short)(q0 >> 16)));
        ushort8_t v0 = src8[(size_t)r0 * F8 + f8];
#pragma unroll
        for (int j = 0; j < 8; j++) {
            float f0 = bf2f(v0[j]);
            if (BN) f0 = fmaxf(fmaf(f0, sc[j], sh[j]), 0.f);
            acc[j] = fmaf(f0, w0, acc[j]);
        }
    }
    ushort8_t o;
#pragma unroll
    for (int j = 0; j < 8; j++) o[j] = f2bf((acc[j] + acc2[j]) * di);
    ((ushort8_t*)dst)[(size_t)node * F8 + f8] = o;
}

// ------------------------------------------------------------- MFMA GEMM ----
// C[M, NTOT] = A[M, K](bf16) @ B[K, NTOT](f32 -> bf16) + bias; out f32 or bf16.
// Block: 256 thr = 4 waves (2x2), tile 64x64; wave: 32x32 via 2x2 16x16x32 frags.
// Accumulates per-column sum/sumsq of C (f32, pre-rounding) into st (atomic).
template <int K, int NTOT, bool OUT_BF16>
__launch_bounds__(256)
__global__ void gemm_mfma_kernel(const unsigned short* __restrict__ A, const float* __restrict__ B,
                                 const float* __restrict__ bias, void* __restrict__ Cout,
                                 float* __restrict__ st, int M) {
    constexpr int KP = K + 8;               // pad: row stride 144B/272B (16B-aligned, bank-skewed)
    __shared__ unsigned short As[64][KP];   // [row][k]
    __shared__ unsigned short Bs[64][KP];   // [col][k]  (B transposed)
    __shared__ float sred[2][64][2];

    const int t    = threadIdx.x;
    const int lane = t & 63;
    const int wave = t >> 6;
    const int wr   = wave >> 1;
    const int wc   = wave & 1;
    const int row0 = blockIdx.x * 64;
    const int col0 = blockIdx.y * 64;

    // stage A (64 x K bf16), direct 16B copies
    constexpr int PA = (64 * K / 8) / 256;
#pragma unroll
    for (int p = 0; p < PA; p++) {
        int fi = t + 256 * p;
        int r  = fi / (K / 8);
        int c8 = fi % (K / 8);
        ushort8_t v = {};
        if (row0 + r < M) v = *(const ushort8_t*)&A[(size_t)(row0 + r) * K + c8 * 8];
        *(ushort8_t*)&As[r][c8 * 8] = v;
    }
    // stage B (K x 64 f32 -> bf16, transposed into Bs[col][k])
    constexpr int PB = (K * 16) / 256;
#pragma unroll
    for (int p = 0; p < PB; p++) {
        int fi = t + 256 * p;
        int k  = fi >> 4;
        int c4 = fi & 15;
        float4 v = *(const float4*)&B[(size_t)k * NTOT + col0 + c4 * 4];
        Bs[c4 * 4 + 0][k] = f2bf(v.x);
        Bs[c4 * 4 + 1][k] = f2bf(v.y);
        Bs[c4 * 4 + 2][k] = f2bf(v.z);
        Bs[c4 * 4 + 3][k] = f2bf(v.w);
    }
    __syncthreads();

    const int l15 = lane & 15;
    const int l16 = lane >> 4;
    f32x4_t acc[2][2] = {};
#pragma unroll
    for (int ks = 0; ks < K / 32; ks++) {
        int koff = ks * 32 + l16 * 8;
        short8_t a0 = *(const short8_t*)&As[wr * 32 + l15][koff];
        short8_t a1 = *(const short8_t*)&As[wr * 32 + 16 + l15][koff];
        short8_t b0 = *(const short8_t*)&Bs[wc * 32 + l15][koff];
        short8_t b1 = *(const short8_t*)&Bs[wc * 32 + 16 + l15][koff];
        acc[0][0] = __builtin_amdgcn_mfma_f32_16x16x32_bf16(a0, b0, acc[0][0], 0, 0, 0);
        acc[0][1] = __builtin_amdgcn_mfma_f32_16x16x32_bf16(a0, b1, acc[0][1], 0, 0, 0);
        acc[1][0] = __builtin_amdgcn_mfma_f32_16x16x32_bf16(a1, b0, acc[1][0], 0, 0, 0);
        acc[1][1] = __builtin_amdgcn_mfma_f32_16x16x32_bf16(a1, b1, acc[1][1], 0, 0, 0);
    }

    // epilogue: bias + store + per-column stats (C/D: col=l&15, row=(l>>4)*4+j)
    float s1[2] = {0.f, 0.f}, s2[2] = {0.f, 0.f};
#pragma unroll
    for (int m = 0; m < 2; m++) {
#pragma unroll
        for (int j = 0; j < 4; j++) {
            int row = row0 + wr * 32 + m * 16 + l16 * 4 + j;
            if (row < M) {
#pragma unroll
                for (int nn = 0; nn < 2; nn++) {
                    int col = col0 + wc * 32 + nn * 16 + l15;
                    float v = acc[m][nn][j] + bias[col];
                    if (OUT_BF16) ((unsigned short*)Cout)[(size_t)row * NTOT + col] = f2bf(v);
                    else          ((float*)Cout)[(size_t)row * NTOT + col] = v;
                    s1[nn] += v;
                    s2[nn] += v * v;
                }
            }
        }
    }
#pragma unroll
    for (int nn = 0; nn < 2; nn++) {
        s1[nn] += __shfl_xor(s1[nn], 16);
        s1[nn] += __shfl_xor(s1[nn], 32);
        s2[nn] += __shfl_xor(s2[nn], 16);
        s2[nn] += __shfl_xor(s2[nn], 32);
    }
    if (lane < 16) {
#pragma unroll
        for (int nn = 0; nn < 2; nn++) {
            sred[wr][wc * 32 + nn * 16 + lane][0] = s1[nn];
            sred[wr][wc * 32 + nn * 16 + lane][1] = s2[nn];
        }
    }
    __syncthreads();
    if (t < 64) {
        float a = sred[0][t][0] + sred[1][t][0];
        float b = sred[0][t][1] + sred[1][t][1];
        atomicAdd(&st[col0 + t], a);
        atomicAdd(&st[NTOT + col0 + t], b);
    }
}

// -------------------------------------------- fused pool + solv + fc1 + stats
// block g: pooled[256] = mean relu(BN2(a2[seg])); solv = relu(sf@Ws+bs);
// yf[g] = [pooled|solv] @ Wf1 + bf1; atomic stats of yf into stf.
__launch_bounds__(256)
__global__ void poolfc_kernel(const float* __restrict__ a2, const int* __restrict__ seg,
                              const float* __restrict__ st2, const float* __restrict__ g2,
                              const float* __restrict__ be2, float inv_n,
                              const float* __restrict__ sf, const float* __restrict__ Ws,
                              const float* __restrict__ bs, const float* __restrict__ Wf1,
                              const float* __restrict__ bf1,
                              float* __restrict__ yf, float* __restrict__ stf) {
    __shared__ float zb[384];
    __shared__ float sl[128];
    int g = blockIdx.x, t = threadIdx.x;
    if (t < 128) sl[t] = sf[g * 128 + t];

    float mean = st2[t] * inv_n;
    float var  = st2[256 + t] * inv_n - mean * mean;
    float sc   = g2[t] * rsqrtf(var + EPS);
    float sh   = be2[t] - mean * sc;
    int i0 = seg[g], i1 = seg[g + 1];
    float acc = 0.f, accB = 0.f;
    int i = i0;
    for (; i + 1 < i1; i += 2) {
        acc  += fmaxf(fmaf(a2[(size_t)i * 256 + t], sc, sh), 0.f);
        accB += fmaxf(fmaf(a2[(size_t)(i + 1) * 256 + t], sc, sh), 0.f);
    }
    if (i < i1) acc += fmaxf(fmaf(a2[(size_t)i * 256 + t], sc, sh), 0.f);
    zb[t] = (acc + accB) / fmaxf((float)(i1 - i0), 1.f);
    __syncthreads();

    if (t < 128) {
        float a = 0.f;
#pragma unroll 8
        for (int k = 0; k < 128; k++) a = fmaf(sl[k], Ws[k * 128 + t], a);
        zb[256 + t] = fmaxf(a + bs[t], 0.f);
    }
    __syncthreads();

    if (t < 128) {
        float y = 0.f;
#pragma unroll 8
        for (int k = 0; k < 384; k++) y = fmaf(zb[k], Wf1[k * 128 + t], y);
        y += bf1[t];
        yf[g * 128 + t] = y;
        atomicAdd(&stf[t], y);
        atomicAdd(&stf[128 + t], y * y);
    }
}

__launch_bounds__(128)
__global__ void final_kernel(const float* __restrict__ y, const float* __restrict__ stf,
                             const float* __restrict__ gf, const float* __restrict__ bef,
                             const float* __restrict__ Wf2, const float* __restrict__ bf2,
                             float* __restrict__ out, float inv_n) {
    __shared__ float red[2];
    int g = blockIdx.x, f = threadIdx.x;
    float mean = stf[f] * inv_n;
    float var  = stf[128 + f] * inv_n - mean * mean;
    float sc   = gf[f] * rsqrtf(var + EPS);
    float sh   = bef[f] - mean * sc;
    float v = fmaxf(y[g * 128 + f] * sc + sh, 0.f) * Wf2[f];
#pragma unroll
    for (int off = 32; off > 0; off >>= 1) v += __shfl_down(v, off);
    if ((f & 63) == 0) red[f >> 6] = v;
    __syncthreads();
    if (f == 0) out[g] = red[0] + red[1] + bf2[0];
}

// ---------------------------------------------------------------- launch ----
extern "C" void kernel_launch(void* const* d_in, const int* in_sizes, int n_in,
                              void* d_out, int out_size, void* d_ws, size_t ws_size,
                              hipStream_t stream) {
    const float* x    = (const float*)d_in[0];
    const int*   ei   = (const int*)d_in[1];
    const int*   batch= (const int*)d_in[2];
    const float* sf   = (const float*)d_in[3];
    const float* W1   = (const float*)d_in[4];
    const float* b1   = (const float*)d_in[5];
    const float* g1   = (const float*)d_in[6];
    const float* be1  = (const float*)d_in[7];
    const float* W2   = (const float*)d_in[8];
    const float* b2   = (const float*)d_in[9];
    const float* g2   = (const float*)d_in[10];
    const float* be2  = (const float*)d_in[11];
    const float* Ws   = (const float*)d_in[12];
    const float* bs   = (const float*)d_in[13];
    const float* Wf1  = (const float*)d_in[14];
    const float* bf1  = (const float*)d_in[15];
    const float* gf1  = (const float*)d_in[16];
    const float* bef1 = (const float*)d_in[17];
    const float* Wf2  = (const float*)d_in[18];
    const float* bf2  = (const float*)d_in[19];
    float* out = (float*)d_out;

    const int n = in_sizes[0] / 64;    // 20000 nodes
    const int E = in_sizes[1] / 2;     // 320000 edges
    const int G = in_sizes[3] / 128;   // 512 graphs
    const int nb = (n + 255) / 256;

    // workspace (floats unless noted):
    // a2[256n] | xb[n*64 bf16 = 32n] | a1b[n*128 bf16 = 64n] | h1b[64n] |
    // st[1024] | counts[n] | start[n+1] | cursor[n] | bsum[256] | seg[G+1] |
    // dis[n] | recs[E u32] | yf[G*128]
    float* ws   = (float*)d_ws;
    float* a2   = ws;
    unsigned short* xb  = (unsigned short*)(ws + (size_t)n * 256);
    unsigned short* a1b = (unsigned short*)(ws + (size_t)n * 288);
    unsigned short* h1b = (unsigned short*)(ws + (size_t)n * 352);
    float* st   = ws + (size_t)n * 416;
    float* st1  = st;            // 256
    float* st2  = st + 256;      // 512
    float* stf  = st + 768;      // 256
    int*   counts = (int*)(st + 1024);
    int*   start  = counts + n;
    int*   cursor = start + n + 1;
    int*   bsum   = cursor + n;
    int*   seg    = bsum + 256;
    float* dis    = (float*)(seg + G + 1);
    unsigned int* recs = (unsigned int*)(dis + n);
    float* yf     = (float*)(recs + E);

    const float inv_nn = 1.0f / (float)n;
    const float inv_gg = 1.0f / (float)G;

    // prep: zero, seg, x->bf16  (needs n*8 threads for the conversion)
    prep_kernel<<<(n * 8 + 255) / 256, 256, 0, stream>>>(x, xb, counts, st, batch, seg, n, G);

    count_kernel<<<(E + 255) / 256, 256, 0, stream>>>(ei, counts, E);
    scan_partial_kernel<<<nb, 256, 0, stream>>>(counts, bsum, n);
    scan_offsets_kernel<<<1, 256, 0, stream>>>(bsum, start, nb, n);
    scan_write_kernel<<<nb, 256, 0, stream>>>(counts, bsum, start, cursor, dis, n);
    fill_kernel<<<(E + 255) / 256, 256, 0, stream>>>(ei, cursor, dis, recs, E);

    // layer 1: xa = A_hat @ X (bf16 in/out; 2 slices x 4 ushort8-lanes)
    {
        constexpr int NPB = 64;                    // 256 / (8/2)
        int gps  = (n + NPB - 1) / NPB;
        int grid = ((gps + 3) / 4) * 8;
        gather_kernel<64, 2, false><<<grid, 256, 0, stream>>>(
            xb, start, recs, dis, nullptr, nullptr, nullptr, 0.f, a1b /*tmp xa*/, n, gps);
    }
    // NOTE: gather1 wrote xa into a1b buffer temporarily? No — keep separate:
    // (xa lives in h1b region before gemm1; h1b is rewritten by gather2 later)
    // -- see corrected call order below; gemm1 reads from h1b.

    // a1 = xa @ W1 + b1 (MFMA, bf16 out), fused BN1 stats -> st1
    gemm_mfma_kernel<64, 128, true><<<dim3((n + 63) / 64, 2), 256, 0, stream>>>(
        a1b /*xa*/, W1, b1, (void*)h1b /*a1*/, st1, n);

    // layer 2: h1 = A_hat @ relu(BN1(a1)) (bf16; 2 slices x 8 ushort8-lanes)
    {
        constexpr int NPB = 32;                    // 256 / (16/2)
        int gps  = (n + NPB - 1) / NPB;
        int grid = ((gps + 3) / 4) * 8;
        gather_kernel<128, 2, true><<<grid, 256, 0, stream>>>(
            h1b /*a1*/, start, recs, dis, st1, g1, be1, inv_nn, a1b /*h1*/, n, gps);
    }
    // a2 = h1 @ W2 + b2 (MFMA, f32 out), fused BN2 stats -> st2
    gemm_mfma_kernel<128, 256, false><<<dim3((n + 63) / 64, 4), 256, 0, stream>>>(
        a1b /*h1*/, W2, b2, (void*)a2, st2, n);

    // fused pool + solvent FC + fc1 + stats
    poolfc_kernel<<<G, 256, 0, stream>>>(a2, seg, st2, g2, be2, inv_nn,
                                         sf, Ws, bs, Wf1, bf1, yf, stf);

    final_kernel<<<G, 128, 0, stream>>>(yf, stf, gf1, bef1, Wf2, bf2, out, inv_gg);
}

// Round 10
// 141.069 us; speedup vs baseline: 3.9557x; 1.0861x over previous
//
#include <hip/hip_runtime.h>
#include <hip/hip_bf16.h>
#include <hip/hip_fp16.h>

#define EPS 1e-5f

typedef __attribute__((ext_vector_type(8))) short short8_t;            // 8 bf16 (MFMA operand)
typedef __attribute__((ext_vector_type(8))) unsigned short ushort8_t;  // 8 bf16 storage
typedef __attribute__((ext_vector_type(4))) float f32x4_t;             // MFMA accumulator

__device__ inline unsigned short f2bf(float f) {              // f32 -> bf16 RNE
    unsigned int u = __float_as_uint(f);
    unsigned int r = (u + 0x7FFFu + ((u >> 16) & 1u)) >> 16;
    return (unsigned short)r;
}
__device__ inline float bf2f(unsigned short h) {
    return __uint_as_float((unsigned int)h << 16);
}

// ------------------------------------------------- prep: zero+seg+convert ----
__global__ void prep_kernel(const float* __restrict__ x, unsigned short* __restrict__ xb,
                            int* __restrict__ counts, float* __restrict__ st,
                            const int* __restrict__ batch, int* __restrict__ seg,
                            int n, int G) {
    int i = blockIdx.x * blockDim.x + threadIdx.x;
    if (i < n * 8) {               // one ushort8 (8 feats) per thread; x row = 64 feats
        const float4* xf4 = (const float4*)x;
        float4 u = xf4[i * 2];
        float4 v = xf4[i * 2 + 1];
        ushort8_t h;
        h[0] = f2bf(u.x); h[1] = f2bf(u.y); h[2] = f2bf(u.z); h[3] = f2bf(u.w);
        h[4] = f2bf(v.x); h[5] = f2bf(v.y); h[6] = f2bf(v.z); h[7] = f2bf(v.w);
        ((ushort8_t*)xb)[i] = h;
    }
    if (i < n) counts[i] = 0;
    if (i < 1024) st[i] = 0.f;     // st1[256] | st2[512] | stf[256]
    if (i <= G) {
        if (i == G) { seg[G] = n; }
        else {
            int lo = 0, hi = n;
            while (lo < hi) {
                int mid = (lo + hi) >> 1;
                if (batch[mid] < i) lo = mid + 1; else hi = mid;
            }
            seg[i] = lo;
        }
    }
}

// ------------------------------------------------------------- CSR build ----
__global__ void count_kernel(const int* __restrict__ ei, int* __restrict__ counts, int E) {
    int e = blockIdx.x * blockDim.x + threadIdx.x;
    if (e < E) atomicAdd(&counts[ei[E + e]], 1);   // col = ei[1][e]
}

__global__ void scan_partial_kernel(const int* __restrict__ counts, int* __restrict__ bsum, int n) {
    __shared__ int s[256];
    int t = threadIdx.x;
    int i = blockIdx.x * 256 + t;
    s[t] = (i < n) ? counts[i] : 0;
    __syncthreads();
#pragma unroll
    for (int off = 128; off > 0; off >>= 1) {
        if (t < off) s[t] += s[t + off];
        __syncthreads();
    }
    if (t == 0) bsum[blockIdx.x] = s[0];
}

__global__ void scan_offsets_kernel(int* __restrict__ bsum, int* __restrict__ start, int nb, int n) {
    __shared__ int s[256];
    int t = threadIdx.x;
    int v = (t < nb) ? bsum[t] : 0;
    s[t] = v;
    __syncthreads();
#pragma unroll
    for (int off = 1; off < 256; off <<= 1) {
        int x = (t >= off) ? s[t - off] : 0;
        __syncthreads();
        s[t] += x;
        __syncthreads();
    }
    if (t < nb) bsum[t] = s[t] - v;     // exclusive
    if (t == 255) start[n] = s[255];    // grand total
}

__global__ void scan_write_kernel(const int* __restrict__ counts, const int* __restrict__ bsum,
                                  int* __restrict__ start, int* __restrict__ cursor,
                                  float* __restrict__ dis, int n) {
    __shared__ int s[256];
    int t = threadIdx.x;
    int i = blockIdx.x * 256 + t;
    int v = (i < n) ? counts[i] : 0;
    s[t] = v;
    __syncthreads();
#pragma unroll
    for (int off = 1; off < 256; off <<= 1) {
        int x = (t >= off) ? s[t - off] : 0;
        __syncthreads();
        s[t] += x;
        __syncthreads();
    }
    if (i < n) {
        int g = bsum[blockIdx.x] + s[t] - v;
        start[i]  = g;
        cursor[i] = g;
        dis[i]    = rsqrtf((float)v + 1.0f);   // deg = counts + self-loop
    }
}

// packed edge record: low 16 = source row (n < 65536), high 16 = f16(dis[row])
__global__ void fill_kernel(const int* __restrict__ ei, int* __restrict__ cursor,
                            const float* __restrict__ dis, unsigned int* __restrict__ recs,
                            int E) {
    int e = blockIdx.x * blockDim.x + threadIdx.x;
    if (e >= E) return;
    int r = ei[e];
    int c = ei[E + e];
    int pos = atomicAdd(&cursor[c], 1);
    unsigned int hw = __half_as_ushort(__float2half_rn(dis[r]));
    recs[pos] = (hw << 16) | (unsigned int)r;
}

// ---------------------------------------------------------------- gather ----
template <int F, int SLICES, bool BN>
__launch_bounds__(256)
__global__ void gather_kernel(const unsigned short* __restrict__ src, const int* __restrict__ start,
                              const unsigned int* __restrict__ recs,
                              const float* __restrict__ dis,
                              const float* __restrict__ st, const float* __restrict__ gamma,
                              const float* __restrict__ beta, float inv_n,
                              unsigned short* __restrict__ dst, int n, int gps) {
    constexpr int F8  = F / 8;        // ushort8s per node row
    constexpr int W8  = F8 / SLICES;  // lanes per node
    constexpr int NPB = 256 / W8;     // nodes per block

    int bid = blockIdx.x;
    int xl  = bid & 7;
    int slice, group;
    if (SLICES == 2) { slice = xl >> 2; group = (bid >> 3) * 4 + (xl & 3); }
    else             { slice = 0;       group = bid; }
    if (group >= gps) return;

    int local = threadIdx.x / W8;
    int lane  = threadIdx.x % W8;
    int node  = group * NPB + local;
    if (node >= n) return;
    int f8    = slice * W8 + lane;
    int feat0 = f8 * 8;

    float sc[8], sh[8];
    if (BN) {
#pragma unroll
        for (int j = 0; j < 8; j++) {
            float m = st[feat0 + j] * inv_n;
            float v = st[F + feat0 + j] * inv_n - m * m;
            sc[j] = gamma[feat0 + j] * rsqrtf(v + EPS);
            sh[j] = beta[feat0 + j] - m * sc[j];
        }
    }

    const ushort8_t* src8 = (const ushort8_t*)src;

    float di = dis[node];
    ushort8_t sv = src8[(size_t)node * F8 + f8];
    float acc[8], acc2[8];
#pragma unroll
    for (int j = 0; j < 8; j++) {
        float f = bf2f(sv[j]);
        if (BN) f = fmaxf(fmaf(f, sc[j], sh[j]), 0.f);
        acc[j]  = f * di;
        acc2[j] = 0.f;
    }

    int e  = start[node];
    int e1 = start[node + 1];
    for (; e + 1 < e1; e += 2) {
        unsigned int q0 = recs[e], q1 = recs[e + 1];
        int r0 = q0 & 0xFFFF, r1 = q1 & 0xFFFF;
        float w0 = __half2float(__ushort_as_half((unsigned short)(q0 >> 16)));
        float w1 = __half2float(__ushort_as_half((unsigned short)(q1 >> 16)));
        ushort8_t v0 = src8[(size_t)r0 * F8 + f8];
        ushort8_t v1 = src8[(size_t)r1 * F8 + f8];
#pragma unroll
        for (int j = 0; j < 8; j++) {
            float f0 = bf2f(v0[j]);
            float f1 = bf2f(v1[j]);
            if (BN) {
                f0 = fmaxf(fmaf(f0, sc[j], sh[j]), 0.f);
                f1 = fmaxf(fmaf(f1, sc[j], sh[j]), 0.f);
            }
            acc[j]  = fmaf(f0, w0, acc[j]);
            acc2[j] = fmaf(f1, w1, acc2[j]);
        }
    }
    if (e < e1) {
        unsigned int q0 = recs[e];
        int r0 = q0 & 0xFFFF;
        float w0 = __half2float(__ushort_as_half((unsigned short)(q0 >> 16)));
        ushort8_t v0 = src8[(size_t)r0 * F8 + f8];
#pragma unroll
        for (int j = 0; j < 8; j++) {
            float f0 = bf2f(v0[j]);
            if (BN) f0 = fmaxf(fmaf(f0, sc[j], sh[j]), 0.f);
            acc[j] = fmaf(f0, w0, acc[j]);
        }
    }
    ushort8_t o;
#pragma unroll
    for (int j = 0; j < 8; j++) o[j] = f2bf((acc[j] + acc2[j]) * di);
    ((ushort8_t*)dst)[(size_t)node * F8 + f8] = o;
}

// ------------------------------------------------------------- MFMA GEMM ----
// C[M, NTOT] = A[M, K] @ B[K, NTOT] + bias.
// OMODE: 0 = f32 out, 1 = bf16 out, 2 = bf16 relu out.
// A_F32: A is f32 (converted in staging) else bf16.
// STATS: atomically accumulate per-column sum/sumsq of (pre-rounding) C into st.
// Block: 4 waves (2x2), tile 64x64; wave: 32x32 via 2x2 16x16x32 bf16 frags.
template <int K, int NTOT, int OMODE, bool A_F32, bool STATS>
__launch_bounds__(256)
__global__ void gemm_mfma_kernel(const void* __restrict__ A, int lda,
                                 const float* __restrict__ B,
                                 const float* __restrict__ bias, void* __restrict__ Cout,
                                 int ldc, float* __restrict__ st, int M) {
    constexpr int KP = K + 8;               // row pad: 16B-aligned, bank-skewed
    __shared__ unsigned short As[64][KP];
    __shared__ unsigned short Bs[64][KP];   // [col][k] (B transposed)
    __shared__ float sred[2][64][2];

    const int t    = threadIdx.x;
    const int lane = t & 63;
    const int wave = t >> 6;
    const int wr   = wave >> 1;
    const int wc   = wave & 1;
    const int row0 = blockIdx.x * 64;
    const int col0 = blockIdx.y * 64;

    // stage A (64 x K -> bf16 LDS)
    constexpr int PA = (64 * K / 8) / 256;
#pragma unroll
    for (int p = 0; p < PA; p++) {
        int fi = t + 256 * p;
        int r  = fi / (K / 8);
        int c8 = fi % (K / 8);
        ushort8_t v = {};
        if (row0 + r < M) {
            if (A_F32) {
                const float* Af = (const float*)A;
                float4 u0 = *(const float4*)&Af[(size_t)(row0 + r) * lda + c8 * 8];
                float4 u1 = *(const float4*)&Af[(size_t)(row0 + r) * lda + c8 * 8 + 4];
                v[0] = f2bf(u0.x); v[1] = f2bf(u0.y); v[2] = f2bf(u0.z); v[3] = f2bf(u0.w);
                v[4] = f2bf(u1.x); v[5] = f2bf(u1.y); v[6] = f2bf(u1.z); v[7] = f2bf(u1.w);
            } else {
                v = *(const ushort8_t*)&((const unsigned short*)A)[(size_t)(row0 + r) * lda + c8 * 8];
            }
        }
        *(ushort8_t*)&As[r][c8 * 8] = v;
    }
    // stage B (K x 64 f32 -> bf16, transposed into Bs[col][k])
    constexpr int PB = (K * 16) / 256;
#pragma unroll
    for (int p = 0; p < PB; p++) {
        int fi = t + 256 * p;
        int k  = fi >> 4;
        int c4 = fi & 15;
        float4 v = *(const float4*)&B[(size_t)k * NTOT + col0 + c4 * 4];
        Bs[c4 * 4 + 0][k] = f2bf(v.x);
        Bs[c4 * 4 + 1][k] = f2bf(v.y);
        Bs[c4 * 4 + 2][k] = f2bf(v.z);
        Bs[c4 * 4 + 3][k] = f2bf(v.w);
    }
    __syncthreads();

    const int l15 = lane & 15;
    const int l16 = lane >> 4;
    f32x4_t acc[2][2] = {};
#pragma unroll
    for (int ks = 0; ks < K / 32; ks++) {
        int koff = ks * 32 + l16 * 8;
        short8_t a0 = *(const short8_t*)&As[wr * 32 + l15][koff];
        short8_t a1 = *(const short8_t*)&As[wr * 32 + 16 + l15][koff];
        short8_t b0 = *(const short8_t*)&Bs[wc * 32 + l15][koff];
        short8_t b1 = *(const short8_t*)&Bs[wc * 32 + 16 + l15][koff];
        acc[0][0] = __builtin_amdgcn_mfma_f32_16x16x32_bf16(a0, b0, acc[0][0], 0, 0, 0);
        acc[0][1] = __builtin_amdgcn_mfma_f32_16x16x32_bf16(a0, b1, acc[0][1], 0, 0, 0);
        acc[1][0] = __builtin_amdgcn_mfma_f32_16x16x32_bf16(a1, b0, acc[1][0], 0, 0, 0);
        acc[1][1] = __builtin_amdgcn_mfma_f32_16x16x32_bf16(a1, b1, acc[1][1], 0, 0, 0);
    }

    // epilogue (C/D: col=l&15, row=(l>>4)*4+j)
    float s1[2] = {0.f, 0.f}, s2[2] = {0.f, 0.f};
#pragma unroll
    for (int m = 0; m < 2; m++) {
#pragma unroll
        for (int j = 0; j < 4; j++) {
            int row = row0 + wr * 32 + m * 16 + l16 * 4 + j;
            if (row < M) {
#pragma unroll
                for (int nn = 0; nn < 2; nn++) {
                    int col = col0 + wc * 32 + nn * 16 + l15;
                    float v = acc[m][nn][j] + bias[col];
                    if (OMODE == 2) v = fmaxf(v, 0.f);
                    if (OMODE == 0) ((float*)Cout)[(size_t)row * ldc + col] = v;
                    else ((unsigned short*)Cout)[(size_t)row * ldc + col] = f2bf(v);
                    if (STATS) { s1[nn] += v; s2[nn] += v * v; }
                }
            }
        }
    }
    if (STATS) {
#pragma unroll
        for (int nn = 0; nn < 2; nn++) {
            s1[nn] += __shfl_xor(s1[nn], 16);
            s1[nn] += __shfl_xor(s1[nn], 32);
            s2[nn] += __shfl_xor(s2[nn], 16);
            s2[nn] += __shfl_xor(s2[nn], 32);
        }
        if (lane < 16) {
#pragma unroll
            for (int nn = 0; nn < 2; nn++) {
                sred[wr][wc * 32 + nn * 16 + lane][0] = s1[nn];
                sred[wr][wc * 32 + nn * 16 + lane][1] = s2[nn];
            }
        }
        __syncthreads();
        if (t < 64) {
            float a = sred[0][t][0] + sred[1][t][0];
            float b = sred[0][t][1] + sred[1][t][1];
            atomicAdd(&st[col0 + t], a);
            atomicAdd(&st[NTOT + col0 + t], b);
        }
    }
}

// ------------------------------------------------------------------ pool ----
// block g: z[g][0..256) = bf16( mean_i relu(BN2(a2[i])) ), wave-per-row reads.
// 256 thr = 4 row-slots x 64 float4-lanes; one wave load = one full 1KB a2 row.
__launch_bounds__(256)
__global__ void pool_kernel(const float* __restrict__ a2, const int* __restrict__ seg,
                            const float* __restrict__ st2, const float* __restrict__ g2,
                            const float* __restrict__ be2, float inv_n,
                            unsigned short* __restrict__ z) {
    __shared__ float4 red[4][64];
    int g  = blockIdx.x;
    int t  = threadIdx.x;
    int r  = t >> 6;          // row slot 0..3
    int f4 = t & 63;          // float4 lane (feats f4*4..f4*4+3)

    float4 sc, sh;
    {
        float m0 = st2[f4 * 4 + 0] * inv_n, m1 = st2[f4 * 4 + 1] * inv_n;
        float m2 = st2[f4 * 4 + 2] * inv_n, m3 = st2[f4 * 4 + 3] * inv_n;
        sc.x = g2[f4 * 4 + 0] * rsqrtf(st2[256 + f4 * 4 + 0] * inv_n - m0 * m0 + EPS);
        sc.y = g2[f4 * 4 + 1] * rsqrtf(st2[256 + f4 * 4 + 1] * inv_n - m1 * m1 + EPS);
        sc.z = g2[f4 * 4 + 2] * rsqrtf(st2[256 + f4 * 4 + 2] * inv_n - m2 * m2 + EPS);
        sc.w = g2[f4 * 4 + 3] * rsqrtf(st2[256 + f4 * 4 + 3] * inv_n - m3 * m3 + EPS);
        sh.x = be2[f4 * 4 + 0] - m0 * sc.x;
        sh.y = be2[f4 * 4 + 1] - m1 * sc.y;
        sh.z = be2[f4 * 4 + 2] - m2 * sc.z;
        sh.w = be2[f4 * 4 + 3] - m3 * sc.w;
    }

    int i0 = seg[g], i1 = seg[g + 1];
    float4 acc = make_float4(0.f, 0.f, 0.f, 0.f);
    for (int i = i0 + r; i < i1; i += 4) {
        float4 v = *(const float4*)&a2[(size_t)i * 256 + f4 * 4];
        acc.x += fmaxf(fmaf(v.x, sc.x, sh.x), 0.f);
        acc.y += fmaxf(fmaf(v.y, sc.y, sh.y), 0.f);
        acc.z += fmaxf(fmaf(v.z, sc.z, sh.z), 0.f);
        acc.w += fmaxf(fmaf(v.w, sc.w, sh.w), 0.f);
    }
    red[r][f4] = acc;
    __syncthreads();
    if (t < 64) {
        float4 a = red[0][t], b = red[1][t], c = red[2][t], d = red[3][t];
        float inv = 1.0f / fmaxf((float)(i1 - i0), 1.f);
        ushort4 o;
        o.x = f2bf((a.x + b.x + c.x + d.x) * inv);
        o.y = f2bf((a.y + b.y + c.y + d.y) * inv);
        o.z = f2bf((a.z + b.z + c.z + d.z) * inv);
        o.w = f2bf((a.w + b.w + c.w + d.w) * inv);
        *(ushort4*)&z[(size_t)g * 384 + t * 4] = o;
    }
}

// ----------------------------------------------------------------- final ----
__launch_bounds__(128)
__global__ void final_kernel(const float* __restrict__ y, const float* __restrict__ stf,
                             const float* __restrict__ gf, const float* __restrict__ bef,
                             const float* __restrict__ Wf2, const float* __restrict__ bf2,
                             float* __restrict__ out, float inv_n) {
    __shared__ float red[2];
    int g = blockIdx.x, f = threadIdx.x;
    float mean = stf[f] * inv_n;
    float var  = stf[128 + f] * inv_n - mean * mean;
    float sc   = gf[f] * rsqrtf(var + EPS);
    float sh   = bef[f] - mean * sc;
    float v = fmaxf(y[g * 128 + f] * sc + sh, 0.f) * Wf2[f];
#pragma unroll
    for (int off = 32; off > 0; off >>= 1) v += __shfl_down(v, off);
    if ((f & 63) == 0) red[f >> 6] = v;
    __syncthreads();
    if (f == 0) out[g] = red[0] + red[1] + bf2[0];
}

// ---------------------------------------------------------------- launch ----
extern "C" void kernel_launch(void* const* d_in, const int* in_sizes, int n_in,
                              void* d_out, int out_size, void* d_ws, size_t ws_size,
                              hipStream_t stream) {
    const float* x    = (const float*)d_in[0];
    const int*   ei   = (const int*)d_in[1];
    const int*   batch= (const int*)d_in[2];
    const float* sf   = (const float*)d_in[3];
    const float* W1   = (const float*)d_in[4];
    const float* b1   = (const float*)d_in[5];
    const float* g1   = (const float*)d_in[6];
    const float* be1  = (const float*)d_in[7];
    const float* W2   = (const float*)d_in[8];
    const float* b2   = (const float*)d_in[9];
    const float* g2   = (const float*)d_in[10];
    const float* be2  = (const float*)d_in[11];
    const float* Ws   = (const float*)d_in[12];
    const float* bs   = (const float*)d_in[13];
    const float* Wf1  = (const float*)d_in[14];
    const float* bf1  = (const float*)d_in[15];
    const float* gf1  = (const float*)d_in[16];
    const float* bef1 = (const float*)d_in[17];
    const float* Wf2  = (const float*)d_in[18];
    const float* bf2  = (const float*)d_in[19];
    float* out = (float*)d_out;

    const int n = in_sizes[0] / 64;    // 20000 nodes
    const int E = in_sizes[1] / 2;     // 320000 edges
    const int G = in_sizes[3] / 128;   // 512 graphs
    const int nb = (n + 255) / 256;

    // workspace (f32 units unless noted):
    // a2[256n] | xb[32n] | a1b[64n] | h1b[64n] | z[G*384 bf16 = G*192] |
    // st[1024] | counts[n] | start[n+1] | cursor[n] | bsum[256] | seg[G+1] |
    // dis[n] | recs[E u32] | yf[G*128]
    float* ws   = (float*)d_ws;
    float* a2   = ws;
    unsigned short* xb  = (unsigned short*)(ws + (size_t)n * 256);
    unsigned short* a1b = (unsigned short*)(ws + (size_t)n * 288);
    unsigned short* h1b = (unsigned short*)(ws + (size_t)n * 352);
    unsigned short* z   = (unsigned short*)(ws + (size_t)n * 416);
    float* st   = ws + (size_t)n * 416 + (size_t)G * 192;
    float* st1  = st;            // 256
    float* st2  = st + 256;      // 512
    float* stf  = st + 768;      // 256
    int*   counts = (int*)(st + 1024);
    int*   start  = counts + n;
    int*   cursor = start + n + 1;
    int*   bsum   = cursor + n;
    int*   seg    = bsum + 256;
    float* dis    = (float*)(seg + G + 1);
    unsigned int* recs = (unsigned int*)(dis + n);
    float* yf     = (float*)(recs + E);

    const float inv_nn = 1.0f / (float)n;
    const float inv_gg = 1.0f / (float)G;

    prep_kernel<<<(n * 8 + 255) / 256, 256, 0, stream>>>(x, xb, counts, st, batch, seg, n, G);

    count_kernel<<<(E + 255) / 256, 256, 0, stream>>>(ei, counts, E);
    scan_partial_kernel<<<nb, 256, 0, stream>>>(counts, bsum, n);
    scan_offsets_kernel<<<1, 256, 0, stream>>>(bsum, start, nb, n);
    scan_write_kernel<<<nb, 256, 0, stream>>>(counts, bsum, start, cursor, dis, n);
    fill_kernel<<<(E + 255) / 256, 256, 0, stream>>>(ei, cursor, dis, recs, E);

    // layer 1: xa = A_hat @ X  (bf16; xa -> a1b buffer)
    {
        constexpr int NPB = 64;
        int gps  = (n + NPB - 1) / NPB;
        int grid = ((gps + 3) / 4) * 8;
        gather_kernel<64, 2, false><<<grid, 256, 0, stream>>>(
            xb, start, recs, dis, nullptr, nullptr, nullptr, 0.f, a1b, n, gps);
    }
    // a1 = xa @ W1 + b1 (bf16 out -> h1b), stats -> st1
    gemm_mfma_kernel<64, 128, 1, false, true><<<dim3((n + 63) / 64, 2), 256, 0, stream>>>(
        a1b, 64, W1, b1, (void*)h1b, 128, st1, n);

    // layer 2: h1 = A_hat @ relu(BN1(a1))  (bf16; h1 -> a1b, xa dead)
    {
        constexpr int NPB = 32;
        int gps  = (n + NPB - 1) / NPB;
        int grid = ((gps + 3) / 4) * 8;
        gather_kernel<128, 2, true><<<grid, 256, 0, stream>>>(
            h1b, start, recs, dis, st1, g1, be1, inv_nn, a1b, n, gps);
    }
    // a2 = h1 @ W2 + b2 (f32 out), stats -> st2
    gemm_mfma_kernel<128, 256, 0, false, true><<<dim3((n + 63) / 64, 4), 256, 0, stream>>>(
        a1b, 128, W2, b2, (void*)a2, 256, st2, n);

    // pool -> z[:, 0:256) bf16
    pool_kernel<<<G, 256, 0, stream>>>(a2, seg, st2, g2, be2, inv_nn, z);

    // solv = relu(sf @ Ws + bs) -> z[:, 256:384) bf16   (A f32, M=G=512)
    gemm_mfma_kernel<128, 128, 2, true, false><<<dim3(G / 64, 2), 256, 0, stream>>>(
        sf, 128, Ws, bs, (void*)(z + 256), 384, nullptr, G);

    // yf = z @ Wf1 + bf1 (f32 out), stats -> stf
    gemm_mfma_kernel<384, 128, 0, false, true><<<dim3(G / 64, 2), 256, 0, stream>>>(
        z, 384, Wf1, bf1, (void*)yf, 128, stf, G);

    final_kernel<<<G, 128, 0, stream>>>(yf, stf, gf1, bef1, Wf2, bf2, out, inv_gg);
}

// Round 11
// 124.875 us; speedup vs baseline: 4.4686x; 1.1297x over previous
//
#include <hip/hip_runtime.h>
#include <hip/hip_bf16.h>
#include <hip/hip_fp16.h>

#define EPS 1e-5f
#define CAP 64   // max in-degree bucket capacity (Poisson(16) tail @64 ~ 1e-18/node)

typedef __attribute__((ext_vector_type(8))) short short8_t;            // 8 bf16 (MFMA operand)
typedef __attribute__((ext_vector_type(8))) unsigned short ushort8_t;  // 8 bf16 storage
typedef __attribute__((ext_vector_type(4))) float f32x4_t;             // MFMA accumulator

__device__ inline unsigned short f2bf(float f) {              // f32 -> bf16 RNE
    unsigned int u = __float_as_uint(f);
    unsigned int r = (u + 0x7FFFu + ((u >> 16) & 1u)) >> 16;
    return (unsigned short)r;
}
__device__ inline float bf2f(unsigned short h) {
    return __uint_as_float((unsigned int)h << 16);
}

// --------------------------------------- prep: zero + seg + convert + out ----
// zero cursor[n], st[1028] (incl barrier ctr); seg[g] binary search;
// x f32 -> xb bf16; out[g] = bf2[0] (head atomically accumulates into it).
__global__ void prep_kernel(const float* __restrict__ x, unsigned short* __restrict__ xb,
                            int* __restrict__ cursor, float* __restrict__ st,
                            const int* __restrict__ batch, int* __restrict__ seg,
                            float* __restrict__ out, const float* __restrict__ bf2,
                            int n, int G) {
    int i = blockIdx.x * blockDim.x + threadIdx.x;
    if (i < n * 8) {               // one ushort8 (8 feats) per thread; x row = 64 feats
        const float4* xf4 = (const float4*)x;
        float4 u = xf4[i * 2];
        float4 v = xf4[i * 2 + 1];
        ushort8_t h;
        h[0] = f2bf(u.x); h[1] = f2bf(u.y); h[2] = f2bf(u.z); h[3] = f2bf(u.w);
        h[4] = f2bf(v.x); h[5] = f2bf(v.y); h[6] = f2bf(v.z); h[7] = f2bf(v.w);
        ((ushort8_t*)xb)[i] = h;
    }
    if (i < n) cursor[i] = 0;
    if (i < 1028) st[i] = 0.f;     // st1[256] | st2[512] | stf[256] | ctr
    if (i < G) out[i] = bf2[0];
    if (i <= G) {
        if (i == G) { seg[G] = n; }
        else {
            int lo = 0, hi = n;
            while (lo < hi) {
                int mid = (lo + hi) >> 1;
                if (batch[mid] < i) lo = mid + 1; else hi = mid;
            }
            seg[i] = lo;
        }
    }
}

// ----------------------------------------------------------- bucket build ----
__global__ void fillb_kernel(const int* __restrict__ ei, int* __restrict__ cursor,
                             unsigned int* __restrict__ recs, int E) {
    int e = blockIdx.x * blockDim.x + threadIdx.x;
    if (e >= E) return;
    int r = ei[e];
    int c = ei[E + e];
    int pos = atomicAdd(&cursor[c], 1);
    recs[(size_t)c * CAP + pos] = (unsigned int)r;
}

// stamp f16(rsqrt(deg[row]+1)) into high 16 bits of each record
__global__ void pack_kernel(unsigned int* __restrict__ recs, const int* __restrict__ cursor, int n) {
    int i = blockIdx.x * blockDim.x + threadIdx.x;   // over n*CAP
    int node = i >> 6;    // CAP = 64
    int slot = i & 63;
    if (node >= n) return;
    if (slot < cursor[node]) {
        unsigned int r = recs[i];
        float w = rsqrtf((float)cursor[r] + 1.0f);
        recs[i] = (((unsigned int)__half_as_ushort(__float2half_rn(w))) << 16) | r;
    }
}

// ---------------------------------------------------------------- gather ----
// bf16 in / bf16 out; bucket records (row | f16 w). Lane owns 8 feats (16B).
template <int F, int SLICES, bool BN>
__launch_bounds__(256)
__global__ void gather_kernel(const unsigned short* __restrict__ src,
                              const int* __restrict__ cursor,
                              const unsigned int* __restrict__ recs,
                              const float* __restrict__ st, const float* __restrict__ gamma,
                              const float* __restrict__ beta, float inv_n,
                              unsigned short* __restrict__ dst, int n, int gps) {
    constexpr int F8  = F / 8;
    constexpr int W8  = F8 / SLICES;
    constexpr int NPB = 256 / W8;

    int bid = blockIdx.x;
    int xl  = bid & 7;
    int slice, group;
    if (SLICES == 2) { slice = xl >> 2; group = (bid >> 3) * 4 + (xl & 3); }
    else             { slice = 0;       group = bid; }
    if (group >= gps) return;

    int local = threadIdx.x / W8;
    int lane  = threadIdx.x % W8;
    int node  = group * NPB + local;
    if (node >= n) return;
    int f8    = slice * W8 + lane;
    int feat0 = f8 * 8;

    float sc[8], sh[8];
    if (BN) {
#pragma unroll
        for (int j = 0; j < 8; j++) {
            float m = st[feat0 + j] * inv_n;
            float v = st[F + feat0 + j] * inv_n - m * m;
            sc[j] = gamma[feat0 + j] * rsqrtf(v + EPS);
            sh[j] = beta[feat0 + j] - m * sc[j];
        }
    }

    const ushort8_t* src8 = (const ushort8_t*)src;

    int deg  = cursor[node];
    float di = rsqrtf((float)deg + 1.0f);
    ushort8_t sv = src8[(size_t)node * F8 + f8];
    float acc[8], acc2[8];
#pragma unroll
    for (int j = 0; j < 8; j++) {
        float f = bf2f(sv[j]);
        if (BN) f = fmaxf(fmaf(f, sc[j], sh[j]), 0.f);
        acc[j]  = f * di;
        acc2[j] = 0.f;
    }

    int e  = node * CAP;
    int e1 = e + deg;
    for (; e + 1 < e1; e += 2) {
        unsigned int q0 = recs[e], q1 = recs[e + 1];
        int r0 = q0 & 0xFFFF, r1 = q1 & 0xFFFF;
        float w0 = __half2float(__ushort_as_half((unsigned short)(q0 >> 16)));
        float w1 = __half2float(__ushort_as_half((unsigned short)(q1 >> 16)));
        ushort8_t v0 = src8[(size_t)r0 * F8 + f8];
        ushort8_t v1 = src8[(size_t)r1 * F8 + f8];
#pragma unroll
        for (int j = 0; j < 8; j++) {
            float f0 = bf2f(v0[j]);
            float f1 = bf2f(v1[j]);
            if (BN) {
                f0 = fmaxf(fmaf(f0, sc[j], sh[j]), 0.f);
                f1 = fmaxf(fmaf(f1, sc[j], sh[j]), 0.f);
            }
            acc[j]  = fmaf(f0, w0, acc[j]);
            acc2[j] = fmaf(f1, w1, acc2[j]);
        }
    }
    if (e < e1) {
        unsigned int q0 = recs[e];
        int r0 = q0 & 0xFFFF;
        float w0 = __half2float(__ushort_as_half((unsigned short)(q0 >> 16)));
        ushort8_t v0 = src8[(size_t)r0 * F8 + f8];
#pragma unroll
        for (int j = 0; j < 8; j++) {
            float f0 = bf2f(v0[j]);
            if (BN) f0 = fmaxf(fmaf(f0, sc[j], sh[j]), 0.f);
            acc[j] = fmaf(f0, w0, acc[j]);
        }
    }
    ushort8_t o;
#pragma unroll
    for (int j = 0; j < 8; j++) o[j] = f2bf((acc[j] + acc2[j]) * di);
    ((ushort8_t*)dst)[(size_t)node * F8 + f8] = o;
}

// ------------------------------------------------------------- MFMA GEMM ----
// C[M, NTOT] = A[M, K](bf16) @ B[K, NTOT](f32->bf16) + bias; out f32 or bf16.
// STATS: per-column sum/sumsq of C (pre-rounding) -> st atomically.
template <int K, int NTOT, bool OUT_BF16>
__launch_bounds__(256)
__global__ void gemm_mfma_kernel(const unsigned short* __restrict__ A, int lda,
                                 const float* __restrict__ B,
                                 const float* __restrict__ bias, void* __restrict__ Cout,
                                 int ldc, float* __restrict__ st, int M) {
    constexpr int KP = K + 8;
    __shared__ unsigned short As[64][KP];
    __shared__ unsigned short Bs[64][KP];   // [col][k] (B transposed)
    __shared__ float sred[2][64][2];

    const int t    = threadIdx.x;
    const int lane = t & 63;
    const int wave = t >> 6;
    const int wr   = wave >> 1;
    const int wc   = wave & 1;
    const int row0 = blockIdx.x * 64;
    const int col0 = blockIdx.y * 64;

    constexpr int PA = (64 * K / 8) / 256;
#pragma unroll
    for (int p = 0; p < PA; p++) {
        int fi = t + 256 * p;
        int r  = fi / (K / 8);
        int c8 = fi % (K / 8);
        ushort8_t v = {};
        if (row0 + r < M) v = *(const ushort8_t*)&A[(size_t)(row0 + r) * lda + c8 * 8];
        *(ushort8_t*)&As[r][c8 * 8] = v;
    }
    constexpr int PB = (K * 16) / 256;
#pragma unroll
    for (int p = 0; p < PB; p++) {
        int fi = t + 256 * p;
        int k  = fi >> 4;
        int c4 = fi & 15;
        float4 v = *(const float4*)&B[(size_t)k * NTOT + col0 + c4 * 4];
        Bs[c4 * 4 + 0][k] = f2bf(v.x);
        Bs[c4 * 4 + 1][k] = f2bf(v.y);
        Bs[c4 * 4 + 2][k] = f2bf(v.z);
        Bs[c4 * 4 + 3][k] = f2bf(v.w);
    }
    __syncthreads();

    const int l15 = lane & 15;
    const int l16 = lane >> 4;
    f32x4_t acc[2][2] = {};
#pragma unroll
    for (int ks = 0; ks < K / 32; ks++) {
        int koff = ks * 32 + l16 * 8;
        short8_t a0 = *(const short8_t*)&As[wr * 32 + l15][koff];
        short8_t a1 = *(const short8_t*)&As[wr * 32 + 16 + l15][koff];
        short8_t b0 = *(const short8_t*)&Bs[wc * 32 + l15][koff];
        short8_t b1 = *(const short8_t*)&Bs[wc * 32 + 16 + l15][koff];
        acc[0][0] = __builtin_amdgcn_mfma_f32_16x16x32_bf16(a0, b0, acc[0][0], 0, 0, 0);
        acc[0][1] = __builtin_amdgcn_mfma_f32_16x16x32_bf16(a0, b1, acc[0][1], 0, 0, 0);
        acc[1][0] = __builtin_amdgcn_mfma_f32_16x16x32_bf16(a1, b0, acc[1][0], 0, 0, 0);
        acc[1][1] = __builtin_amdgcn_mfma_f32_16x16x32_bf16(a1, b1, acc[1][1], 0, 0, 0);
    }

    float s1[2] = {0.f, 0.f}, s2[2] = {0.f, 0.f};
#pragma unroll
    for (int m = 0; m < 2; m++) {
#pragma unroll
        for (int j = 0; j < 4; j++) {
            int row = row0 + wr * 32 + m * 16 + l16 * 4 + j;
            if (row < M) {
#pragma unroll
                for (int nn = 0; nn < 2; nn++) {
                    int col = col0 + wc * 32 + nn * 16 + l15;
                    float v = acc[m][nn][j] + bias[col];
                    if (OUT_BF16) ((unsigned short*)Cout)[(size_t)row * ldc + col] = f2bf(v);
                    else          ((float*)Cout)[(size_t)row * ldc + col] = v;
                    s1[nn] += v;
                    s2[nn] += v * v;
                }
            }
        }
    }
#pragma unroll
    for (int nn = 0; nn < 2; nn++) {
        s1[nn] += __shfl_xor(s1[nn], 16);
        s1[nn] += __shfl_xor(s1[nn], 32);
        s2[nn] += __shfl_xor(s2[nn], 16);
        s2[nn] += __shfl_xor(s2[nn], 32);
    }
    if (lane < 16) {
#pragma unroll
        for (int nn = 0; nn < 2; nn++) {
            sred[wr][wc * 32 + nn * 16 + lane][0] = s1[nn];
            sred[wr][wc * 32 + nn * 16 + lane][1] = s2[nn];
        }
    }
    __syncthreads();
    if (t < 64) {
        float a = sred[0][t][0] + sred[1][t][0];
        float b = sred[0][t][1] + sred[1][t][1];
        atomicAdd(&st[col0 + t], a);
        atomicAdd(&st[NTOT + col0 + t], b);
    }
}

// ------------------------------------------------------------------ pool ----
// block g: z[g][0..256) = bf16( mean_i relu(BN2(a2[i])) ); wave-per-row reads.
__launch_bounds__(256)
__global__ void pool_kernel(const float* __restrict__ a2, const int* __restrict__ seg,
                            const float* __restrict__ st2, const float* __restrict__ g2,
                            const float* __restrict__ be2, float inv_n,
                            unsigned short* __restrict__ z) {
    __shared__ float4 red[4][64];
    int g  = blockIdx.x;
    int t  = threadIdx.x;
    int r  = t >> 6;
    int f4 = t & 63;

    float4 sc, sh;
    {
        float m0 = st2[f4 * 4 + 0] * inv_n, m1 = st2[f4 * 4 + 1] * inv_n;
        float m2 = st2[f4 * 4 + 2] * inv_n, m3 = st2[f4 * 4 + 3] * inv_n;
        sc.x = g2[f4 * 4 + 0] * rsqrtf(st2[256 + f4 * 4 + 0] * inv_n - m0 * m0 + EPS);
        sc.y = g2[f4 * 4 + 1] * rsqrtf(st2[256 + f4 * 4 + 1] * inv_n - m1 * m1 + EPS);
        sc.z = g2[f4 * 4 + 2] * rsqrtf(st2[256 + f4 * 4 + 2] * inv_n - m2 * m2 + EPS);
        sc.w = g2[f4 * 4 + 3] * rsqrtf(st2[256 + f4 * 4 + 3] * inv_n - m3 * m3 + EPS);
        sh.x = be2[f4 * 4 + 0] - m0 * sc.x;
        sh.y = be2[f4 * 4 + 1] - m1 * sc.y;
        sh.z = be2[f4 * 4 + 2] - m2 * sc.z;
        sh.w = be2[f4 * 4 + 3] - m3 * sc.w;
    }

    int i0 = seg[g], i1 = seg[g + 1];
    float4 acc = make_float4(0.f, 0.f, 0.f, 0.f);
    for (int i = i0 + r; i < i1; i += 4) {
        float4 v = *(const float4*)&a2[(size_t)i * 256 + f4 * 4];
        acc.x += fmaxf(fmaf(v.x, sc.x, sh.x), 0.f);
        acc.y += fmaxf(fmaf(v.y, sc.y, sh.y), 0.f);
        acc.z += fmaxf(fmaf(v.z, sc.z, sh.z), 0.f);
        acc.w += fmaxf(fmaf(v.w, sc.w, sh.w), 0.f);
    }
    red[r][f4] = acc;
    __syncthreads();
    if (t < 64) {
        float4 a = red[0][t], b = red[1][t], c = red[2][t], d = red[3][t];
        float inv = 1.0f / fmaxf((float)(i1 - i0), 1.f);
        ushort4 o;
        o.x = f2bf((a.x + b.x + c.x + d.x) * inv);
        o.y = f2bf((a.y + b.y + c.y + d.y) * inv);
        o.z = f2bf((a.z + b.z + c.z + d.z) * inv);
        o.w = f2bf((a.w + b.w + c.w + d.w) * inv);
        *(ushort4*)&z[(size_t)g * 256 + t * 4] = o;
    }
}

// ------------------------------------------------------------------ head ----
// Grid dim3(G/64, 2). Per block: solv tile (LDS, MFMA) -> fc1 (K=384 MFMA) ->
// stats atomics -> 16-block spin barrier -> BN+ReLU+Wf2 dot on live regs ->
// atomicAdd partials into out (pre-initialized to bf2[0]).
__launch_bounds__(256)
__global__ void head_kernel(const unsigned short* __restrict__ z,   // [G][256] bf16
                            const float* __restrict__ sf,
                            const float* __restrict__ Ws, const float* __restrict__ bs,
                            const float* __restrict__ Wf1, const float* __restrict__ bf1,
                            const float* __restrict__ gf, const float* __restrict__ bef,
                            const float* __restrict__ Wf2,
                            float* __restrict__ stf, int* __restrict__ ctr,
                            float* __restrict__ out, float inv_g, int nblocks) {
    constexpr int KP = 136;
    __shared__ unsigned short solvs[64][KP];
    __shared__ unsigned short As[64][KP];
    __shared__ unsigned short Bs[64][KP];
    __shared__ float sred[2][64][2];   // also reused as stf cache (256 floats)

    const int t    = threadIdx.x;
    const int lane = t & 63;
    const int wave = t >> 6;
    const int wr   = wave >> 1;
    const int wc   = wave & 1;
    const int row0 = blockIdx.x * 64;   // graph rows
    const int col0 = blockIdx.y * 64;   // output cols (0 or 64)
    const int l15  = lane & 15;
    const int l16  = lane >> 4;

    // ---- phase 1: solvs = relu(sf_tile @ Ws + bs)  (64 x 128)
#pragma unroll
    for (int p = 0; p < 4; p++) {       // As <- sf tile (f32->bf16): 64 x 16 c8
        int fi = t + 256 * p;
        int r  = fi >> 4, c8 = fi & 15;
        const float* src = &sf[(size_t)(row0 + r) * 128 + c8 * 8];
        float4 u0 = *(const float4*)src;
        float4 u1 = *(const float4*)(src + 4);
        ushort8_t v;
        v[0] = f2bf(u0.x); v[1] = f2bf(u0.y); v[2] = f2bf(u0.z); v[3] = f2bf(u0.w);
        v[4] = f2bf(u1.x); v[5] = f2bf(u1.y); v[6] = f2bf(u1.z); v[7] = f2bf(u1.w);
        *(ushort8_t*)&As[r][c8 * 8] = v;
    }
    for (int ch = 0; ch < 2; ch++) {
        __syncthreads();
#pragma unroll
        for (int p = 0; p < 8; p++) {   // Bs <- Ws[:, ch*64..] transposed
            int fi = t + 256 * p;
            int k  = fi >> 4, c4 = fi & 15;
            float4 v = *(const float4*)&Ws[(size_t)k * 128 + ch * 64 + c4 * 4];
            Bs[c4 * 4 + 0][k] = f2bf(v.x);
            Bs[c4 * 4 + 1][k] = f2bf(v.y);
            Bs[c4 * 4 + 2][k] = f2bf(v.z);
            Bs[c4 * 4 + 3][k] = f2bf(v.w);
        }
        __syncthreads();
        f32x4_t sacc[2][2] = {};
#pragma unroll
        for (int ks = 0; ks < 4; ks++) {
            int koff = ks * 32 + l16 * 8;
            short8_t a0 = *(const short8_t*)&As[wr * 32 + l15][koff];
            short8_t a1 = *(const short8_t*)&As[wr * 32 + 16 + l15][koff];
            short8_t b0 = *(const short8_t*)&Bs[wc * 32 + l15][koff];
            short8_t b1 = *(const short8_t*)&Bs[wc * 32 + 16 + l15][koff];
            sacc[0][0] = __builtin_amdgcn_mfma_f32_16x16x32_bf16(a0, b0, sacc[0][0], 0, 0, 0);
            sacc[0][1] = __builtin_amdgcn_mfma_f32_16x16x32_bf16(a0, b1, sacc[0][1], 0, 0, 0);
            sacc[1][0] = __builtin_amdgcn_mfma_f32_16x16x32_bf16(a1, b0, sacc[1][0], 0, 0, 0);
            sacc[1][1] = __builtin_amdgcn_mfma_f32_16x16x32_bf16(a1, b1, sacc[1][1], 0, 0, 0);
        }
#pragma unroll
        for (int m = 0; m < 2; m++)
#pragma unroll
            for (int j = 0; j < 4; j++)
#pragma unroll
                for (int nn = 0; nn < 2; nn++) {
                    int row = wr * 32 + m * 16 + l16 * 4 + j;
                    int col = ch * 64 + wc * 32 + nn * 16 + l15;
                    solvs[row][col] = f2bf(fmaxf(sacc[m][nn][j] + bs[col], 0.f));
                }
    }

    // ---- phase 2: fc1 tile = [z | solvs] @ Wf1 + bf1   (K = 384, 3 chunks)
    f32x4_t acc[2][2] = {};
    for (int kc = 0; kc < 3; kc++) {
        __syncthreads();
        if (kc < 2) {
#pragma unroll
            for (int p = 0; p < 4; p++) {   // As <- z chunk (bf16 direct)
                int fi = t + 256 * p;
                int r  = fi >> 4, c8 = fi & 15;
                *(ushort8_t*)&As[r][c8 * 8] =
                    *(const ushort8_t*)&z[(size_t)(row0 + r) * 256 + kc * 128 + c8 * 8];
            }
        }
#pragma unroll
        for (int p = 0; p < 8; p++) {       // Bs <- Wf1 chunk transposed
            int fi = t + 256 * p;
            int k  = fi >> 4, c4 = fi & 15;
            float4 v = *(const float4*)&Wf1[(size_t)(kc * 128 + k) * 128 + col0 + c4 * 4];
            Bs[c4 * 4 + 0][k] = f2bf(v.x);
            Bs[c4 * 4 + 1][k] = f2bf(v.y);
            Bs[c4 * 4 + 2][k] = f2bf(v.z);
            Bs[c4 * 4 + 3][k] = f2bf(v.w);
        }
        __syncthreads();
        const unsigned short (*Ap)[KP] = (kc < 2) ? As : solvs;
#pragma unroll
        for (int ks = 0; ks < 4; ks++) {
            int koff = ks * 32 + l16 * 8;
            short8_t a0 = *(const short8_t*)&Ap[wr * 32 + l15][koff];
            short8_t a1 = *(const short8_t*)&Ap[wr * 32 + 16 + l15][koff];
            short8_t b0 = *(const short8_t*)&Bs[wc * 32 + l15][koff];
            short8_t b1 = *(const short8_t*)&Bs[wc * 32 + 16 + l15][koff];
            acc[0][0] = __builtin_amdgcn_mfma_f32_16x16x32_bf16(a0, b0, acc[0][0], 0, 0, 0);
            acc[0][1] = __builtin_amdgcn_mfma_f32_16x16x32_bf16(a0, b1, acc[0][1], 0, 0, 0);
            acc[1][0] = __builtin_amdgcn_mfma_f32_16x16x32_bf16(a1, b0, acc[1][0], 0, 0, 0);
            acc[1][1] = __builtin_amdgcn_mfma_f32_16x16x32_bf16(a1, b1, acc[1][1], 0, 0, 0);
        }
    }

    // bias into acc + stats
    float s1[2] = {0.f, 0.f}, s2[2] = {0.f, 0.f};
#pragma unroll
    for (int m = 0; m < 2; m++)
#pragma unroll
        for (int j = 0; j < 4; j++)
#pragma unroll
            for (int nn = 0; nn < 2; nn++) {
                int col = col0 + wc * 32 + nn * 16 + l15;
                float v = acc[m][nn][j] + bf1[col];
                acc[m][nn][j] = v;
                s1[nn] += v;
                s2[nn] += v * v;
            }
#pragma unroll
    for (int nn = 0; nn < 2; nn++) {
        s1[nn] += __shfl_xor(s1[nn], 16);
        s1[nn] += __shfl_xor(s1[nn], 32);
        s2[nn] += __shfl_xor(s2[nn], 16);
        s2[nn] += __shfl_xor(s2[nn], 32);
    }
    if (lane < 16) {
#pragma unroll
        for (int nn = 0; nn < 2; nn++) {
            sred[wr][wc * 32 + nn * 16 + lane][0] = s1[nn];
            sred[wr][wc * 32 + nn * 16 + lane][1] = s2[nn];
        }
    }
    __syncthreads();
    if (t < 64) {
        atomicAdd(&stf[col0 + t],       sred[0][t][0] + sred[1][t][0]);
        atomicAdd(&stf[128 + col0 + t], sred[0][t][1] + sred[1][t][1]);
    }

    // ---- device-scope barrier across all head blocks
    __threadfence();
    __syncthreads();
    if (t == 0) {
        atomicAdd(ctr, 1);
        while (atomicAdd(ctr, 0) < nblocks) { }
    }
    __syncthreads();

    // ---- final: BN + ReLU + Wf2 dot on live accumulators, atomic into out
    float* sflat = &sred[0][0][0];
    sflat[t] = atomicAdd(&stf[t], 0.f);   // t < 256: cache full stats in LDS
    __syncthreads();

#pragma unroll
    for (int m = 0; m < 2; m++)
#pragma unroll
        for (int j = 0; j < 4; j++) {
            float p = 0.f;
#pragma unroll
            for (int nn = 0; nn < 2; nn++) {
                int col = col0 + wc * 32 + nn * 16 + l15;
                float mean = sflat[col] * inv_g;
                float var  = sflat[128 + col] * inv_g - mean * mean;
                float sc   = gf[col] * rsqrtf(var + EPS);
                float sh   = bef[col] - mean * sc;
                p += fmaxf(fmaf(acc[m][nn][j], sc, sh), 0.f) * Wf2[col];
            }
            // reduce over l15 within each 16-lane group
            p += __shfl_xor(p, 1);
            p += __shfl_xor(p, 2);
            p += __shfl_xor(p, 4);
            p += __shfl_xor(p, 8);
            if (l15 == 0) {
                int row = wr * 32 + m * 16 + l16 * 4 + j;
                atomicAdd(&out[row0 + row], p);
            }
        }
}

// ---------------------------------------------------------------- launch ----
extern "C" void kernel_launch(void* const* d_in, const int* in_sizes, int n_in,
                              void* d_out, int out_size, void* d_ws, size_t ws_size,
                              hipStream_t stream) {
    const float* x    = (const float*)d_in[0];
    const int*   ei   = (const int*)d_in[1];
    const int*   batch= (const int*)d_in[2];
    const float* sf   = (const float*)d_in[3];
    const float* W1   = (const float*)d_in[4];
    const float* b1   = (const float*)d_in[5];
    const float* g1   = (const float*)d_in[6];
    const float* be1  = (const float*)d_in[7];
    const float* W2   = (const float*)d_in[8];
    const float* b2   = (const float*)d_in[9];
    const float* g2   = (const float*)d_in[10];
    const float* be2  = (const float*)d_in[11];
    const float* Ws   = (const float*)d_in[12];
    const float* bs   = (const float*)d_in[13];
    const float* Wf1  = (const float*)d_in[14];
    const float* bf1  = (const float*)d_in[15];
    const float* gf1  = (const float*)d_in[16];
    const float* bef1 = (const float*)d_in[17];
    const float* Wf2  = (const float*)d_in[18];
    const float* bf2  = (const float*)d_in[19];
    float* out = (float*)d_out;

    const int n = in_sizes[0] / 64;    // 20000 nodes
    const int E = in_sizes[1] / 2;     // 320000 edges
    const int G = in_sizes[3] / 128;   // 512 graphs

    // workspace (f32 units unless noted):
    // a2[256n] | xb[32n] | a1b[64n] | h1b[64n] | z[G*256 bf16 = G*128] |
    // st[1028: st1 256, st2 512, stf 256, ctr] | cursor[n] | seg[G+1] | recs[n*CAP u32]
    float* ws   = (float*)d_ws;
    float* a2   = ws;
    unsigned short* xb  = (unsigned short*)(ws + (size_t)n * 256);
    unsigned short* a1b = (unsigned short*)(ws + (size_t)n * 288);
    unsigned short* h1b = (unsigned short*)(ws + (size_t)n * 352);
    unsigned short* z   = (unsigned short*)(ws + (size_t)n * 416);
    float* st   = ws + (size_t)n * 416 + (size_t)G * 128;
    float* st1  = st;
    float* st2  = st + 256;
    float* stf  = st + 768;
    int*   ctr  = (int*)(st + 1024);
    int*   cursor = (int*)(st + 1028);
    int*   seg    = cursor + n;
    unsigned int* recs = (unsigned int*)(seg + G + 1);

    const float inv_nn = 1.0f / (float)n;
    const float inv_gg = 1.0f / (float)G;

    prep_kernel<<<(n * 8 + 255) / 256, 256, 0, stream>>>(x, xb, cursor, st, batch, seg,
                                                         out, bf2, n, G);
    fillb_kernel<<<(E + 255) / 256, 256, 0, stream>>>(ei, cursor, recs, E);
    pack_kernel<<<(n * CAP + 255) / 256, 256, 0, stream>>>(recs, cursor, n);

    // layer 1: xa = A_hat @ X  (bf16; -> a1b)
    {
        constexpr int NPB = 64;
        int gps  = (n + NPB - 1) / NPB;
        int grid = ((gps + 3) / 4) * 8;
        gather_kernel<64, 2, false><<<grid, 256, 0, stream>>>(
            xb, cursor, recs, nullptr, nullptr, nullptr, 0.f, a1b, n, gps);
    }
    // a1 = xa @ W1 + b1 (bf16 out -> h1b), stats -> st1
    gemm_mfma_kernel<64, 128, true><<<dim3((n + 63) / 64, 2), 256, 0, stream>>>(
        a1b, 64, W1, b1, (void*)h1b, 128, st1, n);

    // layer 2: h1 = A_hat @ relu(BN1(a1))  (bf16; -> a1b)
    {
        constexpr int NPB = 32;
        int gps  = (n + NPB - 1) / NPB;
        int grid = ((gps + 3) / 4) * 8;
        gather_kernel<128, 2, true><<<grid, 256, 0, stream>>>(
            h1b, cursor, recs, st1, g1, be1, inv_nn, a1b, n, gps);
    }
    // a2 = h1 @ W2 + b2 (f32 out), stats -> st2
    gemm_mfma_kernel<128, 256, false><<<dim3((n + 63) / 64, 4), 256, 0, stream>>>(
        a1b, 128, W2, b2, (void*)a2, 256, st2, n);

    // pool -> z (bf16 [G][256])
    pool_kernel<<<G, 256, 0, stream>>>(a2, seg, st2, g2, be2, inv_nn, z);

    // head: solv + fc1 + BN-stats + barrier + final (out += partials)
    head_kernel<<<dim3(G / 64, 2), 256, 0, stream>>>(z, sf, Ws, bs, Wf1, bf1,
                                                     gf1, bef1, Wf2, stf, ctr,
                                                     out, inv_gg, (G / 64) * 2);
}